// Round 14
// baseline (220.712 us; speedup 1.0000x reference)
//
#include <hip/hip_runtime.h>
#include <hip/hip_bf16.h>

// TSP decoder forward: B=64, POMO=200, N=1000, EMB=128, H=8, D=16.
// k0 W->f16 | kpre mask->tiled f16 (MFMA-fragment order, wave-contiguous) |
// k1 MFMA K/V proj (weights LDS-staged) | k1b kmax | k2 q (+LoRA) | k2b qnorm |
// k3 MFMA attention n-split (tiled mask) | k3c combine | k4 combine (+LoRA) |
// k5 MFMA final (tiled mask).

typedef _Float16 f16;
typedef _Float16 f16x2 __attribute__((ext_vector_type(2)));
typedef _Float16 f16x4 __attribute__((ext_vector_type(4)));
typedef _Float16 f16x8 __attribute__((ext_vector_type(8)));
typedef __fp16  h4   __attribute__((ext_vector_type(4)));
typedef float   f32x4 __attribute__((ext_vector_type(4)));

#define LORA_SCALE 1.0f
#define L2E 1.44269504f

__device__ __forceinline__ f16x2 pk2(f16 a, f16 b){ f16x2 r; r[0]=a; r[1]=b; return r; }

#if __has_builtin(__builtin_amdgcn_fdot2)
__device__ __forceinline__ float fdot2f(f16x2 a, f16x2 b, float c){ return __builtin_amdgcn_fdot2(a, b, c, false); }
#else
__device__ __forceinline__ float fdot2f(f16x2 a, f16x2 b, float c){ return c + (float)a[0]*(float)b[0] + (float)a[1]*(float)b[1]; }
#endif

#if __has_builtin(__builtin_amdgcn_cvt_pkrtz)
__device__ __forceinline__ f16x2 pkrtz(float a, float b){
  return __builtin_bit_cast(f16x2, __builtin_amdgcn_cvt_pkrtz(a, b));
}
#else
__device__ __forceinline__ f16x2 pkrtz(float a, float b){ return pk2((f16)a, (f16)b); }
#endif

// D[i][j] = sum_k A[i][k]*B[k][j] + C  via v_mfma_f32_16x16x16_f16.
// A: lane holds row i=(l&15), k=4*(l>>4)+j. B: lane holds col j=(l&15), k=4*(l>>4)+j.
// D: lane holds col j=(l&15), row i=4*(l>>4)+reg.   (validated end-to-end in k3/k5)
__device__ __forceinline__ f32x4 mfma16(f16x4 a, f16x4 b, f32x4 c){
  return __builtin_amdgcn_mfma_f32_16x16x16f16(
      __builtin_bit_cast(h4, a), __builtin_bit_cast(h4, b), c, 0, 0, 0);
}

__device__ __forceinline__ float sumsq16(const f16* p){
  const f16x8* v = (const f16x8*)p;
  f16x8 a = v[0], b = v[1];
  float s = 0.f;
  s = fdot2f(pk2(a[0],a[1]), pk2(a[0],a[1]), s);
  s = fdot2f(pk2(a[2],a[3]), pk2(a[2],a[3]), s);
  s = fdot2f(pk2(a[4],a[5]), pk2(a[4],a[5]), s);
  s = fdot2f(pk2(a[6],a[7]), pk2(a[6],a[7]), s);
  s = fdot2f(pk2(b[0],b[1]), pk2(b[0],b[1]), s);
  s = fdot2f(pk2(b[2],b[3]), pk2(b[2],b[3]), s);
  s = fdot2f(pk2(b[4],b[5]), pk2(b[4],b[5]), s);
  s = fdot2f(pk2(b[6],b[7]), pk2(b[6],b[7]), s);
  return s;
}

// ---------------- k0: Wk|Wv -> f16 [256][128] ----------------
__global__ __launch_bounds__(256) void k0_wconv(const float* __restrict__ Wk,
    const float* __restrict__ Wv, f16* __restrict__ WkvF)
{
  const int i = blockIdx.x*256 + threadIdx.x;           // 0..8191, one f32x4 each
  const float4 v = (i < 4096) ? ((const float4*)Wk)[i] : ((const float4*)Wv)[i-4096];
  f16x2 lo = pkrtz(v.x,v.y), hi = pkrtz(v.z,v.w);
  f16x4 o = __builtin_shufflevector(lo, hi, 0, 1, 2, 3);
  *(f16x4*)(WkvF + i*4) = o;
}

// ---------------- kpre: mask -> maskT16 tiled (value = mask*log2e as f16) ----------------
// Layout: [b][mt(13)][t(63)][g(4)][col(16)][r(4)] f16; lane (g*16+col) covers its 4 r's
// -> MFMA-fragment lane order; every consumer wave-load is ONE contiguous 512B f16x4.
// Rows clamped at 199 (matches consumers' mq clamp); n>=1000 zero-filled.
__global__ __launch_bounds__(256) void kpre_mtile(const float* __restrict__ mask,
    f16* __restrict__ maskT)
{
  const int tid = threadIdx.x, lane = tid & 63, w = tid >> 6;
  const int b = blockIdx.x, mt = blockIdx.y;
  const int t = blockIdx.z*4 + w;
  if (t >= 63) return;
  const int col = lane & 15, g = lane >> 4;
  const int row = min(mt*16 + col, 199);
  const int n0 = t*16 + g*4;
  float4 v = {0.f, 0.f, 0.f, 0.f};
  if (n0 + 3 < 1000) v = *(const float4*)(mask + ((size_t)b*200 + row)*1000 + n0);
  f16x4 o = __builtin_shufflevector(pkrtz(v.x*L2E, v.y*L2E), pkrtz(v.z*L2E, v.w*L2E), 0,1,2,3);
  *(f16x4*)(maskT + (((size_t)(b*13 + mt)*63) + t)*256 + lane*4) = o;
}

// ---------------- k1: MFMA K/V projection + nodes -> f16 ----------------
// grid (16, 64), 256 thr (4 waves), 64 node rows per block. Weights LDS-staged per ct.
#define NSTR 132
#define WSTR 136
__global__ __launch_bounds__(256) void k1_proj(const float* __restrict__ nodes,
    const f16* __restrict__ WkvF,
    f16* __restrict__ nodesF, f16* __restrict__ Kp, f16* __restrict__ Vt)
{
  __shared__ f16 lds[64*NSTR];     // 16896 B node tile
  __shared__ f16 wlds[16*WSTR];    //  4352 B weight tile
  const int tid = threadIdx.x, lane = tid & 63, w = tid >> 6;
  const int b = blockIdx.y;
  const int n0 = blockIdx.x * 64;
  const int rows = min(64, 1000 - n0);                  // 64 or 40
  for (int i = tid; i < rows*32; i += 256) {            // 32 f32x4 per row
    const int r = i >> 5, cq = i & 31;
    float4 v = ((const float4*)(nodes + ((size_t)b*1000 + n0 + r)*128))[cq];
    f16x2 lo = pkrtz(v.x,v.y), hi = pkrtz(v.z,v.w);
    f16x4 o = __builtin_shufflevector(lo, hi, 0, 1, 2, 3);
    *(f16x4*)(lds + r*NSTR + cq*4) = o;
    *(f16x4*)(nodesF + ((size_t)b*1000 + n0 + r)*128 + cq*4) = o;
  }
  __syncthreads();
  const int col = lane & 15, g = lane >> 4, g4 = g*4;
  const int mloc = w*16 + col;
  f16x4 nf[8];
  #pragma unroll
  for (int kk = 0; kk < 8; ++kk)
    nf[kk] = *(const f16x4*)(lds + min(mloc, rows-1)*NSTR + kk*16 + g4);
  const int wr = tid >> 4, wc = tid & 15;
  for (int ct = 0; ct < 16; ++ct) {
    __syncthreads();
    *(f16x8*)(wlds + wr*WSTR + wc*8) =
        *(const f16x8*)(WkvF + (ct*16 + wr)*128 + wc*8);
    __syncthreads();
    f16x4 wf[8];
    #pragma unroll
    for (int kk = 0; kk < 8; ++kk)
      wf[kk] = *(const f16x4*)(wlds + col*WSTR + kk*16 + g4);
    f32x4 acc = {0.f, 0.f, 0.f, 0.f};
    if (ct < 8) {                                       // K-head ct: D[c][m]
      #pragma unroll
      for (int kk = 0; kk < 8; ++kk) acc = mfma16(wf[kk], nf[kk], acc);
      if (mloc < rows) {
        const int nn = n0 + mloc;
        f16x4 ov = __builtin_shufflevector(pk2((f16)acc[0],(f16)acc[1]),
                                           pk2((f16)acc[2],(f16)acc[3]), 0,1,2,3);
        *(f16x4*)(Kp + ((size_t)(b*8+ct)*1000 + nn)*16 + g4) = ov;
      }
    } else {                                            // V-head ct-8: D[m][c]
      #pragma unroll
      for (int kk = 0; kk < 8; ++kk) acc = mfma16(nf[kk], wf[kk], acc);
      if (w*16 + g4 + 3 < rows) {
        const int nbase = n0 + w*16 + g4;
        f16x4 ov = __builtin_shufflevector(pk2((f16)acc[0],(f16)acc[1]),
                                           pk2((f16)acc[2],(f16)acc[3]), 0,1,2,3);
        *(f16x4*)(Vt + ((size_t)(b*8+(ct-8))*16 + col)*1000 + nbase) = ov;
      }
    }
  }
}

// ---------------- k1b: kmax[bh] = max_n ||Kp[bh][n]|| ----------------
__global__ __launch_bounds__(256) void k1b_kmax(const f16* __restrict__ Kp,
    float* __restrict__ kmaxA)
{
  __shared__ float wmax[4];
  const int bh = blockIdx.x, tid = threadIdx.x, lane = tid & 63, w = tid >> 6;
  const f16* base = Kp + (size_t)bh*16000;
  float mx = 0.f;
  for (int n = tid; n < 1000; n += 256) mx = fmaxf(mx, sumsq16(base + n*16));
  #pragma unroll
  for (int off = 32; off; off >>= 1) mx = fmaxf(mx, __shfl_xor(mx, off, 64));
  if (lane == 0) wmax[w] = mx;
  __syncthreads();
  if (tid == 0) {
    float m = fmaxf(fmaxf(wmax[0], wmax[1]), fmaxf(wmax[2], wmax[3]));
    kmaxA[bh] = sqrtf(m);
  }
}

// ---------------- k2: q = q1@Wqf^T + last@Wql^T + LoRA ----------------
__global__ __launch_bounds__(256) void k2_q(const float* __restrict__ q1,
    const float* __restrict__ last, const float* __restrict__ Wqf,
    const float* __restrict__ Wql, const float* __restrict__ lqA,
    const float* __restrict__ lqB, f16* __restrict__ qF)
{
  __shared__ f16 q1r[32*128];
  __shared__ f16 lar[32*128];
  __shared__ float t16[32*16];
  const int tid = threadIdx.x;
  const int row0 = blockIdx.x * 32;
  {
    const float4* s1 = (const float4*)(q1 + (size_t)row0*128);
    const float4* s2 = (const float4*)(last + (size_t)row0*128);
    f16x2* d1 = (f16x2*)q1r; f16x2* d2 = (f16x2*)lar;
    for (int i = tid; i < 32*32; i += 256) {
      float4 v = s1[i];
      d1[2*i] = pkrtz(v.x,v.y); d1[2*i+1] = pkrtz(v.z,v.w);
      float4 u = s2[i];
      d2[2*i] = pkrtz(u.x,u.y); d2[2*i+1] = pkrtz(u.z,u.w);
    }
  }
  __syncthreads();
  for (int idx = tid; idx < 32*16; idx += 256) {
    const int r = idx >> 4, kk = idx & 15;
    const f16x8* lrow = (const f16x8*)(lar + r*128);
    const float* arow = lqA + kk*128;
    float s = 0.f;
    #pragma unroll
    for (int cc = 0; cc < 16; ++cc) {
      f16x8 a = lrow[cc];
      float4 wa = *(const float4*)(arow + cc*8);
      float4 wb = *(const float4*)(arow + cc*8 + 4);
      s = fdot2f(pk2(a[0],a[1]), pkrtz(wa.x,wa.y), s);
      s = fdot2f(pk2(a[2],a[3]), pkrtz(wa.z,wa.w), s);
      s = fdot2f(pk2(a[4],a[5]), pkrtz(wb.x,wb.y), s);
      s = fdot2f(pk2(a[6],a[7]), pkrtz(wb.z,wb.w), s);
    }
    t16[idx] = s;
  }
  __syncthreads();
  const int c = tid & 127, rg = tid >> 7, rb = rg*16;
  float acc[16];
  #pragma unroll
  for (int r = 0; r < 16; ++r) acc[r] = 0.f;
  const float* wfr = Wqf + c*128;
  const float* wlr = Wql + c*128;
  for (int c0 = 0; c0 < 128; c0 += 16) {
    float4 f0 = *(const float4*)(wfr + c0);
    float4 f1 = *(const float4*)(wfr + c0 + 4);
    float4 f2 = *(const float4*)(wfr + c0 + 8);
    float4 f3 = *(const float4*)(wfr + c0 + 12);
    f16x2 wf[8] = { pkrtz(f0.x,f0.y), pkrtz(f0.z,f0.w), pkrtz(f1.x,f1.y), pkrtz(f1.z,f1.w),
                    pkrtz(f2.x,f2.y), pkrtz(f2.z,f2.w), pkrtz(f3.x,f3.y), pkrtz(f3.z,f3.w) };
    float4 g0 = *(const float4*)(wlr + c0);
    float4 g1 = *(const float4*)(wlr + c0 + 4);
    float4 g2 = *(const float4*)(wlr + c0 + 8);
    float4 g3 = *(const float4*)(wlr + c0 + 12);
    f16x2 wl[8] = { pkrtz(g0.x,g0.y), pkrtz(g0.z,g0.w), pkrtz(g1.x,g1.y), pkrtz(g1.z,g1.w),
                    pkrtz(g2.x,g2.y), pkrtz(g2.z,g2.w), pkrtz(g3.x,g3.y), pkrtz(g3.z,g3.w) };
    #pragma unroll
    for (int r = 0; r < 16; ++r) {
      const f16x8* qp = (const f16x8*)(q1r + (rb+r)*128 + c0);
      const f16x8* lp = (const f16x8*)(lar + (rb+r)*128 + c0);
      f16x8 a0 = qp[0], a1 = qp[1], b0 = lp[0], b1 = lp[1];
      float s = acc[r];
      s = fdot2f(pk2(a0[0],a0[1]), wf[0], s);
      s = fdot2f(pk2(a0[2],a0[3]), wf[1], s);
      s = fdot2f(pk2(a0[4],a0[5]), wf[2], s);
      s = fdot2f(pk2(a0[6],a0[7]), wf[3], s);
      s = fdot2f(pk2(a1[0],a1[1]), wf[4], s);
      s = fdot2f(pk2(a1[2],a1[3]), wf[5], s);
      s = fdot2f(pk2(a1[4],a1[5]), wf[6], s);
      s = fdot2f(pk2(a1[6],a1[7]), wf[7], s);
      s = fdot2f(pk2(b0[0],b0[1]), wl[0], s);
      s = fdot2f(pk2(b0[2],b0[3]), wl[1], s);
      s = fdot2f(pk2(b0[4],b0[5]), wl[2], s);
      s = fdot2f(pk2(b0[6],b0[7]), wl[3], s);
      s = fdot2f(pk2(b1[0],b1[1]), wl[4], s);
      s = fdot2f(pk2(b1[2],b1[3]), wl[5], s);
      s = fdot2f(pk2(b1[4],b1[5]), wl[6], s);
      s = fdot2f(pk2(b1[6],b1[7]), wl[7], s);
      acc[r] = s;
    }
  }
  const float* lb = lqB + c*16;
  float lbv[16];
  #pragma unroll
  for (int i = 0; i < 16; i += 4) {
    float4 t = *(const float4*)(lb + i);
    lbv[i] = t.x; lbv[i+1] = t.y; lbv[i+2] = t.z; lbv[i+3] = t.w;
  }
  #pragma unroll
  for (int r = 0; r < 16; ++r) {
    float dl = 0.f;
    #pragma unroll
    for (int kk = 0; kk < 16; ++kk) dl += t16[(rb+r)*16 + kk] * lbv[kk];
    acc[r] += dl * LORA_SCALE;
  }
  const int h = c >> 4, d = c & 15;
  #pragma unroll
  for (int r = 0; r < 16; ++r) {
    const int grow = row0 + rb + r;
    const int b = grow / 200, m = grow % 200;
    qF[(((size_t)b*8 + h)*200 + m)*16 + d] = (f16)acc[r];
  }
}

// ---------------- k2b: qn[bh][m] = ||qF[bh][m]|| ----------------
__global__ __launch_bounds__(256) void k2b_qnorm(const f16* __restrict__ qF,
    float* __restrict__ qnA)
{
  const int idx = blockIdx.x*256 + threadIdx.x;         // 0..102399
  qnA[idx] = sqrtf(sumsq16(qF + (size_t)idx*16));
}

// ---------------- k3: MFMA attention, n-split halves, partial (O,l) out ----------------
// grid (64,8,2), 512 thr. TILED=1: mask from maskT16 (wave-contiguous f16x4, value
// already *log2e). TILED=0: legacy scattered float4 path.
#define VSTRL 516
template<int TILED>
__global__ __launch_bounds__(512) void k3_attn(const f16* __restrict__ Kp,
    const f16* __restrict__ Vt, const f16* __restrict__ qF,
    const float* __restrict__ mask, const f16* __restrict__ maskT,
    const float* __restrict__ kmaxA, const float* __restrict__ qnA,
    f16* __restrict__ Opart, float* __restrict__ lpart)
{
  extern __shared__ char smem[];
  f16* Kl = (f16*)smem;                     // [512][16] : 16384 B
  f16* Vl = (f16*)(smem + 16384);           // [16][516] : 16512 B
  const int tid = threadIdx.x;
  const int lane = tid & 63, w = tid >> 6;
  const int b = blockIdx.x, h = blockIdx.y, z = blockIdx.z;
  const int bh = b*8 + h;
  { // stage K half: one row per thread, quad-swizzled
    const int nl = tid;
    const int n = z*512 + nl;
    f16x4 v0{}, v1{}, v2{}, v3{};
    if (n < 1000) {
      const f16x4* src = (const f16x4*)(Kp + (size_t)bh*16000 + n*16);
      v0 = src[0]; v1 = src[1]; v2 = src[2]; v3 = src[3];
    }
    const int sw = (nl >> 2) & 3;
    f16* dst = Kl + nl*16;
    *(f16x4*)(dst + (0^sw)*4) = v0;
    *(f16x4*)(dst + (1^sw)*4) = v1;
    *(f16x4*)(dst + (2^sw)*4) = v2;
    *(f16x4*)(dst + (3^sw)*4) = v3;
  }
  { // stage V half: 16 f16 per thread
    const int d = tid >> 5, c16 = (tid & 31) * 16;
    const f16* srow = Vt + (size_t)bh*16000 + d*1000;
    f16* drow = Vl + d*VSTRL + c16;
    const int nbase = z*512 + c16;
    if (nbase + 15 < 1000) {
      const f16x4* s4 = (const f16x4*)(srow + nbase);
      *(f16x4*)(drow)    = s4[0];
      *(f16x4*)(drow+4)  = s4[1];
      *(f16x4*)(drow+8)  = s4[2];
      *(f16x4*)(drow+12) = s4[3];
    } else {
      for (int j = 0; j < 16; ++j) drow[j] = (nbase+j < 1000) ? srow[nbase+j] : (f16)0;
    }
  }
  __syncthreads();

  const int col = lane & 15, g = lane >> 4, g4 = g*4;
  const int kqoff = (g ^ (col >> 2)) * 4;
  const f32x4 zero = {0.f, 0.f, 0.f, 0.f};
  const int tA = w, tB = (w + 8 < 13) ? (w + 8) : 12;
  const int mA = tA*16, mB = tB*16;
  const int mqA = min(mA + col, 199), mqB = min(mB + col, 199);
  const f16x4 qfA = *(const f16x4*)(qF + (size_t)bh*3200 + mqA*16 + g4);
  const f16x4 qfB = *(const f16x4*)(qF + (size_t)bh*3200 + mqB*16 + g4);
  const float kmx = kmaxA[bh];
  const float mbA = -kmx * qnA[bh*200 + mqA] * 0.360673760f;
  const float mbB = -kmx * qnA[bh*200 + mqB] * 0.360673760f;
  const float* mpA = mask + ((size_t)b*200 + mqA)*1000 + z*512;
  const float* mpB = mask + ((size_t)b*200 + mqB)*1000 + z*512;
  const f16* mtA = maskT + ((size_t)(b*13 + tA)*63)*256 + lane*4;
  const f16* mtB = maskT + ((size_t)(b*13 + tB)*63)*256 + lane*4;

  f32x4 OA = zero, OB = zero;
  float lA0=0.f, lA1=0.f, lA2=0.f, lA3=0.f;
  float lB0=0.f, lB1=0.f, lB2=0.f, lB3=0.f;
  const int NTc = 32 - z*2;
  #pragma unroll 2
  for (int t = 0; t < NTc; ++t) {
    const int nl = t*16;
    const int tg = z*32 + t;
    const f16x4 kf = *(const f16x4*)(Kl + (nl+col)*16 + kqoff);
    f32x4 sA = mfma16(kf, qfA, zero);
    f32x4 sB = mfma16(kf, qfB, zero);
    float xA0, xA1, xA2, xA3, xB0, xB1, xB2, xB3;
    if (TILED) {
      const f16x4 ka = *(const f16x4*)(mtA + tg*256);
      const f16x4 kb = *(const f16x4*)(mtB + tg*256);
      xA0 = (float)ka[0] + mbA; xA1 = (float)ka[1] + mbA;
      xA2 = (float)ka[2] + mbA; xA3 = (float)ka[3] + mbA;
      xB0 = (float)kb[0] + mbB; xB1 = (float)kb[1] + mbB;
      xB2 = (float)kb[2] + mbB; xB3 = (float)kb[3] + mbB;
    } else {
      const float4 mkA = *(const float4*)(mpA + nl + g4);
      const float4 mkB = *(const float4*)(mpB + nl + g4);
      xA0 = fmaf(mkA.x, L2E, mbA); xA1 = fmaf(mkA.y, L2E, mbA);
      xA2 = fmaf(mkA.z, L2E, mbA); xA3 = fmaf(mkA.w, L2E, mbA);
      xB0 = fmaf(mkB.x, L2E, mbB); xB1 = fmaf(mkB.y, L2E, mbB);
      xB2 = fmaf(mkB.z, L2E, mbB); xB3 = fmaf(mkB.w, L2E, mbB);
    }
    const float pA0 = exp2f(fmaf(sA[0], 0.360673760f, xA0));
    const float pA1 = exp2f(fmaf(sA[1], 0.360673760f, xA1));
    const float pA2 = exp2f(fmaf(sA[2], 0.360673760f, xA2));
    const float pA3 = exp2f(fmaf(sA[3], 0.360673760f, xA3));
    const float pB0 = exp2f(fmaf(sB[0], 0.360673760f, xB0));
    const float pB1 = exp2f(fmaf(sB[1], 0.360673760f, xB1));
    const float pB2 = exp2f(fmaf(sB[2], 0.360673760f, xB2));
    const float pB3 = exp2f(fmaf(sB[3], 0.360673760f, xB3));
    lA0 += pA0; lA1 += pA1; lA2 += pA2; lA3 += pA3;
    lB0 += pB0; lB1 += pB1; lB2 += pB2; lB3 += pB3;
    const f16x4 pfA = __builtin_shufflevector(pkrtz(pA0,pA1), pkrtz(pA2,pA3), 0,1,2,3);
    const f16x4 pfB = __builtin_shufflevector(pkrtz(pB0,pB1), pkrtz(pB2,pB3), 0,1,2,3);
    const f16x4 vf = *(const f16x4*)(Vl + col*VSTRL + nl + g4);
    OA = mfma16(vf, pfA, OA);
    OB = mfma16(vf, pfB, OB);
  }
  if (z == 1) { // ragged global tile 62: local rows 480..495, keys valid only g<2
    const int nl = 480;
    const f16x4 kf = *(const f16x4*)(Kl + (nl+col)*16 + kqoff);
    f32x4 sA = mfma16(kf, qfA, zero);
    f32x4 sB = mfma16(kf, qfB, zero);
    float pA0=0.f,pA1=0.f,pA2=0.f,pA3=0.f, pB0=0.f,pB1=0.f,pB2=0.f,pB3=0.f;
    if (g < 2) {
      float xA0, xA1, xA2, xA3, xB0, xB1, xB2, xB3;
      if (TILED) {
        const f16x4 ka = *(const f16x4*)(mtA + 62*256);
        const f16x4 kb = *(const f16x4*)(mtB + 62*256);
        xA0 = (float)ka[0] + mbA; xA1 = (float)ka[1] + mbA;
        xA2 = (float)ka[2] + mbA; xA3 = (float)ka[3] + mbA;
        xB0 = (float)kb[0] + mbB; xB1 = (float)kb[1] + mbB;
        xB2 = (float)kb[2] + mbB; xB3 = (float)kb[3] + mbB;
      } else {
        const float4 mkA = *(const float4*)(mpA + nl + g4);
        const float4 mkB = *(const float4*)(mpB + nl + g4);
        xA0 = fmaf(mkA.x, L2E, mbA); xA1 = fmaf(mkA.y, L2E, mbA);
        xA2 = fmaf(mkA.z, L2E, mbA); xA3 = fmaf(mkA.w, L2E, mbA);
        xB0 = fmaf(mkB.x, L2E, mbB); xB1 = fmaf(mkB.y, L2E, mbB);
        xB2 = fmaf(mkB.z, L2E, mbB); xB3 = fmaf(mkB.w, L2E, mbB);
      }
      pA0 = exp2f(fmaf(sA[0], 0.360673760f, xA0));
      pA1 = exp2f(fmaf(sA[1], 0.360673760f, xA1));
      pA2 = exp2f(fmaf(sA[2], 0.360673760f, xA2));
      pA3 = exp2f(fmaf(sA[3], 0.360673760f, xA3));
      pB0 = exp2f(fmaf(sB[0], 0.360673760f, xB0));
      pB1 = exp2f(fmaf(sB[1], 0.360673760f, xB1));
      pB2 = exp2f(fmaf(sB[2], 0.360673760f, xB2));
      pB3 = exp2f(fmaf(sB[3], 0.360673760f, xB3));
      lA0 += pA0; lA1 += pA1; lA2 += pA2; lA3 += pA3;
      lB0 += pB0; lB1 += pB1; lB2 += pB2; lB3 += pB3;
    }
    const f16x4 pfA = __builtin_shufflevector(pkrtz(pA0,pA1), pkrtz(pA2,pA3), 0,1,2,3);
    const f16x4 pfB = __builtin_shufflevector(pkrtz(pB0,pB1), pkrtz(pB2,pB3), 0,1,2,3);
    const f16x4 vf = *(const f16x4*)(Vl + col*VSTRL + ((g < 2) ? (nl + g4) : 0));
    OA = mfma16(vf, pfA, OA);
    OB = mfma16(vf, pfB, OB);
  }
  float lA = (lA0 + lA1) + (lA2 + lA3);
  float lB = (lB0 + lB1) + (lB2 + lB3);
  lA += __shfl_xor(lA, 16, 64); lA += __shfl_xor(lA, 32, 64);
  lB += __shfl_xor(lB, 16, 64); lB += __shfl_xor(lB, 32, 64);
  const size_t pbase = (size_t)(z*512 + bh)*200;
  if (mA + col < 200) {
    const f16x4 ov = __builtin_shufflevector(pkrtz(OA[0], OA[1]), pkrtz(OA[2], OA[3]), 0,1,2,3);
    *(f16x4*)(Opart + (pbase + mA + col)*16 + g4) = ov;
    if (g == 0) lpart[pbase + mA + col] = lA;
  }
  if (mB + col < 200) {
    const f16x4 ov = __builtin_shufflevector(pkrtz(OB[0], OB[1]), pkrtz(OB[2], OB[3]), 0,1,2,3);
    *(f16x4*)(Opart + (pbase + mB + col)*16 + g4) = ov;
    if (g == 0) lpart[pbase + mB + col] = lB;
  }
}

// ---------------- k3c: combine halves + normalize -> oc ----------------
__global__ __launch_bounds__(256) void k3c_comb(const f16* __restrict__ Opart,
    const float* __restrict__ lpart, f16* __restrict__ ocmh)
{
  const int idx = blockIdx.x*256 + threadIdx.x;         // 0..409599
  const int r = idx >> 2, q = idx & 3;
  const f16x4 o0 = *(const f16x4*)(Opart + (size_t)r*16 + q*4);
  const f16x4 o1 = *(const f16x4*)(Opart + ((size_t)102400 + r)*16 + q*4);
  const float l = lpart[r] + lpart[102400 + r];
  const float inv = 1.f / fmaxf(l, 1e-35f);
  const int bh = r / 200, m = r - bh*200;
  const int b = bh >> 3, hh = bh & 7;
  const float v0 = ((float)o0[0] + (float)o1[0]) * inv;
  const float v1 = ((float)o0[1] + (float)o1[1]) * inv;
  const float v2 = ((float)o0[2] + (float)o1[2]) * inv;
  const float v3 = ((float)o0[3] + (float)o1[3]) * inv;
  const f16x4 o = __builtin_shufflevector(pkrtz(v0, v1), pkrtz(v2, v3), 0, 1, 2, 3);
  *(f16x4*)(ocmh + ((size_t)(b*200 + m)*128) + hh*16 + q*4) = o;
}

// ---------------- k4: mh = oc@Wc^T + bc + LoRA (IN-PLACE oc->mh) ----------------
__global__ __launch_bounds__(256) void k4_comb(const f16* ocF,
    const float* __restrict__ Wc, const float* __restrict__ bc,
    const float* __restrict__ lcA, const float* __restrict__ lcB,
    f16* mhF)
{
  __shared__ f16 ocr[32*128];
  __shared__ float t16[32*16];
  const int tid = threadIdx.x;
  const int row0 = blockIdx.x * 32;
  {
    const f16x8* s1 = (const f16x8*)(ocF + (size_t)row0*128);
    f16x8* d1 = (f16x8*)ocr;
    for (int i = tid; i < 512; i += 256) d1[i] = s1[i];
  }
  __syncthreads();
  for (int idx = tid; idx < 32*16; idx += 256) {
    const int r = idx >> 4, kk = idx & 15;
    const f16x8* lrow = (const f16x8*)(ocr + r*128);
    const float* arow = lcA + kk*128;
    float s = 0.f;
    #pragma unroll
    for (int cc = 0; cc < 16; ++cc) {
      f16x8 a = lrow[cc];
      float4 wa = *(const float4*)(arow + cc*8);
      float4 wb = *(const float4*)(arow + cc*8 + 4);
      s = fdot2f(pk2(a[0],a[1]), pkrtz(wa.x,wa.y), s);
      s = fdot2f(pk2(a[2],a[3]), pkrtz(wa.z,wa.w), s);
      s = fdot2f(pk2(a[4],a[5]), pkrtz(wb.x,wb.y), s);
      s = fdot2f(pk2(a[6],a[7]), pkrtz(wb.z,wb.w), s);
    }
    t16[idx] = s;
  }
  __syncthreads();
  const int c = tid & 127, rg = tid >> 7, rb = rg*16;
  float acc[16];
  const float bias = bc[c];
  #pragma unroll
  for (int r = 0; r < 16; ++r) acc[r] = bias;
  const float* wrow = Wc + c*128;
  for (int c0 = 0; c0 < 128; c0 += 16) {
    float4 w0 = *(const float4*)(wrow + c0);
    float4 w1 = *(const float4*)(wrow + c0 + 4);
    float4 w2 = *(const float4*)(wrow + c0 + 8);
    float4 w3 = *(const float4*)(wrow + c0 + 12);
    f16x2 wv[8] = { pkrtz(w0.x,w0.y), pkrtz(w0.z,w0.w), pkrtz(w1.x,w1.y), pkrtz(w1.z,w1.w),
                    pkrtz(w2.x,w2.y), pkrtz(w2.z,w2.w), pkrtz(w3.x,w3.y), pkrtz(w3.z,w3.w) };
    #pragma unroll
    for (int r = 0; r < 16; ++r) {
      const f16x8* op = (const f16x8*)(ocr + (rb+r)*128 + c0);
      f16x8 a0 = op[0], a1 = op[1];
      float s = acc[r];
      s = fdot2f(pk2(a0[0],a0[1]), wv[0], s);
      s = fdot2f(pk2(a0[2],a0[3]), wv[1], s);
      s = fdot2f(pk2(a0[4],a0[5]), wv[2], s);
      s = fdot2f(pk2(a0[6],a0[7]), wv[3], s);
      s = fdot2f(pk2(a1[0],a1[1]), wv[4], s);
      s = fdot2f(pk2(a1[2],a1[3]), wv[5], s);
      s = fdot2f(pk2(a1[4],a1[5]), wv[6], s);
      s = fdot2f(pk2(a1[6],a1[7]), wv[7], s);
      acc[r] = s;
    }
  }
  const float* lb = lcB + c*16;
  float lbv[16];
  #pragma unroll
  for (int i = 0; i < 16; i += 4) {
    float4 t = *(const float4*)(lb + i);
    lbv[i] = t.x; lbv[i+1] = t.y; lbv[i+2] = t.z; lbv[i+3] = t.w;
  }
  #pragma unroll
  for (int r = 0; r < 16; ++r) {
    float dl = 0.f;
    #pragma unroll
    for (int kk = 0; kk < 16; ++kk) dl += t16[(rb+r)*16 + kk] * lbv[kk];
    acc[r] += dl * LORA_SCALE;
  }
  #pragma unroll
  for (int r = 0; r < 16; ++r) {
    mhF[(size_t)(row0 + rb + r)*128 + c] = (f16)acc[r];
  }
}

// ---------------- k5: MFMA probs = softmax(10*tanh(mh@nodes^T/sqrt(128)) + mask) ----------------
// grid (64, 7), 1024 thr (16 waves). TILED=1: mask from maskT16 (contiguous f16x4).
template<int TILED>
__global__ __launch_bounds__(1024) void k5_final(const f16* __restrict__ mhF,
    const f16* __restrict__ nodesF, const float* __restrict__ mask,
    const f16* __restrict__ maskT, float* __restrict__ out)
{
  __shared__ float sumsA[16][16];
  __shared__ float sumsB[16][16];
  const int tid = threadIdx.x, lane = tid & 63, w = tid >> 6;
  const int b = blockIdx.x, j = blockIdx.y;
  const int col = lane & 15, g = lane >> 4, g4 = g*4;
  const int tmA = 2*j, tmB = min(2*j + 1, 12);
  const int mA = tmA*16 + col, mB = tmB*16 + col;
  const int mqA = min(mA, 199), mqB = min(mB, 199);
  f16x4 bfA[8], bfB[8];
  {
    const f16* a = mhF + (size_t)(b*200 + mqA)*128;
    const f16* bb = mhF + (size_t)(b*200 + mqB)*128;
    #pragma unroll
    for (int kk = 0; kk < 8; ++kk) {
      bfA[kk] = *(const f16x4*)(a + kk*16 + g4);
      bfB[kk] = *(const f16x4*)(bb + kk*16 + g4);
    }
  }
  const float* mrowA = mask + (size_t)(b*200 + mqA)*1000;
  const float* mrowB = mask + (size_t)(b*200 + mqB)*1000;
  const f16* mtA = maskT + ((size_t)(b*13 + tmA)*63)*256 + lane*4;
  const f16* mtB = maskT + ((size_t)(b*13 + tmB)*63)*256 + lane*4;
  const f16* nb = nodesF + (size_t)b*128000;
  f16x4 pfA[4], pfB[4];
  float lsumA = 0.f, lsumB = 0.f;
  #pragma unroll
  for (int i = 0; i < 4; ++i) {
    const int t = w + i*16;
    float pA0 = 0.f, pA1 = 0.f, pA2 = 0.f, pA3 = 0.f;
    float pB0 = 0.f, pB1 = 0.f, pB2 = 0.f, pB3 = 0.f;
    if (t < 63) {
      const int nr = min(t*16 + col, 999);
      const f16* na = nb + nr*128;
      f32x4 accA = {0.f, 0.f, 0.f, 0.f};
      f32x4 accB = {0.f, 0.f, 0.f, 0.f};
      #pragma unroll
      for (int kk = 0; kk < 8; ++kk) {
        f16x4 af = *(const f16x4*)(na + kk*16 + g4);
        accA = mfma16(af, bfA[kk], accA);
        accB = mfma16(af, bfB[kk], accB);
      }
      const int n0 = t*16 + g4;
      float mklA[4], mklB[4];                 // mask * log2e
      if (TILED) {
        const f16x4 ka = *(const f16x4*)(mtA + t*256);
        const f16x4 kb = *(const f16x4*)(mtB + t*256);
        #pragma unroll
        for (int r = 0; r < 4; ++r) { mklA[r] = (float)ka[r]; mklB[r] = (float)kb[r]; }
      } else {
        float4 a = {0,0,0,0}, bb = {0,0,0,0};
        if (n0 + 3 < 1000) { a = *(const float4*)(mrowA + n0); bb = *(const float4*)(mrowB + n0); }
        mklA[0]=a.x*L2E; mklA[1]=a.y*L2E; mklA[2]=a.z*L2E; mklA[3]=a.w*L2E;
        mklB[0]=bb.x*L2E; mklB[1]=bb.y*L2E; mklB[2]=bb.z*L2E; mklB[3]=bb.w*L2E;
      }
      float pvA[4], pvB[4];
      #pragma unroll
      for (int r = 0; r < 4; ++r) {
        const bool ok = (n0 + r < 1000);
        float xA = accA[r] * 0.08838834764831845f;          // /sqrt(128)
        float eA = exp2f(xA * 2.8853900817779268f);         // e^{2x}
        float thA = 1.f - 2.f/(eA + 1.f);                   // tanh
        float tA0 = exp2f(fmaf(thA, 14.4269504f, mklA[r])); // 10*l2e*th + mk*l2e
        pvA[r] = ok ? tA0 : 0.f;
        lsumA += pvA[r];
        float xB = accB[r] * 0.08838834764831845f;
        float eB = exp2f(xB * 2.8853900817779268f);
        float thB = 1.f - 2.f/(eB + 1.f);
        float tB0 = exp2f(fmaf(thB, 14.4269504f, mklB[r]));
        pvB[r] = ok ? tB0 : 0.f;
        lsumB += pvB[r];
      }
      pA0 = pvA[0]; pA1 = pvA[1]; pA2 = pvA[2]; pA3 = pvA[3];
      pB0 = pvB[0]; pB1 = pvB[1]; pB2 = pvB[2]; pB3 = pvB[3];
    }
    pfA[i] = __builtin_shufflevector(pkrtz(pA0, pA1), pkrtz(pA2, pA3), 0, 1, 2, 3);
    pfB[i] = __builtin_shufflevector(pkrtz(pB0, pB1), pkrtz(pB2, pB3), 0, 1, 2, 3);
  }
  lsumA += __shfl_xor(lsumA, 16, 64);
  lsumA += __shfl_xor(lsumA, 32, 64);
  lsumB += __shfl_xor(lsumB, 16, 64);
  lsumB += __shfl_xor(lsumB, 32, 64);
  if (lane < 16) { sumsA[w][lane] = lsumA; sumsB[w][lane] = lsumB; }
  __syncthreads();
  float SA = 0.f, SB = 0.f;
  #pragma unroll
  for (int ww = 0; ww < 16; ++ww) { SA += sumsA[ww][col]; SB += sumsB[ww][col]; }
  const float invA = 1.f / SA;
  const float invB = 1.f / SB;
  if (mA < 200) {
    float* ob = out + (size_t)(b*200 + mA)*1000;
    #pragma unroll
    for (int i = 0; i < 4; ++i) {
      const int t = w + i*16;
      if (t < 63) {
        const int n0 = t*16 + g4;
        const f16x4 pv = pfA[i];
        if (n0 + 3 < 1000) {
          float4 o;
          o.x = (float)pv[0]*invA; o.y = (float)pv[1]*invA;
          o.z = (float)pv[2]*invA; o.w = (float)pv[3]*invA;
          *(float4*)(ob + n0) = o;
        } else {
          #pragma unroll
          for (int r = 0; r < 4; ++r) if (n0 + r < 1000) ob[n0+r] = (float)pv[r]*invA;
        }
      }
    }
  }
  if (mB < 200 && tmB != tmA) {
    float* ob = out + (size_t)(b*200 + mB)*1000;
    #pragma unroll
    for (int i = 0; i < 4; ++i) {
      const int t = w + i*16;
      if (t < 63) {
        const int n0 = t*16 + g4;
        const f16x4 pv = pfB[i];
        if (n0 + 3 < 1000) {
          float4 o;
          o.x = (float)pv[0]*invB; o.y = (float)pv[1]*invB;
          o.z = (float)pv[2]*invB; o.w = (float)pv[3]*invB;
          *(float4*)(ob + n0) = o;
        } else {
          #pragma unroll
          for (int r = 0; r < 4; ++r) if (n0 + r < 1000) ob[n0+r] = (float)pv[r]*invB;
        }
      }
    }
  }
}

extern "C" void kernel_launch(void* const* d_in, const int* in_sizes, int n_in,
                              void* d_out, int out_size, void* d_ws, size_t ws_size,
                              hipStream_t stream)
{
  (void)in_sizes; (void)n_in; (void)out_size;
  const float* nodes = (const float*)d_in[0];
  const float* q1    = (const float*)d_in[1];
  const float* last  = (const float*)d_in[2];
  const float* mask  = (const float*)d_in[3];
  const float* Wqf   = (const float*)d_in[4];
  const float* Wql   = (const float*)d_in[5];
  const float* Wk    = (const float*)d_in[6];
  const float* Wv    = (const float*)d_in[7];
  const float* Wc    = (const float*)d_in[8];
  const float* bc    = (const float*)d_in[9];
  const float* lqA   = (const float*)d_in[10];
  const float* lqB   = (const float*)d_in[11];
  const float* lcA   = (const float*)d_in[12];
  const float* lcB   = (const float*)d_in[13];
  float* out = (float*)d_out;
  char* ws = (char*)d_ws;
  // ws layout (bytes):
  f16* nodesF  = (f16*)(ws);               // 16,384,000
  f16* Kp      = (f16*)(ws + 16384000);    // 16,384,000
  f16* Vt      = (f16*)(ws + 32768000);    // 16,384,000
  f16* qF      = (f16*)(ws + 49152000);    //  3,276,800
  f16* ocmh    = (f16*)(ws + 52428800);    //  3,276,800
  f16* WkvF    = (f16*)(ws + 55705600);    //     65,536
  float* kmaxA = (float*)(ws + 55771136);  //      2,048
  float* qnA   = (float*)(ws + 55773184);  //    409,600
  f16* OpartF  = (f16*)(ws + 56182784);    //  6,553,600
  float* lpart = (float*)(ws + 62736384);  //    819,200  (end 63,555,584)
  f16* maskT   = (f16*)(ws + 63555584);    // 26,836,992  (end 90,392,576)
  const bool tiled = ws_size >= 90392576ULL;

  k0_wconv<<<dim3(32), 256, 0, stream>>>(Wk, Wv, WkvF);
  if (tiled) kpre_mtile<<<dim3(64, 13, 16), 256, 0, stream>>>(mask, maskT);
  k1_proj<<<dim3(16, 64), 256, 0, stream>>>(nodes, WkvF, nodesF, Kp, Vt);
  k1b_kmax<<<dim3(512), 256, 0, stream>>>(Kp, kmaxA);
  k2_q<<<dim3(400), 256, 0, stream>>>(q1, last, Wqf, Wql, lqA, lqB, qF);
  k2b_qnorm<<<dim3(400), 256, 0, stream>>>(qF, qnA);
  if (tiled)
    k3_attn<1><<<dim3(64, 8, 2), 512, 32896, stream>>>(Kp, Vt, qF, mask, maskT, kmaxA, qnA, OpartF, lpart);
  else
    k3_attn<0><<<dim3(64, 8, 2), 512, 32896, stream>>>(Kp, Vt, qF, mask, maskT, kmaxA, qnA, OpartF, lpart);
  k3c_comb<<<dim3(1600), 256, 0, stream>>>(OpartF, lpart, ocmh);
  k4_comb<<<dim3(400), 256, 0, stream>>>(ocmh, Wc, bc, lcA, lcB, ocmh);
  if (tiled)
    k5_final<1><<<dim3(64, 7), 1024, 0, stream>>>(ocmh, nodesF, mask, maskT, out);
  else
    k5_final<0><<<dim3(64, 7), 1024, 0, stream>>>(ocmh, nodesF, mask, maskT, out);
}

// Round 15
// 195.438 us; speedup vs baseline: 1.1293x; 1.1293x over previous
//
#include <hip/hip_runtime.h>
#include <hip/hip_bf16.h>

// TSP decoder forward: B=64, POMO=200, N=1000, EMB=128, H=8, D=16.
// k0 W->f16 | k1 MFMA K/V proj + nodes->nodesT (fragment-tiled) | k1b kmax |
// k2 q (+LoRA) | k2b qnorm | k3 MFMA attention n-split | k3c combine |
// k4 combine (+LoRA, in-place) | k5 MFMA final (tiled nodesT reads, LDS-coalesced writes).

typedef _Float16 f16;
typedef _Float16 f16x2 __attribute__((ext_vector_type(2)));
typedef _Float16 f16x4 __attribute__((ext_vector_type(4)));
typedef _Float16 f16x8 __attribute__((ext_vector_type(8)));
typedef __fp16  h4   __attribute__((ext_vector_type(4)));
typedef float   f32x4 __attribute__((ext_vector_type(4)));

#define LORA_SCALE 1.0f
#define L2E 1.44269504f

__device__ __forceinline__ f16x2 pk2(f16 a, f16 b){ f16x2 r; r[0]=a; r[1]=b; return r; }

#if __has_builtin(__builtin_amdgcn_fdot2)
__device__ __forceinline__ float fdot2f(f16x2 a, f16x2 b, float c){ return __builtin_amdgcn_fdot2(a, b, c, false); }
#else
__device__ __forceinline__ float fdot2f(f16x2 a, f16x2 b, float c){ return c + (float)a[0]*(float)b[0] + (float)a[1]*(float)b[1]; }
#endif

#if __has_builtin(__builtin_amdgcn_cvt_pkrtz)
__device__ __forceinline__ f16x2 pkrtz(float a, float b){
  return __builtin_bit_cast(f16x2, __builtin_amdgcn_cvt_pkrtz(a, b));
}
#else
__device__ __forceinline__ f16x2 pkrtz(float a, float b){ return pk2((f16)a, (f16)b); }
#endif

// D[i][j] = sum_k A[i][k]*B[k][j] + C  via v_mfma_f32_16x16x16_f16.
// A: lane holds row i=(l&15), k=4*(l>>4)+j. B: lane holds col j=(l&15), k=4*(l>>4)+j.
// D: lane holds col j=(l&15), row i=4*(l>>4)+reg.   (validated end-to-end in k3/k5)
__device__ __forceinline__ f32x4 mfma16(f16x4 a, f16x4 b, f32x4 c){
  return __builtin_amdgcn_mfma_f32_16x16x16f16(
      __builtin_bit_cast(h4, a), __builtin_bit_cast(h4, b), c, 0, 0, 0);
}

__device__ __forceinline__ float sumsq16(const f16* p){
  const f16x8* v = (const f16x8*)p;
  f16x8 a = v[0], b = v[1];
  float s = 0.f;
  s = fdot2f(pk2(a[0],a[1]), pk2(a[0],a[1]), s);
  s = fdot2f(pk2(a[2],a[3]), pk2(a[2],a[3]), s);
  s = fdot2f(pk2(a[4],a[5]), pk2(a[4],a[5]), s);
  s = fdot2f(pk2(a[6],a[7]), pk2(a[6],a[7]), s);
  s = fdot2f(pk2(b[0],b[1]), pk2(b[0],b[1]), s);
  s = fdot2f(pk2(b[2],b[3]), pk2(b[2],b[3]), s);
  s = fdot2f(pk2(b[4],b[5]), pk2(b[4],b[5]), s);
  s = fdot2f(pk2(b[6],b[7]), pk2(b[6],b[7]), s);
  return s;
}

// ---------------- k0: Wk|Wv -> f16 [256][128] ----------------
__global__ __launch_bounds__(256) void k0_wconv(const float* __restrict__ Wk,
    const float* __restrict__ Wv, f16* __restrict__ WkvF)
{
  const int i = blockIdx.x*256 + threadIdx.x;           // 0..8191, one f32x4 each
  const float4 v = (i < 4096) ? ((const float4*)Wk)[i] : ((const float4*)Wv)[i-4096];
  f16x2 lo = pkrtz(v.x,v.y), hi = pkrtz(v.z,v.w);
  f16x4 o = __builtin_shufflevector(lo, hi, 0, 1, 2, 3);
  *(f16x4*)(WkvF + i*4) = o;
}

// ---------------- k1: MFMA K/V projection + nodes -> nodesT (fragment-tiled) ----------------
// grid (16, 64), 256 thr (4 waves), 64 node rows per block. Weights LDS-staged per ct.
// nodesT layout: [b][t(63)][kk(8)][lane(64)][r(4)] f16 where lane=(g*16+col),
// value = nodes_f16[row=t*16+col][kk*16+g*4+r]. k5's A-frag loads are then ONE
// contiguous 512B wave-load each. Tail tile 62 cols 8..15 filled with row 999
// (replicates consumers' min(nr,999) clamp bit-exactly).
#define NSTR 132
#define WSTR 136
__global__ __launch_bounds__(256) void k1_proj(const float* __restrict__ nodes,
    const f16* __restrict__ WkvF,
    f16* __restrict__ nodesT, f16* __restrict__ Kp, f16* __restrict__ Vt)
{
  __shared__ f16 lds[64*NSTR];     // 16896 B node tile
  __shared__ f16 wlds[16*WSTR];    //  4352 B weight tile
  const int tid = threadIdx.x, lane = tid & 63, w = tid >> 6;
  const int b = blockIdx.y;
  const int n0 = blockIdx.x * 64;
  const int rows = min(64, 1000 - n0);                  // 64 or 40
  for (int i = tid; i < rows*32; i += 256) {            // 32 f32x4 per row
    const int r = i >> 5, cq = i & 31;
    float4 v = ((const float4*)(nodes + ((size_t)b*1000 + n0 + r)*128))[cq];
    f16x2 lo = pkrtz(v.x,v.y), hi = pkrtz(v.z,v.w);
    f16x4 o = __builtin_shufflevector(lo, hi, 0, 1, 2, 3);
    *(f16x4*)(lds + r*NSTR + cq*4) = o;
    const int grow = n0 + r;
    const int t = grow >> 4, gcol = grow & 15;
    const int kk = cq >> 2, gg = cq & 3;
    f16* dstT = nodesT + (((size_t)(b*63 + t)*8 + kk)*256);
    *(f16x4*)(dstT + (gg*16 + gcol)*4) = o;
    if (grow == 999) {                                   // clamp-fill tile 62 cols 8..15
      f16* d62 = nodesT + (((size_t)(b*63 + 62)*8 + kk)*256);
      #pragma unroll
      for (int cf = 8; cf < 16; ++cf) *(f16x4*)(d62 + (gg*16 + cf)*4) = o;
    }
  }
  __syncthreads();
  const int col = lane & 15, g = lane >> 4, g4 = g*4;
  const int mloc = w*16 + col;
  f16x4 nf[8];
  #pragma unroll
  for (int kk = 0; kk < 8; ++kk)
    nf[kk] = *(const f16x4*)(lds + min(mloc, rows-1)*NSTR + kk*16 + g4);
  const int wr = tid >> 4, wc = tid & 15;
  for (int ct = 0; ct < 16; ++ct) {
    __syncthreads();
    *(f16x8*)(wlds + wr*WSTR + wc*8) =
        *(const f16x8*)(WkvF + (ct*16 + wr)*128 + wc*8);
    __syncthreads();
    f16x4 wf[8];
    #pragma unroll
    for (int kk = 0; kk < 8; ++kk)
      wf[kk] = *(const f16x4*)(wlds + col*WSTR + kk*16 + g4);
    f32x4 acc = {0.f, 0.f, 0.f, 0.f};
    if (ct < 8) {                                       // K-head ct: D[c][m]
      #pragma unroll
      for (int kk = 0; kk < 8; ++kk) acc = mfma16(wf[kk], nf[kk], acc);
      if (mloc < rows) {
        const int nn = n0 + mloc;
        f16x4 ov = __builtin_shufflevector(pk2((f16)acc[0],(f16)acc[1]),
                                           pk2((f16)acc[2],(f16)acc[3]), 0,1,2,3);
        *(f16x4*)(Kp + ((size_t)(b*8+ct)*1000 + nn)*16 + g4) = ov;
      }
    } else {                                            // V-head ct-8: D[m][c]
      #pragma unroll
      for (int kk = 0; kk < 8; ++kk) acc = mfma16(nf[kk], wf[kk], acc);
      if (w*16 + g4 + 3 < rows) {
        const int nbase = n0 + w*16 + g4;
        f16x4 ov = __builtin_shufflevector(pk2((f16)acc[0],(f16)acc[1]),
                                           pk2((f16)acc[2],(f16)acc[3]), 0,1,2,3);
        *(f16x4*)(Vt + ((size_t)(b*8+(ct-8))*16 + col)*1000 + nbase) = ov;
      }
    }
  }
}

// ---------------- k1b: kmax[bh] = max_n ||Kp[bh][n]|| ----------------
__global__ __launch_bounds__(256) void k1b_kmax(const f16* __restrict__ Kp,
    float* __restrict__ kmaxA)
{
  __shared__ float wmax[4];
  const int bh = blockIdx.x, tid = threadIdx.x, lane = tid & 63, w = tid >> 6;
  const f16* base = Kp + (size_t)bh*16000;
  float mx = 0.f;
  for (int n = tid; n < 1000; n += 256) mx = fmaxf(mx, sumsq16(base + n*16));
  #pragma unroll
  for (int off = 32; off; off >>= 1) mx = fmaxf(mx, __shfl_xor(mx, off, 64));
  if (lane == 0) wmax[w] = mx;
  __syncthreads();
  if (tid == 0) {
    float m = fmaxf(fmaxf(wmax[0], wmax[1]), fmaxf(wmax[2], wmax[3]));
    kmaxA[bh] = sqrtf(m);
  }
}

// ---------------- k2: q = q1@Wqf^T + last@Wql^T + LoRA ----------------
__global__ __launch_bounds__(256) void k2_q(const float* __restrict__ q1,
    const float* __restrict__ last, const float* __restrict__ Wqf,
    const float* __restrict__ Wql, const float* __restrict__ lqA,
    const float* __restrict__ lqB, f16* __restrict__ qF)
{
  __shared__ f16 q1r[32*128];
  __shared__ f16 lar[32*128];
  __shared__ float t16[32*16];
  const int tid = threadIdx.x;
  const int row0 = blockIdx.x * 32;
  {
    const float4* s1 = (const float4*)(q1 + (size_t)row0*128);
    const float4* s2 = (const float4*)(last + (size_t)row0*128);
    f16x2* d1 = (f16x2*)q1r; f16x2* d2 = (f16x2*)lar;
    for (int i = tid; i < 32*32; i += 256) {
      float4 v = s1[i];
      d1[2*i] = pkrtz(v.x,v.y); d1[2*i+1] = pkrtz(v.z,v.w);
      float4 u = s2[i];
      d2[2*i] = pkrtz(u.x,u.y); d2[2*i+1] = pkrtz(u.z,u.w);
    }
  }
  __syncthreads();
  for (int idx = tid; idx < 32*16; idx += 256) {
    const int r = idx >> 4, kk = idx & 15;
    const f16x8* lrow = (const f16x8*)(lar + r*128);
    const float* arow = lqA + kk*128;
    float s = 0.f;
    #pragma unroll
    for (int cc = 0; cc < 16; ++cc) {
      f16x8 a = lrow[cc];
      float4 wa = *(const float4*)(arow + cc*8);
      float4 wb = *(const float4*)(arow + cc*8 + 4);
      s = fdot2f(pk2(a[0],a[1]), pkrtz(wa.x,wa.y), s);
      s = fdot2f(pk2(a[2],a[3]), pkrtz(wa.z,wa.w), s);
      s = fdot2f(pk2(a[4],a[5]), pkrtz(wb.x,wb.y), s);
      s = fdot2f(pk2(a[6],a[7]), pkrtz(wb.z,wb.w), s);
    }
    t16[idx] = s;
  }
  __syncthreads();
  const int c = tid & 127, rg = tid >> 7, rb = rg*16;
  float acc[16];
  #pragma unroll
  for (int r = 0; r < 16; ++r) acc[r] = 0.f;
  const float* wfr = Wqf + c*128;
  const float* wlr = Wql + c*128;
  for (int c0 = 0; c0 < 128; c0 += 16) {
    float4 f0 = *(const float4*)(wfr + c0);
    float4 f1 = *(const float4*)(wfr + c0 + 4);
    float4 f2 = *(const float4*)(wfr + c0 + 8);
    float4 f3 = *(const float4*)(wfr + c0 + 12);
    f16x2 wf[8] = { pkrtz(f0.x,f0.y), pkrtz(f0.z,f0.w), pkrtz(f1.x,f1.y), pkrtz(f1.z,f1.w),
                    pkrtz(f2.x,f2.y), pkrtz(f2.z,f2.w), pkrtz(f3.x,f3.y), pkrtz(f3.z,f3.w) };
    float4 g0 = *(const float4*)(wlr + c0);
    float4 g1 = *(const float4*)(wlr + c0 + 4);
    float4 g2 = *(const float4*)(wlr + c0 + 8);
    float4 g3 = *(const float4*)(wlr + c0 + 12);
    f16x2 wl[8] = { pkrtz(g0.x,g0.y), pkrtz(g0.z,g0.w), pkrtz(g1.x,g1.y), pkrtz(g1.z,g1.w),
                    pkrtz(g2.x,g2.y), pkrtz(g2.z,g2.w), pkrtz(g3.x,g3.y), pkrtz(g3.z,g3.w) };
    #pragma unroll
    for (int r = 0; r < 16; ++r) {
      const f16x8* qp = (const f16x8*)(q1r + (rb+r)*128 + c0);
      const f16x8* lp = (const f16x8*)(lar + (rb+r)*128 + c0);
      f16x8 a0 = qp[0], a1 = qp[1], b0 = lp[0], b1 = lp[1];
      float s = acc[r];
      s = fdot2f(pk2(a0[0],a0[1]), wf[0], s);
      s = fdot2f(pk2(a0[2],a0[3]), wf[1], s);
      s = fdot2f(pk2(a0[4],a0[5]), wf[2], s);
      s = fdot2f(pk2(a0[6],a0[7]), wf[3], s);
      s = fdot2f(pk2(a1[0],a1[1]), wf[4], s);
      s = fdot2f(pk2(a1[2],a1[3]), wf[5], s);
      s = fdot2f(pk2(a1[4],a1[5]), wf[6], s);
      s = fdot2f(pk2(a1[6],a1[7]), wf[7], s);
      s = fdot2f(pk2(b0[0],b0[1]), wl[0], s);
      s = fdot2f(pk2(b0[2],b0[3]), wl[1], s);
      s = fdot2f(pk2(b0[4],b0[5]), wl[2], s);
      s = fdot2f(pk2(b0[6],b0[7]), wl[3], s);
      s = fdot2f(pk2(b1[0],b1[1]), wl[4], s);
      s = fdot2f(pk2(b1[2],b1[3]), wl[5], s);
      s = fdot2f(pk2(b1[4],b1[5]), wl[6], s);
      s = fdot2f(pk2(b1[6],b1[7]), wl[7], s);
      acc[r] = s;
    }
  }
  const float* lb = lqB + c*16;
  float lbv[16];
  #pragma unroll
  for (int i = 0; i < 16; i += 4) {
    float4 t = *(const float4*)(lb + i);
    lbv[i] = t.x; lbv[i+1] = t.y; lbv[i+2] = t.z; lbv[i+3] = t.w;
  }
  #pragma unroll
  for (int r = 0; r < 16; ++r) {
    float dl = 0.f;
    #pragma unroll
    for (int kk = 0; kk < 16; ++kk) dl += t16[(rb+r)*16 + kk] * lbv[kk];
    acc[r] += dl * LORA_SCALE;
  }
  const int h = c >> 4, d = c & 15;
  #pragma unroll
  for (int r = 0; r < 16; ++r) {
    const int grow = row0 + rb + r;
    const int b = grow / 200, m = grow % 200;
    qF[(((size_t)b*8 + h)*200 + m)*16 + d] = (f16)acc[r];
  }
}

// ---------------- k2b: qn[bh][m] = ||qF[bh][m]|| ----------------
__global__ __launch_bounds__(256) void k2b_qnorm(const f16* __restrict__ qF,
    float* __restrict__ qnA)
{
  const int idx = blockIdx.x*256 + threadIdx.x;         // 0..102399
  qnA[idx] = sqrtf(sumsq16(qF + (size_t)idx*16));
}

// ---------------- k3: MFMA attention, n-split halves, partial (O,l) out ----------------
// grid (64,8,2), 512 thr (8 waves). z selects keys [z*512, z*512+512). LDS 32.9KB ->
// 4 blocks/CU = 32 waves/CU. Wave w: m-tiles (w, w+8 or dup 12) dual-fused.
#define VSTRL 516
__global__ __launch_bounds__(512) void k3_attn(const f16* __restrict__ Kp,
    const f16* __restrict__ Vt, const f16* __restrict__ qF,
    const float* __restrict__ mask, const float* __restrict__ kmaxA,
    const float* __restrict__ qnA, f16* __restrict__ Opart,
    float* __restrict__ lpart)
{
  extern __shared__ char smem[];
  f16* Kl = (f16*)smem;                     // [512][16] : 16384 B
  f16* Vl = (f16*)(smem + 16384);           // [16][516] : 16512 B
  const int tid = threadIdx.x;
  const int lane = tid & 63, w = tid >> 6;
  const int b = blockIdx.x, h = blockIdx.y, z = blockIdx.z;
  const int bh = b*8 + h;
  { // stage K half: one row per thread, quad-swizzled
    const int nl = tid;
    const int n = z*512 + nl;
    f16x4 v0{}, v1{}, v2{}, v3{};
    if (n < 1000) {
      const f16x4* src = (const f16x4*)(Kp + (size_t)bh*16000 + n*16);
      v0 = src[0]; v1 = src[1]; v2 = src[2]; v3 = src[3];
    }
    const int sw = (nl >> 2) & 3;
    f16* dst = Kl + nl*16;
    *(f16x4*)(dst + (0^sw)*4) = v0;
    *(f16x4*)(dst + (1^sw)*4) = v1;
    *(f16x4*)(dst + (2^sw)*4) = v2;
    *(f16x4*)(dst + (3^sw)*4) = v3;
  }
  { // stage V half: 16 f16 per thread
    const int d = tid >> 5, c16 = (tid & 31) * 16;
    const f16* srow = Vt + (size_t)bh*16000 + d*1000;
    f16* drow = Vl + d*VSTRL + c16;
    const int nbase = z*512 + c16;
    if (nbase + 15 < 1000) {
      const f16x4* s4 = (const f16x4*)(srow + nbase);
      *(f16x4*)(drow)    = s4[0];
      *(f16x4*)(drow+4)  = s4[1];
      *(f16x4*)(drow+8)  = s4[2];
      *(f16x4*)(drow+12) = s4[3];
    } else {
      for (int j = 0; j < 16; ++j) drow[j] = (nbase+j < 1000) ? srow[nbase+j] : (f16)0;
    }
  }
  __syncthreads();

  const int col = lane & 15, g = lane >> 4, g4 = g*4;
  const int kqoff = (g ^ (col >> 2)) * 4;
  const f32x4 zero = {0.f, 0.f, 0.f, 0.f};
  const int tA = w, tB = (w + 8 < 13) ? (w + 8) : 12;
  const int mA = tA*16, mB = tB*16;
  const int mqA = min(mA + col, 199), mqB = min(mB + col, 199);
  const f16x4 qfA = *(const f16x4*)(qF + (size_t)bh*3200 + mqA*16 + g4);
  const f16x4 qfB = *(const f16x4*)(qF + (size_t)bh*3200 + mqB*16 + g4);
  const float kmx = kmaxA[bh];
  const float mbA = -kmx * qnA[bh*200 + mqA] * 0.360673760f;
  const float mbB = -kmx * qnA[bh*200 + mqB] * 0.360673760f;
  const float* mpA = mask + ((size_t)b*200 + mqA)*1000 + z*512;
  const float* mpB = mask + ((size_t)b*200 + mqB)*1000 + z*512;

  f32x4 OA = zero, OB = zero;
  float lA0=0.f, lA1=0.f, lA2=0.f, lA3=0.f;
  float lB0=0.f, lB1=0.f, lB2=0.f, lB3=0.f;
  const int NTc = 32 - z*2;
  #pragma unroll 2
  for (int t = 0; t < NTc; ++t) {
    const int nl = t*16;
    const f16x4 kf = *(const f16x4*)(Kl + (nl+col)*16 + kqoff);
    f32x4 sA = mfma16(kf, qfA, zero);
    f32x4 sB = mfma16(kf, qfB, zero);
    const float4 mkA = *(const float4*)(mpA + nl + g4);
    const float4 mkB = *(const float4*)(mpB + nl + g4);
    const float pA0 = exp2f(fmaf(sA[0], 0.360673760f, fmaf(mkA.x, L2E, mbA)));
    const float pA1 = exp2f(fmaf(sA[1], 0.360673760f, fmaf(mkA.y, L2E, mbA)));
    const float pA2 = exp2f(fmaf(sA[2], 0.360673760f, fmaf(mkA.z, L2E, mbA)));
    const float pA3 = exp2f(fmaf(sA[3], 0.360673760f, fmaf(mkA.w, L2E, mbA)));
    const float pB0 = exp2f(fmaf(sB[0], 0.360673760f, fmaf(mkB.x, L2E, mbB)));
    const float pB1 = exp2f(fmaf(sB[1], 0.360673760f, fmaf(mkB.y, L2E, mbB)));
    const float pB2 = exp2f(fmaf(sB[2], 0.360673760f, fmaf(mkB.z, L2E, mbB)));
    const float pB3 = exp2f(fmaf(sB[3], 0.360673760f, fmaf(mkB.w, L2E, mbB)));
    lA0 += pA0; lA1 += pA1; lA2 += pA2; lA3 += pA3;
    lB0 += pB0; lB1 += pB1; lB2 += pB2; lB3 += pB3;
    const f16x4 pfA = __builtin_shufflevector(pkrtz(pA0,pA1), pkrtz(pA2,pA3), 0,1,2,3);
    const f16x4 pfB = __builtin_shufflevector(pkrtz(pB0,pB1), pkrtz(pB2,pB3), 0,1,2,3);
    const f16x4 vf = *(const f16x4*)(Vl + col*VSTRL + nl + g4);
    OA = mfma16(vf, pfA, OA);
    OB = mfma16(vf, pfB, OB);
  }
  if (z == 1) { // ragged global tile 62: local rows 480..495, keys valid only g<2
    const int nl = 480;
    const f16x4 kf = *(const f16x4*)(Kl + (nl+col)*16 + kqoff);
    f32x4 sA = mfma16(kf, qfA, zero);
    f32x4 sB = mfma16(kf, qfB, zero);
    float pA0=0.f,pA1=0.f,pA2=0.f,pA3=0.f, pB0=0.f,pB1=0.f,pB2=0.f,pB3=0.f;
    if (g < 2) {
      const float4 mkA = *(const float4*)(mpA + nl + g4);
      const float4 mkB = *(const float4*)(mpB + nl + g4);
      pA0 = exp2f(fmaf(sA[0], 0.360673760f, fmaf(mkA.x, L2E, mbA)));
      pA1 = exp2f(fmaf(sA[1], 0.360673760f, fmaf(mkA.y, L2E, mbA)));
      pA2 = exp2f(fmaf(sA[2], 0.360673760f, fmaf(mkA.z, L2E, mbA)));
      pA3 = exp2f(fmaf(sA[3], 0.360673760f, fmaf(mkA.w, L2E, mbA)));
      pB0 = exp2f(fmaf(sB[0], 0.360673760f, fmaf(mkB.x, L2E, mbB)));
      pB1 = exp2f(fmaf(sB[1], 0.360673760f, fmaf(mkB.y, L2E, mbB)));
      pB2 = exp2f(fmaf(sB[2], 0.360673760f, fmaf(mkB.z, L2E, mbB)));
      pB3 = exp2f(fmaf(sB[3], 0.360673760f, fmaf(mkB.w, L2E, mbB)));
      lA0 += pA0; lA1 += pA1; lA2 += pA2; lA3 += pA3;
      lB0 += pB0; lB1 += pB1; lB2 += pB2; lB3 += pB3;
    }
    const f16x4 pfA = __builtin_shufflevector(pkrtz(pA0,pA1), pkrtz(pA2,pA3), 0,1,2,3);
    const f16x4 pfB = __builtin_shufflevector(pkrtz(pB0,pB1), pkrtz(pB2,pB3), 0,1,2,3);
    const f16x4 vf = *(const f16x4*)(Vl + col*VSTRL + ((g < 2) ? (nl + g4) : 0));
    OA = mfma16(vf, pfA, OA);
    OB = mfma16(vf, pfB, OB);
  }
  float lA = (lA0 + lA1) + (lA2 + lA3);
  float lB = (lB0 + lB1) + (lB2 + lB3);
  lA += __shfl_xor(lA, 16, 64); lA += __shfl_xor(lA, 32, 64);
  lB += __shfl_xor(lB, 16, 64); lB += __shfl_xor(lB, 32, 64);
  const size_t pbase = (size_t)(z*512 + bh)*200;
  if (mA + col < 200) {
    const f16x4 ov = __builtin_shufflevector(pkrtz(OA[0], OA[1]), pkrtz(OA[2], OA[3]), 0,1,2,3);
    *(f16x4*)(Opart + (pbase + mA + col)*16 + g4) = ov;
    if (g == 0) lpart[pbase + mA + col] = lA;
  }
  if (mB + col < 200) {
    const f16x4 ov = __builtin_shufflevector(pkrtz(OB[0], OB[1]), pkrtz(OB[2], OB[3]), 0,1,2,3);
    *(f16x4*)(Opart + (pbase + mB + col)*16 + g4) = ov;
    if (g == 0) lpart[pbase + mB + col] = lB;
  }
}

// ---------------- k3c: combine halves + normalize -> oc ----------------
__global__ __launch_bounds__(256) void k3c_comb(const f16* __restrict__ Opart,
    const float* __restrict__ lpart, f16* __restrict__ ocmh)
{
  const int idx = blockIdx.x*256 + threadIdx.x;         // 0..409599
  const int r = idx >> 2, q = idx & 3;
  const f16x4 o0 = *(const f16x4*)(Opart + (size_t)r*16 + q*4);
  const f16x4 o1 = *(const f16x4*)(Opart + ((size_t)102400 + r)*16 + q*4);
  const float l = lpart[r] + lpart[102400 + r];
  const float inv = 1.f / fmaxf(l, 1e-35f);
  const int bh = r / 200, m = r - bh*200;
  const int b = bh >> 3, hh = bh & 7;
  const float v0 = ((float)o0[0] + (float)o1[0]) * inv;
  const float v1 = ((float)o0[1] + (float)o1[1]) * inv;
  const float v2 = ((float)o0[2] + (float)o1[2]) * inv;
  const float v3 = ((float)o0[3] + (float)o1[3]) * inv;
  const f16x4 o = __builtin_shufflevector(pkrtz(v0, v1), pkrtz(v2, v3), 0, 1, 2, 3);
  *(f16x4*)(ocmh + ((size_t)(b*200 + m)*128) + hh*16 + q*4) = o;
}

// ---------------- k4: mh = oc@Wc^T + bc + LoRA (IN-PLACE oc->mh) ----------------
__global__ __launch_bounds__(256) void k4_comb(const f16* ocF,
    const float* __restrict__ Wc, const float* __restrict__ bc,
    const float* __restrict__ lcA, const float* __restrict__ lcB,
    f16* mhF)
{
  __shared__ f16 ocr[32*128];
  __shared__ float t16[32*16];
  const int tid = threadIdx.x;
  const int row0 = blockIdx.x * 32;
  {
    const f16x8* s1 = (const f16x8*)(ocF + (size_t)row0*128);
    f16x8* d1 = (f16x8*)ocr;
    for (int i = tid; i < 512; i += 256) d1[i] = s1[i];
  }
  __syncthreads();
  for (int idx = tid; idx < 32*16; idx += 256) {
    const int r = idx >> 4, kk = idx & 15;
    const f16x8* lrow = (const f16x8*)(ocr + r*128);
    const float* arow = lcA + kk*128;
    float s = 0.f;
    #pragma unroll
    for (int cc = 0; cc < 16; ++cc) {
      f16x8 a = lrow[cc];
      float4 wa = *(const float4*)(arow + cc*8);
      float4 wb = *(const float4*)(arow + cc*8 + 4);
      s = fdot2f(pk2(a[0],a[1]), pkrtz(wa.x,wa.y), s);
      s = fdot2f(pk2(a[2],a[3]), pkrtz(wa.z,wa.w), s);
      s = fdot2f(pk2(a[4],a[5]), pkrtz(wb.x,wb.y), s);
      s = fdot2f(pk2(a[6],a[7]), pkrtz(wb.z,wb.w), s);
    }
    t16[idx] = s;
  }
  __syncthreads();
  const int c = tid & 127, rg = tid >> 7, rb = rg*16;
  float acc[16];
  const float bias = bc[c];
  #pragma unroll
  for (int r = 0; r < 16; ++r) acc[r] = bias;
  const float* wrow = Wc + c*128;
  for (int c0 = 0; c0 < 128; c0 += 16) {
    float4 w0 = *(const float4*)(wrow + c0);
    float4 w1 = *(const float4*)(wrow + c0 + 4);
    float4 w2 = *(const float4*)(wrow + c0 + 8);
    float4 w3 = *(const float4*)(wrow + c0 + 12);
    f16x2 wv[8] = { pkrtz(w0.x,w0.y), pkrtz(w0.z,w0.w), pkrtz(w1.x,w1.y), pkrtz(w1.z,w1.w),
                    pkrtz(w2.x,w2.y), pkrtz(w2.z,w2.w), pkrtz(w3.x,w3.y), pkrtz(w3.z,w3.w) };
    #pragma unroll
    for (int r = 0; r < 16; ++r) {
      const f16x8* op = (const f16x8*)(ocr + (rb+r)*128 + c0);
      f16x8 a0 = op[0], a1 = op[1];
      float s = acc[r];
      s = fdot2f(pk2(a0[0],a0[1]), wv[0], s);
      s = fdot2f(pk2(a0[2],a0[3]), wv[1], s);
      s = fdot2f(pk2(a0[4],a0[5]), wv[2], s);
      s = fdot2f(pk2(a0[6],a0[7]), wv[3], s);
      s = fdot2f(pk2(a1[0],a1[1]), wv[4], s);
      s = fdot2f(pk2(a1[2],a1[3]), wv[5], s);
      s = fdot2f(pk2(a1[4],a1[5]), wv[6], s);
      s = fdot2f(pk2(a1[6],a1[7]), wv[7], s);
      acc[r] = s;
    }
  }
  const float* lb = lcB + c*16;
  float lbv[16];
  #pragma unroll
  for (int i = 0; i < 16; i += 4) {
    float4 t = *(const float4*)(lb + i);
    lbv[i] = t.x; lbv[i+1] = t.y; lbv[i+2] = t.z; lbv[i+3] = t.w;
  }
  #pragma unroll
  for (int r = 0; r < 16; ++r) {
    float dl = 0.f;
    #pragma unroll
    for (int kk = 0; kk < 16; ++kk) dl += t16[(rb+r)*16 + kk] * lbv[kk];
    acc[r] += dl * LORA_SCALE;
  }
  #pragma unroll
  for (int r = 0; r < 16; ++r) {
    mhF[(size_t)(row0 + rb + r)*128 + c] = (f16)acc[r];
  }
}

// ---------------- k5: MFMA probs = softmax(10*tanh(mh@nodes^T/sqrt(128)) + mask) ----------------
// grid (64, 7), 1024 thr (16 waves). A-frags from nodesT (one contiguous 512B load per
// wave-inst). Output staged through LDS obuf[16][1012] then streamed coalesced
// (1000-thread row copies) -- R14 showed k5's drain was 16-row-scatter stores
// (WRITE 51.5MB @ 0.8 TB/s).
__global__ __launch_bounds__(1024) void k5_final(const f16* __restrict__ mhF,
    const f16* __restrict__ nodesT, const float* __restrict__ mask,
    float* __restrict__ out)
{
  __shared__ float sumsA[16][16];
  __shared__ float sumsB[16][16];
  __shared__ float obuf[16][1012];
  const int tid = threadIdx.x, lane = tid & 63, w = tid >> 6;
  const int b = blockIdx.x, j = blockIdx.y;
  const int col = lane & 15, g = lane >> 4, g4 = g*4;
  const int tmA = 2*j, tmB = min(2*j + 1, 12);
  const int mA = tmA*16 + col, mB = tmB*16 + col;
  const int mqA = min(mA, 199), mqB = min(mB, 199);
  f16x4 bfA[8], bfB[8];
  {
    const f16* a = mhF + (size_t)(b*200 + mqA)*128;
    const f16* bb = mhF + (size_t)(b*200 + mqB)*128;
    #pragma unroll
    for (int kk = 0; kk < 8; ++kk) {
      bfA[kk] = *(const f16x4*)(a + kk*16 + g4);
      bfB[kk] = *(const f16x4*)(bb + kk*16 + g4);
    }
  }
  const float* mrowA = mask + (size_t)(b*200 + mqA)*1000;
  const float* mrowB = mask + (size_t)(b*200 + mqB)*1000;
  const f16* ntb = nodesT + (size_t)b*129024;           // 63*8*256
  f16x4 pfA[4], pfB[4];
  float lsumA = 0.f, lsumB = 0.f;
  #pragma unroll
  for (int i = 0; i < 4; ++i) {
    const int t = w + i*16;
    float pA0 = 0.f, pA1 = 0.f, pA2 = 0.f, pA3 = 0.f;
    float pB0 = 0.f, pB1 = 0.f, pB2 = 0.f, pB3 = 0.f;
    if (t < 63) {
      const f16* na = ntb + (size_t)t*2048;             // 8*256
      f32x4 accA = {0.f, 0.f, 0.f, 0.f};
      f32x4 accB = {0.f, 0.f, 0.f, 0.f};
      #pragma unroll
      for (int kk = 0; kk < 8; ++kk) {
        f16x4 af = *(const f16x4*)(na + kk*256 + lane*4);
        accA = mfma16(af, bfA[kk], accA);
        accB = mfma16(af, bfB[kk], accB);
      }
      const int n0 = t*16 + g4;
      float mkvA[4] = {0.f, 0.f, 0.f, 0.f};
      float mkvB[4] = {0.f, 0.f, 0.f, 0.f};
      if (n0 + 3 < 1000) {
        float4 mkA = *(const float4*)(mrowA + n0);
        float4 mkB = *(const float4*)(mrowB + n0);
        mkvA[0] = mkA.x; mkvA[1] = mkA.y; mkvA[2] = mkA.z; mkvA[3] = mkA.w;
        mkvB[0] = mkB.x; mkvB[1] = mkB.y; mkvB[2] = mkB.z; mkvB[3] = mkB.w;
      }
      float pvA[4], pvB[4];
      #pragma unroll
      for (int r = 0; r < 4; ++r) {
        const bool ok = (n0 + r < 1000);
        float xA = accA[r] * 0.08838834764831845f;      // /sqrt(128)
        float eA = exp2f(xA * 2.8853900817779268f);     // e^{2x}
        float thA = 1.f - 2.f/(eA + 1.f);               // tanh
        float tA0 = exp2f((10.f*thA + mkvA[r]) * L2E);
        pvA[r] = ok ? tA0 : 0.f;
        lsumA += pvA[r];
        float xB = accB[r] * 0.08838834764831845f;
        float eB = exp2f(xB * 2.8853900817779268f);
        float thB = 1.f - 2.f/(eB + 1.f);
        float tB0 = exp2f((10.f*thB + mkvB[r]) * L2E);
        pvB[r] = ok ? tB0 : 0.f;
        lsumB += pvB[r];
      }
      pA0 = pvA[0]; pA1 = pvA[1]; pA2 = pvA[2]; pA3 = pvA[3];
      pB0 = pvB[0]; pB1 = pvB[1]; pB2 = pvB[2]; pB3 = pvB[3];
    }
    pfA[i] = __builtin_shufflevector(pkrtz(pA0, pA1), pkrtz(pA2, pA3), 0, 1, 2, 3);
    pfB[i] = __builtin_shufflevector(pkrtz(pB0, pB1), pkrtz(pB2, pB3), 0, 1, 2, 3);
  }
  lsumA += __shfl_xor(lsumA, 16, 64);
  lsumA += __shfl_xor(lsumA, 32, 64);
  lsumB += __shfl_xor(lsumB, 16, 64);
  lsumB += __shfl_xor(lsumB, 32, 64);
  if (lane < 16) { sumsA[w][lane] = lsumA; sumsB[w][lane] = lsumB; }
  __syncthreads();
  float SA = 0.f, SB = 0.f;
  #pragma unroll
  for (int ww = 0; ww < 16; ++ww) { SA += sumsA[ww][col]; SB += sumsB[ww][col]; }
  const float invA = 1.f / SA;
  const float invB = 1.f / SB;
  // ---- tile A: stage normalized probs to LDS, then coalesced row streams ----
  #pragma unroll
  for (int i = 0; i < 4; ++i) {
    const int t = w + i*16;
    if (t < 63) {
      const f16x4 pv = pfA[i];
      const int n0 = t*16 + g4;
      #pragma unroll
      for (int r = 0; r < 4; ++r) obuf[col][n0 + r] = (float)pv[r]*invA;
    }
  }
  __syncthreads();
  if (tid < 1000) {
    for (int rr = 0; rr < 16; ++rr) {
      const int m = tmA*16 + rr;
      if (m < 200) out[((size_t)b*200 + m)*1000 + tid] = obuf[rr][tid];
    }
  }
  __syncthreads();
  if (tmB != tmA) {
    #pragma unroll
    for (int i = 0; i < 4; ++i) {
      const int t = w + i*16;
      if (t < 63) {
        const f16x4 pv = pfB[i];
        const int n0 = t*16 + g4;
        #pragma unroll
        for (int r = 0; r < 4; ++r) obuf[col][n0 + r] = (float)pv[r]*invB;
      }
    }
    __syncthreads();
    if (tid < 1000) {
      for (int rr = 0; rr < 16; ++rr) {
        const int m = tmB*16 + rr;
        if (m < 200) out[((size_t)b*200 + m)*1000 + tid] = obuf[rr][tid];
      }
    }
  }
}

extern "C" void kernel_launch(void* const* d_in, const int* in_sizes, int n_in,
                              void* d_out, int out_size, void* d_ws, size_t ws_size,
                              hipStream_t stream)
{
  (void)in_sizes; (void)n_in; (void)out_size; (void)ws_size;
  const float* nodes = (const float*)d_in[0];
  const float* q1    = (const float*)d_in[1];
  const float* last  = (const float*)d_in[2];
  const float* mask  = (const float*)d_in[3];
  const float* Wqf   = (const float*)d_in[4];
  const float* Wql   = (const float*)d_in[5];
  const float* Wk    = (const float*)d_in[6];
  const float* Wv    = (const float*)d_in[7];
  const float* Wc    = (const float*)d_in[8];
  const float* bc    = (const float*)d_in[9];
  const float* lqA   = (const float*)d_in[10];
  const float* lqB   = (const float*)d_in[11];
  const float* lcA   = (const float*)d_in[12];
  const float* lcB   = (const float*)d_in[13];
  float* out = (float*)d_out;
  char* ws = (char*)d_ws;
  // ws layout (bytes):
  f16* Kp      = (f16*)(ws + 16384000);    // 16,384,000
  f16* Vt      = (f16*)(ws + 32768000);    // 16,384,000
  f16* qF      = (f16*)(ws + 49152000);    //  3,276,800
  f16* ocmh    = (f16*)(ws + 52428800);    //  3,276,800
  f16* WkvF    = (f16*)(ws + 55705600);    //     65,536
  float* kmaxA = (float*)(ws + 55771136);  //      2,048
  float* qnA   = (float*)(ws + 55773184);  //    409,600
  f16* OpartF  = (f16*)(ws + 56182784);    //  6,553,600
  float* lpart = (float*)(ws + 62736384);  //    819,200  (end 63,555,584)
  f16* nodesT  = (f16*)(ws + 63555584);    // 16,515,072  (end 80,070,656; ws>=90.4MB per R14)

  k0_wconv<<<dim3(32), 256, 0, stream>>>(Wk, Wv, WkvF);
  k1_proj<<<dim3(16, 64), 256, 0, stream>>>(nodes, WkvF, nodesT, Kp, Vt);
  k1b_kmax<<<dim3(512), 256, 0, stream>>>(Kp, kmaxA);
  k2_q<<<dim3(400), 256, 0, stream>>>(q1, last, Wqf, Wql, lqA, lqB, qF);
  k2b_qnorm<<<dim3(400), 256, 0, stream>>>(qF, qnA);
  k3_attn<<<dim3(64, 8, 2), 512, 32896, stream>>>(Kp, Vt, qF, mask, kmaxA, qnA, OpartF, lpart);
  k3c_comb<<<dim3(1600), 256, 0, stream>>>(OpartF, lpart, ocmh);
  k4_comb<<<dim3(400), 256, 0, stream>>>(ocmh, Wc, bc, lcA, lcB, ocmh);
  k5_final<<<dim3(64, 7), 1024, 0, stream>>>(ocmh, nodesT, mask, out);
}

// Round 17
// 188.609 us; speedup vs baseline: 1.1702x; 1.0362x over previous
//
#include <hip/hip_runtime.h>
#include <hip/hip_bf16.h>

// TSP decoder forward: B=64, POMO=200, N=1000, EMB=128, H=8, D=16.
// k1 MFMA K/V proj + nodes->nodesT (weights staged from f32 in-kernel) |
// k2 q (+LoRA) | kb kmax+qnorm | k3 MFMA attention n-split (padded K LDS, f32 row sums) |
// k3c combine | k4 combine (+LoRA, in-place) | k5 MFMA final.

typedef _Float16 f16;
typedef _Float16 f16x2 __attribute__((ext_vector_type(2)));
typedef _Float16 f16x4 __attribute__((ext_vector_type(4)));
typedef _Float16 f16x8 __attribute__((ext_vector_type(8)));
typedef __fp16  h4   __attribute__((ext_vector_type(4)));
typedef float   f32x4 __attribute__((ext_vector_type(4)));

#define LORA_SCALE 1.0f
#define L2E 1.44269504f

__device__ __forceinline__ f16x2 pk2(f16 a, f16 b){ f16x2 r; r[0]=a; r[1]=b; return r; }

#if __has_builtin(__builtin_amdgcn_fdot2)
__device__ __forceinline__ float fdot2f(f16x2 a, f16x2 b, float c){ return __builtin_amdgcn_fdot2(a, b, c, false); }
#else
__device__ __forceinline__ float fdot2f(f16x2 a, f16x2 b, float c){ return c + (float)a[0]*(float)b[0] + (float)a[1]*(float)b[1]; }
#endif

#if __has_builtin(__builtin_amdgcn_cvt_pkrtz)
__device__ __forceinline__ f16x2 pkrtz(float a, float b){
  return __builtin_bit_cast(f16x2, __builtin_amdgcn_cvt_pkrtz(a, b));
}
#else
__device__ __forceinline__ f16x2 pkrtz(float a, float b){ return pk2((f16)a, (f16)b); }
#endif

// D[i][j] = sum_k A[i][k]*B[k][j] + C  via v_mfma_f32_16x16x16_f16.
// A: lane holds row i=(l&15), k=4*(l>>4)+j. B: lane holds col j=(l&15), k=4*(l>>4)+j.
// D: lane holds col j=(l&15), row i=4*(l>>4)+reg.   (validated end-to-end in k3/k5)
__device__ __forceinline__ f32x4 mfma16(f16x4 a, f16x4 b, f32x4 c){
  return __builtin_amdgcn_mfma_f32_16x16x16f16(
      __builtin_bit_cast(h4, a), __builtin_bit_cast(h4, b), c, 0, 0, 0);
}

__device__ __forceinline__ float sumsq16(const f16* p){
  const f16x8* v = (const f16x8*)p;
  f16x8 a = v[0], b = v[1];
  float s = 0.f;
  s = fdot2f(pk2(a[0],a[1]), pk2(a[0],a[1]), s);
  s = fdot2f(pk2(a[2],a[3]), pk2(a[2],a[3]), s);
  s = fdot2f(pk2(a[4],a[5]), pk2(a[4],a[5]), s);
  s = fdot2f(pk2(a[6],a[7]), pk2(a[6],a[7]), s);
  s = fdot2f(pk2(b[0],b[1]), pk2(b[0],b[1]), s);
  s = fdot2f(pk2(b[2],b[3]), pk2(b[2],b[3]), s);
  s = fdot2f(pk2(b[4],b[5]), pk2(b[4],b[5]), s);
  s = fdot2f(pk2(b[6],b[7]), pk2(b[6],b[7]), s);
  return s;
}

// ---------------- k1: MFMA K/V projection + nodes -> nodesT (fragment-tiled) ----------------
// grid (16, 64), 256 thr (4 waves), 64 node rows per block. Weight tiles staged per ct
// straight from f32 Wk/Wv (same pkrtz rounding as the old k0 -> bit-identical).
// nodesT layout: [b][t(63)][kk(8)][lane(64)][r(4)] f16, lane=(g*16+col); tail tile 62
// cols 8..15 filled with row 999 (replicates consumers' min(nr,999) clamp).
#define NSTR 132
#define WSTR 136
__global__ __launch_bounds__(256) void k1_proj(const float* __restrict__ nodes,
    const float* __restrict__ Wk, const float* __restrict__ Wv,
    f16* __restrict__ nodesT, f16* __restrict__ Kp, f16* __restrict__ Vt)
{
  __shared__ f16 lds[64*NSTR];     // 16896 B node tile
  __shared__ f16 wlds[16*WSTR];    //  4352 B weight tile
  const int tid = threadIdx.x, lane = tid & 63, w = tid >> 6;
  const int b = blockIdx.y;
  const int n0 = blockIdx.x * 64;
  const int rows = min(64, 1000 - n0);                  // 64 or 40
  for (int i = tid; i < rows*32; i += 256) {            // 32 f32x4 per row
    const int r = i >> 5, cq = i & 31;
    float4 v = ((const float4*)(nodes + ((size_t)b*1000 + n0 + r)*128))[cq];
    f16x2 lo = pkrtz(v.x,v.y), hi = pkrtz(v.z,v.w);
    f16x4 o = __builtin_shufflevector(lo, hi, 0, 1, 2, 3);
    *(f16x4*)(lds + r*NSTR + cq*4) = o;
    const int grow = n0 + r;
    const int t = grow >> 4, gcol = grow & 15;
    const int kk = cq >> 2, gg = cq & 3;
    f16* dstT = nodesT + (((size_t)(b*63 + t)*8 + kk)*256);
    *(f16x4*)(dstT + (gg*16 + gcol)*4) = o;
    if (grow == 999) {                                   // clamp-fill tile 62 cols 8..15
      f16* d62 = nodesT + (((size_t)(b*63 + 62)*8 + kk)*256);
      #pragma unroll
      for (int cf = 8; cf < 16; ++cf) *(f16x4*)(d62 + (gg*16 + cf)*4) = o;
    }
  }
  __syncthreads();
  const int col = lane & 15, g = lane >> 4, g4 = g*4;
  const int mloc = w*16 + col;
  f16x4 nf[8];
  #pragma unroll
  for (int kk = 0; kk < 8; ++kk)
    nf[kk] = *(const f16x4*)(lds + min(mloc, rows-1)*NSTR + kk*16 + g4);
  const int wr = tid >> 4, wc = tid & 15;
  for (int ct = 0; ct < 16; ++ct) {
    __syncthreads();
    {
      const int r = ct*16 + wr;                          // 0..255 over Wk|Wv
      const float* src = (r < 128) ? (Wk + (size_t)r*128) : (Wv + (size_t)(r-128)*128);
      float4 a = *(const float4*)(src + wc*8);
      float4 bb = *(const float4*)(src + wc*8 + 4);
      *(f16x4*)(wlds + wr*WSTR + wc*8) =
          __builtin_shufflevector(pkrtz(a.x,a.y), pkrtz(a.z,a.w), 0,1,2,3);
      *(f16x4*)(wlds + wr*WSTR + wc*8 + 4) =
          __builtin_shufflevector(pkrtz(bb.x,bb.y), pkrtz(bb.z,bb.w), 0,1,2,3);
    }
    __syncthreads();
    f16x4 wf[8];
    #pragma unroll
    for (int kk = 0; kk < 8; ++kk)
      wf[kk] = *(const f16x4*)(wlds + col*WSTR + kk*16 + g4);
    f32x4 acc = {0.f, 0.f, 0.f, 0.f};
    if (ct < 8) {                                       // K-head ct: D[c][m]
      #pragma unroll
      for (int kk = 0; kk < 8; ++kk) acc = mfma16(wf[kk], nf[kk], acc);
      if (mloc < rows) {
        const int nn = n0 + mloc;
        f16x4 ov = __builtin_shufflevector(pk2((f16)acc[0],(f16)acc[1]),
                                           pk2((f16)acc[2],(f16)acc[3]), 0,1,2,3);
        *(f16x4*)(Kp + ((size_t)(b*8+ct)*1000 + nn)*16 + g4) = ov;
      }
    } else {                                            // V-head ct-8: D[m][c]
      #pragma unroll
      for (int kk = 0; kk < 8; ++kk) acc = mfma16(nf[kk], wf[kk], acc);
      if (w*16 + g4 + 3 < rows) {
        const int nbase = n0 + w*16 + g4;
        f16x4 ov = __builtin_shufflevector(pk2((f16)acc[0],(f16)acc[1]),
                                           pk2((f16)acc[2],(f16)acc[3]), 0,1,2,3);
        *(f16x4*)(Vt + ((size_t)(b*8+(ct-8))*16 + col)*1000 + nbase) = ov;
      }
    }
  }
}

// ---------------- kb: kmax[bh] (blocks 0..511) + qnorm (blocks 512..911) ----------------
__global__ __launch_bounds__(256) void kb_norms(const f16* __restrict__ Kp,
    const f16* __restrict__ qF, float* __restrict__ kmaxA, float* __restrict__ qnA)
{
  if (blockIdx.x < 512) {
    __shared__ float wmax[4];
    const int bh = blockIdx.x, tid = threadIdx.x, lane = tid & 63, w = tid >> 6;
    const f16* base = Kp + (size_t)bh*16000;
    float mx = 0.f;
    for (int n = tid; n < 1000; n += 256) mx = fmaxf(mx, sumsq16(base + n*16));
    #pragma unroll
    for (int off = 32; off; off >>= 1) mx = fmaxf(mx, __shfl_xor(mx, off, 64));
    if (lane == 0) wmax[w] = mx;
    __syncthreads();
    if (tid == 0) {
      float m = fmaxf(fmaxf(wmax[0], wmax[1]), fmaxf(wmax[2], wmax[3]));
      kmaxA[bh] = sqrtf(m);
    }
  } else {
    const int idx = (blockIdx.x - 512)*256 + threadIdx.x;   // 0..102399
    qnA[idx] = sqrtf(sumsq16(qF + (size_t)idx*16));
  }
}

// ---------------- k2: q = q1@Wqf^T + last@Wql^T + LoRA ----------------
__global__ __launch_bounds__(256) void k2_q(const float* __restrict__ q1,
    const float* __restrict__ last, const float* __restrict__ Wqf,
    const float* __restrict__ Wql, const float* __restrict__ lqA,
    const float* __restrict__ lqB, f16* __restrict__ qF)
{
  __shared__ f16 q1r[32*128];
  __shared__ f16 lar[32*128];
  __shared__ float t16[32*16];
  const int tid = threadIdx.x;
  const int row0 = blockIdx.x * 32;
  {
    const float4* s1 = (const float4*)(q1 + (size_t)row0*128);
    const float4* s2 = (const float4*)(last + (size_t)row0*128);
    f16x2* d1 = (f16x2*)q1r; f16x2* d2 = (f16x2*)lar;
    for (int i = tid; i < 32*32; i += 256) {
      float4 v = s1[i];
      d1[2*i] = pkrtz(v.x,v.y); d1[2*i+1] = pkrtz(v.z,v.w);
      float4 u = s2[i];
      d2[2*i] = pkrtz(u.x,u.y); d2[2*i+1] = pkrtz(u.z,u.w);
    }
  }
  __syncthreads();
  for (int idx = tid; idx < 32*16; idx += 256) {
    const int r = idx >> 4, kk = idx & 15;
    const f16x8* lrow = (const f16x8*)(lar + r*128);
    const float* arow = lqA + kk*128;
    float s = 0.f;
    #pragma unroll
    for (int cc = 0; cc < 16; ++cc) {
      f16x8 a = lrow[cc];
      float4 wa = *(const float4*)(arow + cc*8);
      float4 wb = *(const float4*)(arow + cc*8 + 4);
      s = fdot2f(pk2(a[0],a[1]), pkrtz(wa.x,wa.y), s);
      s = fdot2f(pk2(a[2],a[3]), pkrtz(wa.z,wa.w), s);
      s = fdot2f(pk2(a[4],a[5]), pkrtz(wb.x,wb.y), s);
      s = fdot2f(pk2(a[6],a[7]), pkrtz(wb.z,wb.w), s);
    }
    t16[idx] = s;
  }
  __syncthreads();
  const int c = tid & 127, rg = tid >> 7, rb = rg*16;
  float acc[16];
  #pragma unroll
  for (int r = 0; r < 16; ++r) acc[r] = 0.f;
  const float* wfr = Wqf + c*128;
  const float* wlr = Wql + c*128;
  for (int c0 = 0; c0 < 128; c0 += 16) {
    float4 f0 = *(const float4*)(wfr + c0);
    float4 f1 = *(const float4*)(wfr + c0 + 4);
    float4 f2 = *(const float4*)(wfr + c0 + 8);
    float4 f3 = *(const float4*)(wfr + c0 + 12);
    f16x2 wf[8] = { pkrtz(f0.x,f0.y), pkrtz(f0.z,f0.w), pkrtz(f1.x,f1.y), pkrtz(f1.z,f1.w),
                    pkrtz(f2.x,f2.y), pkrtz(f2.z,f2.w), pkrtz(f3.x,f3.y), pkrtz(f3.z,f3.w) };
    float4 g0 = *(const float4*)(wlr + c0);
    float4 g1 = *(const float4*)(wlr + c0 + 4);
    float4 g2 = *(const float4*)(wlr + c0 + 8);
    float4 g3 = *(const float4*)(wlr + c0 + 12);
    f16x2 wl[8] = { pkrtz(g0.x,g0.y), pkrtz(g0.z,g0.w), pkrtz(g1.x,g1.y), pkrtz(g1.z,g1.w),
                    pkrtz(g2.x,g2.y), pkrtz(g2.z,g2.w), pkrtz(g3.x,g3.y), pkrtz(g3.z,g3.w) };
    #pragma unroll
    for (int r = 0; r < 16; ++r) {
      const f16x8* qp = (const f16x8*)(q1r + (rb+r)*128 + c0);
      const f16x8* lp = (const f16x8*)(lar + (rb+r)*128 + c0);
      f16x8 a0 = qp[0], a1 = qp[1], b0 = lp[0], b1 = lp[1];
      float s = acc[r];
      s = fdot2f(pk2(a0[0],a0[1]), wf[0], s);
      s = fdot2f(pk2(a0[2],a0[3]), wf[1], s);
      s = fdot2f(pk2(a0[4],a0[5]), wf[2], s);
      s = fdot2f(pk2(a0[6],a0[7]), wf[3], s);
      s = fdot2f(pk2(a1[0],a1[1]), wf[4], s);
      s = fdot2f(pk2(a1[2],a1[3]), wf[5], s);
      s = fdot2f(pk2(a1[4],a1[5]), wf[6], s);
      s = fdot2f(pk2(a1[6],a1[7]), wf[7], s);
      s = fdot2f(pk2(b0[0],b0[1]), wl[0], s);
      s = fdot2f(pk2(b0[2],b0[3]), wl[1], s);
      s = fdot2f(pk2(b0[4],b0[5]), wl[2], s);
      s = fdot2f(pk2(b0[6],b0[7]), wl[3], s);
      s = fdot2f(pk2(b1[0],b1[1]), wl[4], s);
      s = fdot2f(pk2(b1[2],b1[3]), wl[5], s);
      s = fdot2f(pk2(b1[4],b1[5]), wl[6], s);
      s = fdot2f(pk2(b1[6],b1[7]), wl[7], s);
      acc[r] = s;
    }
  }
  const float* lb = lqB + c*16;
  float lbv[16];
  #pragma unroll
  for (int i = 0; i < 16; i += 4) {
    float4 t = *(const float4*)(lb + i);
    lbv[i] = t.x; lbv[i+1] = t.y; lbv[i+2] = t.z; lbv[i+3] = t.w;
  }
  #pragma unroll
  for (int r = 0; r < 16; ++r) {
    float dl = 0.f;
    #pragma unroll
    for (int kk = 0; kk < 16; ++kk) dl += t16[(rb+r)*16 + kk] * lbv[kk];
    acc[r] += dl * LORA_SCALE;
  }
  const int h = c >> 4, d = c & 15;
  #pragma unroll
  for (int r = 0; r < 16; ++r) {
    const int grow = row0 + rb + r;
    const int b = grow / 200, m = grow % 200;
    qF[(((size_t)b*8 + h)*200 + m)*16 + d] = (f16)acc[r];
  }
}

// ---------------- k3: MFMA attention, n-split halves, partial (O,l) out ----------------
// grid (64,8,2), 512 thr (8 waves). z selects keys [z*512, z*512+512). LDS 37KB ->
// 4 blocks/CU = 32 waves/CU. Wave w: m-tiles (w, w+8 or dup 12) dual-fused.
// K in padded [512][20] layout (R10's low-conflict layout; R11 quad-swizzle was 6x worse).
// Row sums in f32 VALU (R16's ones-MFMA f16 denominator broke accuracy: 5.4e-3 > 4.45e-3).
#define KSTR 20
#define VSTRL 516
__global__ __launch_bounds__(512) void k3_attn(const f16* __restrict__ Kp,
    const f16* __restrict__ Vt, const f16* __restrict__ qF,
    const float* __restrict__ mask, const float* __restrict__ kmaxA,
    const float* __restrict__ qnA, f16* __restrict__ Opart,
    float* __restrict__ lpart)
{
  extern __shared__ char smem[];
  f16* Kl = (f16*)smem;                     // [512][20] : 20480 B
  f16* Vl = (f16*)(smem + 20480);           // [16][516] : 16512 B
  const int tid = threadIdx.x;
  const int lane = tid & 63, w = tid >> 6;
  const int b = blockIdx.x, h = blockIdx.y, z = blockIdx.z;
  const int bh = b*8 + h;
  { // stage K half: one row per thread, padded stride 20
    const int nl = tid;
    const int n = z*512 + nl;
    f16x4 v0{}, v1{}, v2{}, v3{};
    if (n < 1000) {
      const f16x4* src = (const f16x4*)(Kp + (size_t)bh*16000 + n*16);
      v0 = src[0]; v1 = src[1]; v2 = src[2]; v3 = src[3];
    }
    f16* dst = Kl + nl*KSTR;
    *(f16x4*)(dst)    = v0;
    *(f16x4*)(dst+4)  = v1;
    *(f16x4*)(dst+8)  = v2;
    *(f16x4*)(dst+12) = v3;
  }
  { // stage V half: 16 f16 per thread
    const int d = tid >> 5, c16 = (tid & 31) * 16;
    const f16* srow = Vt + (size_t)bh*16000 + d*1000;
    f16* drow = Vl + d*VSTRL + c16;
    const int nbase = z*512 + c16;
    if (nbase + 15 < 1000) {
      const f16x4* s4 = (const f16x4*)(srow + nbase);
      *(f16x4*)(drow)    = s4[0];
      *(f16x4*)(drow+4)  = s4[1];
      *(f16x4*)(drow+8)  = s4[2];
      *(f16x4*)(drow+12) = s4[3];
    } else {
      for (int j = 0; j < 16; ++j) drow[j] = (nbase+j < 1000) ? srow[nbase+j] : (f16)0;
    }
  }
  __syncthreads();

  const int col = lane & 15, g = lane >> 4, g4 = g*4;
  const f32x4 zero = {0.f, 0.f, 0.f, 0.f};
  const int tA = w, tB = (w + 8 < 13) ? (w + 8) : 12;
  const int mA = tA*16, mB = tB*16;
  const int mqA = min(mA + col, 199), mqB = min(mB + col, 199);
  const f16x4 qfA = *(const f16x4*)(qF + (size_t)bh*3200 + mqA*16 + g4);
  const f16x4 qfB = *(const f16x4*)(qF + (size_t)bh*3200 + mqB*16 + g4);
  const float kmx = kmaxA[bh];
  const float mbA = -kmx * qnA[bh*200 + mqA] * 0.360673760f;
  const float mbB = -kmx * qnA[bh*200 + mqB] * 0.360673760f;
  const float* mpA = mask + ((size_t)b*200 + mqA)*1000 + z*512;
  const float* mpB = mask + ((size_t)b*200 + mqB)*1000 + z*512;

  f32x4 OA = zero, OB = zero;
  float lA0=0.f, lA1=0.f, lA2=0.f, lA3=0.f;
  float lB0=0.f, lB1=0.f, lB2=0.f, lB3=0.f;
  const int NTc = 32 - z*2;
  #pragma unroll 4
  for (int t = 0; t < NTc; ++t) {
    const int nl = t*16;
    const f16x4 kf = *(const f16x4*)(Kl + (nl+col)*KSTR + g4);
    f32x4 sA = mfma16(kf, qfA, zero);
    f32x4 sB = mfma16(kf, qfB, zero);
    const float4 mkA = *(const float4*)(mpA + nl + g4);
    const float4 mkB = *(const float4*)(mpB + nl + g4);
    const float pA0 = exp2f(fmaf(sA[0], 0.360673760f, fmaf(mkA.x, L2E, mbA)));
    const float pA1 = exp2f(fmaf(sA[1], 0.360673760f, fmaf(mkA.y, L2E, mbA)));
    const float pA2 = exp2f(fmaf(sA[2], 0.360673760f, fmaf(mkA.z, L2E, mbA)));
    const float pA3 = exp2f(fmaf(sA[3], 0.360673760f, fmaf(mkA.w, L2E, mbA)));
    const float pB0 = exp2f(fmaf(sB[0], 0.360673760f, fmaf(mkB.x, L2E, mbB)));
    const float pB1 = exp2f(fmaf(sB[1], 0.360673760f, fmaf(mkB.y, L2E, mbB)));
    const float pB2 = exp2f(fmaf(sB[2], 0.360673760f, fmaf(mkB.z, L2E, mbB)));
    const float pB3 = exp2f(fmaf(sB[3], 0.360673760f, fmaf(mkB.w, L2E, mbB)));
    lA0 += pA0; lA1 += pA1; lA2 += pA2; lA3 += pA3;
    lB0 += pB0; lB1 += pB1; lB2 += pB2; lB3 += pB3;
    const f16x4 pfA = __builtin_shufflevector(pkrtz(pA0,pA1), pkrtz(pA2,pA3), 0,1,2,3);
    const f16x4 pfB = __builtin_shufflevector(pkrtz(pB0,pB1), pkrtz(pB2,pB3), 0,1,2,3);
    const f16x4 vf = *(const f16x4*)(Vl + col*VSTRL + nl + g4);
    OA = mfma16(vf, pfA, OA);
    OB = mfma16(vf, pfB, OB);
  }
  if (z == 1) { // ragged global tile 62: local rows 480..495, keys valid only g<2
    const int nl = 480;
    const f16x4 kf = *(const f16x4*)(Kl + (nl+col)*KSTR + g4);
    f32x4 sA = mfma16(kf, qfA, zero);
    f32x4 sB = mfma16(kf, qfB, zero);
    float pA0=0.f,pA1=0.f,pA2=0.f,pA3=0.f, pB0=0.f,pB1=0.f,pB2=0.f,pB3=0.f;
    if (g < 2) {
      const float4 mkA = *(const float4*)(mpA + nl + g4);
      const float4 mkB = *(const float4*)(mpB + nl + g4);
      pA0 = exp2f(fmaf(sA[0], 0.360673760f, fmaf(mkA.x, L2E, mbA)));
      pA1 = exp2f(fmaf(sA[1], 0.360673760f, fmaf(mkA.y, L2E, mbA)));
      pA2 = exp2f(fmaf(sA[2], 0.360673760f, fmaf(mkA.z, L2E, mbA)));
      pA3 = exp2f(fmaf(sA[3], 0.360673760f, fmaf(mkA.w, L2E, mbA)));
      pB0 = exp2f(fmaf(sB[0], 0.360673760f, fmaf(mkB.x, L2E, mbB)));
      pB1 = exp2f(fmaf(sB[1], 0.360673760f, fmaf(mkB.y, L2E, mbB)));
      pB2 = exp2f(fmaf(sB[2], 0.360673760f, fmaf(mkB.z, L2E, mbB)));
      pB3 = exp2f(fmaf(sB[3], 0.360673760f, fmaf(mkB.w, L2E, mbB)));
      lA0 += pA0; lA1 += pA1; lA2 += pA2; lA3 += pA3;
      lB0 += pB0; lB1 += pB1; lB2 += pB2; lB3 += pB3;
    }
    const f16x4 pfA = __builtin_shufflevector(pkrtz(pA0,pA1), pkrtz(pA2,pA3), 0,1,2,3);
    const f16x4 pfB = __builtin_shufflevector(pkrtz(pB0,pB1), pkrtz(pB2,pB3), 0,1,2,3);
    const f16x4 vf = *(const f16x4*)(Vl + col*VSTRL + ((g < 2) ? (nl + g4) : 0));
    OA = mfma16(vf, pfA, OA);
    OB = mfma16(vf, pfB, OB);
  }
  float lA = (lA0 + lA1) + (lA2 + lA3);
  float lB = (lB0 + lB1) + (lB2 + lB3);
  lA += __shfl_xor(lA, 16, 64); lA += __shfl_xor(lA, 32, 64);
  lB += __shfl_xor(lB, 16, 64); lB += __shfl_xor(lB, 32, 64);
  const size_t pbase = (size_t)(z*512 + bh)*200;
  if (mA + col < 200) {
    const f16x4 ov = __builtin_shufflevector(pkrtz(OA[0], OA[1]), pkrtz(OA[2], OA[3]), 0,1,2,3);
    *(f16x4*)(Opart + (pbase + mA + col)*16 + g4) = ov;
    if (g == 0) lpart[pbase + mA + col] = lA;
  }
  if (mB + col < 200) {
    const f16x4 ov = __builtin_shufflevector(pkrtz(OB[0], OB[1]), pkrtz(OB[2], OB[3]), 0,1,2,3);
    *(f16x4*)(Opart + (pbase + mB + col)*16 + g4) = ov;
    if (g == 0) lpart[pbase + mB + col] = lB;
  }
}

// ---------------- k3c: combine halves + normalize -> oc ----------------
__global__ __launch_bounds__(256) void k3c_comb(const f16* __restrict__ Opart,
    const float* __restrict__ lpart, f16* __restrict__ ocmh)
{
  const int idx = blockIdx.x*256 + threadIdx.x;         // 0..409599
  const int r = idx >> 2, q = idx & 3;
  const f16x4 o0 = *(const f16x4*)(Opart + (size_t)r*16 + q*4);
  const f16x4 o1 = *(const f16x4*)(Opart + ((size_t)102400 + r)*16 + q*4);
  const float l = lpart[r] + lpart[102400 + r];
  const float inv = 1.f / fmaxf(l, 1e-35f);
  const int bh = r / 200, m = r - bh*200;
  const int b = bh >> 3, hh = bh & 7;
  const float v0 = ((float)o0[0] + (float)o1[0]) * inv;
  const float v1 = ((float)o0[1] + (float)o1[1]) * inv;
  const float v2 = ((float)o0[2] + (float)o1[2]) * inv;
  const float v3 = ((float)o0[3] + (float)o1[3]) * inv;
  const f16x4 o = __builtin_shufflevector(pkrtz(v0, v1), pkrtz(v2, v3), 0, 1, 2, 3);
  *(f16x4*)(ocmh + ((size_t)(b*200 + m)*128) + hh*16 + q*4) = o;
}

// ---------------- k4: mh = oc@Wc^T + bc + LoRA (IN-PLACE oc->mh) ----------------
__global__ __launch_bounds__(256) void k4_comb(const f16* ocF,
    const float* __restrict__ Wc, const float* __restrict__ bc,
    const float* __restrict__ lcA, const float* __restrict__ lcB,
    f16* mhF)
{
  __shared__ f16 ocr[32*128];
  __shared__ float t16[32*16];
  const int tid = threadIdx.x;
  const int row0 = blockIdx.x * 32;
  {
    const f16x8* s1 = (const f16x8*)(ocF + (size_t)row0*128);
    f16x8* d1 = (f16x8*)ocr;
    for (int i = tid; i < 512; i += 256) d1[i] = s1[i];
  }
  __syncthreads();
  for (int idx = tid; idx < 32*16; idx += 256) {
    const int r = idx >> 4, kk = idx & 15;
    const f16x8* lrow = (const f16x8*)(ocr + r*128);
    const float* arow = lcA + kk*128;
    float s = 0.f;
    #pragma unroll
    for (int cc = 0; cc < 16; ++cc) {
      f16x8 a = lrow[cc];
      float4 wa = *(const float4*)(arow + cc*8);
      float4 wb = *(const float4*)(arow + cc*8 + 4);
      s = fdot2f(pk2(a[0],a[1]), pkrtz(wa.x,wa.y), s);
      s = fdot2f(pk2(a[2],a[3]), pkrtz(wa.z,wa.w), s);
      s = fdot2f(pk2(a[4],a[5]), pkrtz(wb.x,wb.y), s);
      s = fdot2f(pk2(a[6],a[7]), pkrtz(wb.z,wb.w), s);
    }
    t16[idx] = s;
  }
  __syncthreads();
  const int c = tid & 127, rg = tid >> 7, rb = rg*16;
  float acc[16];
  const float bias = bc[c];
  #pragma unroll
  for (int r = 0; r < 16; ++r) acc[r] = bias;
  const float* wrow = Wc + c*128;
  for (int c0 = 0; c0 < 128; c0 += 16) {
    float4 w0 = *(const float4*)(wrow + c0);
    float4 w1 = *(const float4*)(wrow + c0 + 4);
    float4 w2 = *(const float4*)(wrow + c0 + 8);
    float4 w3 = *(const float4*)(wrow + c0 + 12);
    f16x2 wv[8] = { pkrtz(w0.x,w0.y), pkrtz(w0.z,w0.w), pkrtz(w1.x,w1.y), pkrtz(w1.z,w1.w),
                    pkrtz(w2.x,w2.y), pkrtz(w2.z,w2.w), pkrtz(w3.x,w3.y), pkrtz(w3.z,w3.w) };
    #pragma unroll
    for (int r = 0; r < 16; ++r) {
      const f16x8* op = (const f16x8*)(ocr + (rb+r)*128 + c0);
      f16x8 a0 = op[0], a1 = op[1];
      float s = acc[r];
      s = fdot2f(pk2(a0[0],a0[1]), wv[0], s);
      s = fdot2f(pk2(a0[2],a0[3]), wv[1], s);
      s = fdot2f(pk2(a0[4],a0[5]), wv[2], s);
      s = fdot2f(pk2(a0[6],a0[7]), wv[3], s);
      s = fdot2f(pk2(a1[0],a1[1]), wv[4], s);
      s = fdot2f(pk2(a1[2],a1[3]), wv[5], s);
      s = fdot2f(pk2(a1[4],a1[5]), wv[6], s);
      s = fdot2f(pk2(a1[6],a1[7]), wv[7], s);
      acc[r] = s;
    }
  }
  const float* lb = lcB + c*16;
  float lbv[16];
  #pragma unroll
  for (int i = 0; i < 16; i += 4) {
    float4 t = *(const float4*)(lb + i);
    lbv[i] = t.x; lbv[i+1] = t.y; lbv[i+2] = t.z; lbv[i+3] = t.w;
  }
  #pragma unroll
  for (int r = 0; r < 16; ++r) {
    float dl = 0.f;
    #pragma unroll
    for (int kk = 0; kk < 16; ++kk) dl += t16[(rb+r)*16 + kk] * lbv[kk];
    acc[r] += dl * LORA_SCALE;
  }
  #pragma unroll
  for (int r = 0; r < 16; ++r) {
    mhF[(size_t)(row0 + rb + r)*128 + c] = (f16)acc[r];
  }
}

// ---------------- k5: MFMA probs = softmax(10*tanh(mh@nodes^T/sqrt(128)) + mask) ----------------
// grid (64, 7), 1024 thr (16 waves). A-frags from nodesT (contiguous 512B wave-loads),
// output staged through LDS then streamed coalesced.
__global__ __launch_bounds__(1024) void k5_final(const f16* __restrict__ mhF,
    const f16* __restrict__ nodesT, const float* __restrict__ mask,
    float* __restrict__ out)
{
  __shared__ float sumsA[16][16];
  __shared__ float sumsB[16][16];
  __shared__ float obuf[16][1012];
  const int tid = threadIdx.x, lane = tid & 63, w = tid >> 6;
  const int b = blockIdx.x, j = blockIdx.y;
  const int col = lane & 15, g = lane >> 4, g4 = g*4;
  const int tmA = 2*j, tmB = min(2*j + 1, 12);
  const int mA = tmA*16 + col, mB = tmB*16 + col;
  const int mqA = min(mA, 199), mqB = min(mB, 199);
  f16x4 bfA[8], bfB[8];
  {
    const f16* a = mhF + (size_t)(b*200 + mqA)*128;
    const f16* bb = mhF + (size_t)(b*200 + mqB)*128;
    #pragma unroll
    for (int kk = 0; kk < 8; ++kk) {
      bfA[kk] = *(const f16x4*)(a + kk*16 + g4);
      bfB[kk] = *(const f16x4*)(bb + kk*16 + g4);
    }
  }
  const float* mrowA = mask + (size_t)(b*200 + mqA)*1000;
  const float* mrowB = mask + (size_t)(b*200 + mqB)*1000;
  const f16* ntb = nodesT + (size_t)b*129024;           // 63*8*256
  f16x4 pfA[4], pfB[4];
  float lsumA = 0.f, lsumB = 0.f;
  #pragma unroll
  for (int i = 0; i < 4; ++i) {
    const int t = w + i*16;
    float pA0 = 0.f, pA1 = 0.f, pA2 = 0.f, pA3 = 0.f;
    float pB0 = 0.f, pB1 = 0.f, pB2 = 0.f, pB3 = 0.f;
    if (t < 63) {
      const f16* na = ntb + (size_t)t*2048;             // 8*256
      f32x4 accA = {0.f, 0.f, 0.f, 0.f};
      f32x4 accB = {0.f, 0.f, 0.f, 0.f};
      #pragma unroll
      for (int kk = 0; kk < 8; ++kk) {
        f16x4 af = *(const f16x4*)(na + kk*256 + lane*4);
        accA = mfma16(af, bfA[kk], accA);
        accB = mfma16(af, bfB[kk], accB);
      }
      const int n0 = t*16 + g4;
      float mkvA[4] = {0.f, 0.f, 0.f, 0.f};
      float mkvB[4] = {0.f, 0.f, 0.f, 0.f};
      if (n0 + 3 < 1000) {
        float4 mkA = *(const float4*)(mrowA + n0);
        float4 mkB = *(const float4*)(mrowB + n0);
        mkvA[0] = mkA.x; mkvA[1] = mkA.y; mkvA[2] = mkA.z; mkvA[3] = mkA.w;
        mkvB[0] = mkB.x; mkvB[1] = mkB.y; mkvB[2] = mkB.z; mkvB[3] = mkB.w;
      }
      float pvA[4], pvB[4];
      #pragma unroll
      for (int r = 0; r < 4; ++r) {
        const bool ok = (n0 + r < 1000);
        float xA = accA[r] * 0.08838834764831845f;      // /sqrt(128)
        float eA = exp2f(xA * 2.8853900817779268f);     // e^{2x}
        float thA = 1.f - 2.f/(eA + 1.f);               // tanh
        float tA0 = exp2f((10.f*thA + mkvA[r]) * L2E);
        pvA[r] = ok ? tA0 : 0.f;
        lsumA += pvA[r];
        float xB = accB[r] * 0.08838834764831845f;
        float eB = exp2f(xB * 2.8853900817779268f);
        float thB = 1.f - 2.f/(eB + 1.f);
        float tB0 = exp2f((10.f*thB + mkvB[r]) * L2E);
        pvB[r] = ok ? tB0 : 0.f;
        lsumB += pvB[r];
      }
      pA0 = pvA[0]; pA1 = pvA[1]; pA2 = pvA[2]; pA3 = pvA[3];
      pB0 = pvB[0]; pB1 = pvB[1]; pB2 = pvB[2]; pB3 = pvB[3];
    }
    pfA[i] = __builtin_shufflevector(pkrtz(pA0, pA1), pkrtz(pA2, pA3), 0, 1, 2, 3);
    pfB[i] = __builtin_shufflevector(pkrtz(pB0, pB1), pkrtz(pB2, pB3), 0, 1, 2, 3);
  }
  lsumA += __shfl_xor(lsumA, 16, 64);
  lsumA += __shfl_xor(lsumA, 32, 64);
  lsumB += __shfl_xor(lsumB, 16, 64);
  lsumB += __shfl_xor(lsumB, 32, 64);
  if (lane < 16) { sumsA[w][lane] = lsumA; sumsB[w][lane] = lsumB; }
  __syncthreads();
  float SA = 0.f, SB = 0.f;
  #pragma unroll
  for (int ww = 0; ww < 16; ++ww) { SA += sumsA[ww][col]; SB += sumsB[ww][col]; }
  const float invA = 1.f / SA;
  const float invB = 1.f / SB;
  // ---- tile A: stage normalized probs to LDS, then coalesced row streams ----
  #pragma unroll
  for (int i = 0; i < 4; ++i) {
    const int t = w + i*16;
    if (t < 63) {
      const f16x4 pv = pfA[i];
      const int n0 = t*16 + g4;
      #pragma unroll
      for (int r = 0; r < 4; ++r) obuf[col][n0 + r] = (float)pv[r]*invA;
    }
  }
  __syncthreads();
  if (tid < 1000) {
    for (int rr = 0; rr < 16; ++rr) {
      const int m = tmA*16 + rr;
      if (m < 200) out[((size_t)b*200 + m)*1000 + tid] = obuf[rr][tid];
    }
  }
  __syncthreads();
  if (tmB != tmA) {
    #pragma unroll
    for (int i = 0; i < 4; ++i) {
      const int t = w + i*16;
      if (t < 63) {
        const f16x4 pv = pfB[i];
        const int n0 = t*16 + g4;
        #pragma unroll
        for (int r = 0; r < 4; ++r) obuf[col][n0 + r] = (float)pv[r]*invB;
      }
    }
    __syncthreads();
    if (tid < 1000) {
      for (int rr = 0; rr < 16; ++rr) {
        const int m = tmB*16 + rr;
        if (m < 200) out[((size_t)b*200 + m)*1000 + tid] = obuf[rr][tid];
      }
    }
  }
}

extern "C" void kernel_launch(void* const* d_in, const int* in_sizes, int n_in,
                              void* d_out, int out_size, void* d_ws, size_t ws_size,
                              hipStream_t stream)
{
  (void)in_sizes; (void)n_in; (void)out_size; (void)ws_size;
  const float* nodes = (const float*)d_in[0];
  const float* q1    = (const float*)d_in[1];
  const float* last  = (const float*)d_in[2];
  const float* mask  = (const float*)d_in[3];
  const float* Wqf   = (const float*)d_in[4];
  const float* Wql   = (const float*)d_in[5];
  const float* Wk    = (const float*)d_in[6];
  const float* Wv    = (const float*)d_in[7];
  const float* Wc    = (const float*)d_in[8];
  const float* bc    = (const float*)d_in[9];
  const float* lqA   = (const float*)d_in[10];
  const float* lqB   = (const float*)d_in[11];
  const float* lcA   = (const float*)d_in[12];
  const float* lcB   = (const float*)d_in[13];
  float* out = (float*)d_out;
  char* ws = (char*)d_ws;
  // ws layout (bytes):
  f16* Kp      = (f16*)(ws + 16384000);    // 16,384,000
  f16* Vt      = (f16*)(ws + 32768000);    // 16,384,000
  f16* qF      = (f16*)(ws + 49152000);    //  3,276,800
  f16* ocmh    = (f16*)(ws + 52428800);    //  3,276,800
  float* kmaxA = (float*)(ws + 55771136);  //      2,048
  float* qnA   = (float*)(ws + 55773184);  //    409,600
  f16* OpartF  = (f16*)(ws + 56182784);    //  6,553,600
  float* lpart = (float*)(ws + 62736384);  //    819,200  (end 63,555,584)
  f16* nodesT  = (f16*)(ws + 63555584);    // 16,515,072  (end 80,070,656)

  k1_proj<<<dim3(16, 64), 256, 0, stream>>>(nodes, Wk, Wv, nodesT, Kp, Vt);
  k2_q<<<dim3(400), 256, 0, stream>>>(q1, last, Wqf, Wql, lqA, lqB, qF);
  kb_norms<<<dim3(912), 256, 0, stream>>>(Kp, qF, kmaxA, qnA);
  k3_attn<<<dim3(64, 8, 2), 512, 36992, stream>>>(Kp, Vt, qF, mask, kmaxA, qnA, OpartF, lpart);
  k3c_comb<<<dim3(1600), 256, 0, stream>>>(OpartF, lpart, ocmh);
  k4_comb<<<dim3(400), 256, 0, stream>>>(ocmh, Wc, bc, lcA, lcB, ocmh);
  k5_final<<<dim3(64, 7), 1024, 0, stream>>>(ocmh, nodesT, mask, out);
}

// Round 18
// 182.447 us; speedup vs baseline: 1.2097x; 1.0338x over previous
//
#include <hip/hip_runtime.h>
#include <hip/hip_bf16.h>

// TSP decoder forward: B=64, POMO=200, N=1000, EMB=128, H=8, D=16.
// k1 MFMA K/V proj + nodes->nodesT | k2 q (+LoRA) | kb kmax+qnorm |
// k3 MFMA attention n-split (no redundant tile-12 work) |
// k4 combine partials + Wc GEMM (+LoRA) fused | k5 MFMA final.

typedef _Float16 f16;
typedef _Float16 f16x2 __attribute__((ext_vector_type(2)));
typedef _Float16 f16x4 __attribute__((ext_vector_type(4)));
typedef _Float16 f16x8 __attribute__((ext_vector_type(8)));
typedef __fp16  h4   __attribute__((ext_vector_type(4)));
typedef float   f32x4 __attribute__((ext_vector_type(4)));

#define LORA_SCALE 1.0f
#define L2E 1.44269504f

__device__ __forceinline__ f16x2 pk2(f16 a, f16 b){ f16x2 r; r[0]=a; r[1]=b; return r; }

#if __has_builtin(__builtin_amdgcn_fdot2)
__device__ __forceinline__ float fdot2f(f16x2 a, f16x2 b, float c){ return __builtin_amdgcn_fdot2(a, b, c, false); }
#else
__device__ __forceinline__ float fdot2f(f16x2 a, f16x2 b, float c){ return c + (float)a[0]*(float)b[0] + (float)a[1]*(float)b[1]; }
#endif

#if __has_builtin(__builtin_amdgcn_cvt_pkrtz)
__device__ __forceinline__ f16x2 pkrtz(float a, float b){
  return __builtin_bit_cast(f16x2, __builtin_amdgcn_cvt_pkrtz(a, b));
}
#else
__device__ __forceinline__ f16x2 pkrtz(float a, float b){ return pk2((f16)a, (f16)b); }
#endif

// D[i][j] = sum_k A[i][k]*B[k][j] + C  via v_mfma_f32_16x16x16_f16.
// A: lane holds row i=(l&15), k=4*(l>>4)+j. B: lane holds col j=(l&15), k=4*(l>>4)+j.
// D: lane holds col j=(l&15), row i=4*(l>>4)+reg.   (validated end-to-end in k3/k5)
__device__ __forceinline__ f32x4 mfma16(f16x4 a, f16x4 b, f32x4 c){
  return __builtin_amdgcn_mfma_f32_16x16x16f16(
      __builtin_bit_cast(h4, a), __builtin_bit_cast(h4, b), c, 0, 0, 0);
}

__device__ __forceinline__ float sumsq16(const f16* p){
  const f16x8* v = (const f16x8*)p;
  f16x8 a = v[0], b = v[1];
  float s = 0.f;
  s = fdot2f(pk2(a[0],a[1]), pk2(a[0],a[1]), s);
  s = fdot2f(pk2(a[2],a[3]), pk2(a[2],a[3]), s);
  s = fdot2f(pk2(a[4],a[5]), pk2(a[4],a[5]), s);
  s = fdot2f(pk2(a[6],a[7]), pk2(a[6],a[7]), s);
  s = fdot2f(pk2(b[0],b[1]), pk2(b[0],b[1]), s);
  s = fdot2f(pk2(b[2],b[3]), pk2(b[2],b[3]), s);
  s = fdot2f(pk2(b[4],b[5]), pk2(b[4],b[5]), s);
  s = fdot2f(pk2(b[6],b[7]), pk2(b[6],b[7]), s);
  return s;
}

// ---------------- k1: MFMA K/V projection + nodes -> nodesT (fragment-tiled) ----------------
#define NSTR 132
#define WSTR 136
__global__ __launch_bounds__(256) void k1_proj(const float* __restrict__ nodes,
    const float* __restrict__ Wk, const float* __restrict__ Wv,
    f16* __restrict__ nodesT, f16* __restrict__ Kp, f16* __restrict__ Vt)
{
  __shared__ f16 lds[64*NSTR];     // 16896 B node tile
  __shared__ f16 wlds[16*WSTR];    //  4352 B weight tile
  const int tid = threadIdx.x, lane = tid & 63, w = tid >> 6;
  const int b = blockIdx.y;
  const int n0 = blockIdx.x * 64;
  const int rows = min(64, 1000 - n0);                  // 64 or 40
  for (int i = tid; i < rows*32; i += 256) {            // 32 f32x4 per row
    const int r = i >> 5, cq = i & 31;
    float4 v = ((const float4*)(nodes + ((size_t)b*1000 + n0 + r)*128))[cq];
    f16x2 lo = pkrtz(v.x,v.y), hi = pkrtz(v.z,v.w);
    f16x4 o = __builtin_shufflevector(lo, hi, 0, 1, 2, 3);
    *(f16x4*)(lds + r*NSTR + cq*4) = o;
    const int grow = n0 + r;
    const int t = grow >> 4, gcol = grow & 15;
    const int kk = cq >> 2, gg = cq & 3;
    f16* dstT = nodesT + (((size_t)(b*63 + t)*8 + kk)*256);
    *(f16x4*)(dstT + (gg*16 + gcol)*4) = o;
    if (grow == 999) {                                   // clamp-fill tile 62 cols 8..15
      f16* d62 = nodesT + (((size_t)(b*63 + 62)*8 + kk)*256);
      #pragma unroll
      for (int cf = 8; cf < 16; ++cf) *(f16x4*)(d62 + (gg*16 + cf)*4) = o;
    }
  }
  __syncthreads();
  const int col = lane & 15, g = lane >> 4, g4 = g*4;
  const int mloc = w*16 + col;
  f16x4 nf[8];
  #pragma unroll
  for (int kk = 0; kk < 8; ++kk)
    nf[kk] = *(const f16x4*)(lds + min(mloc, rows-1)*NSTR + kk*16 + g4);
  const int wr = tid >> 4, wc = tid & 15;
  for (int ct = 0; ct < 16; ++ct) {
    __syncthreads();
    {
      const int r = ct*16 + wr;                          // 0..255 over Wk|Wv
      const float* src = (r < 128) ? (Wk + (size_t)r*128) : (Wv + (size_t)(r-128)*128);
      float4 a = *(const float4*)(src + wc*8);
      float4 bb = *(const float4*)(src + wc*8 + 4);
      *(f16x4*)(wlds + wr*WSTR + wc*8) =
          __builtin_shufflevector(pkrtz(a.x,a.y), pkrtz(a.z,a.w), 0,1,2,3);
      *(f16x4*)(wlds + wr*WSTR + wc*8 + 4) =
          __builtin_shufflevector(pkrtz(bb.x,bb.y), pkrtz(bb.z,bb.w), 0,1,2,3);
    }
    __syncthreads();
    f16x4 wf[8];
    #pragma unroll
    for (int kk = 0; kk < 8; ++kk)
      wf[kk] = *(const f16x4*)(wlds + col*WSTR + kk*16 + g4);
    f32x4 acc = {0.f, 0.f, 0.f, 0.f};
    if (ct < 8) {                                       // K-head ct: D[c][m]
      #pragma unroll
      for (int kk = 0; kk < 8; ++kk) acc = mfma16(wf[kk], nf[kk], acc);
      if (mloc < rows) {
        const int nn = n0 + mloc;
        f16x4 ov = __builtin_shufflevector(pk2((f16)acc[0],(f16)acc[1]),
                                           pk2((f16)acc[2],(f16)acc[3]), 0,1,2,3);
        *(f16x4*)(Kp + ((size_t)(b*8+ct)*1000 + nn)*16 + g4) = ov;
      }
    } else {                                            // V-head ct-8: D[m][c]
      #pragma unroll
      for (int kk = 0; kk < 8; ++kk) acc = mfma16(nf[kk], wf[kk], acc);
      if (w*16 + g4 + 3 < rows) {
        const int nbase = n0 + w*16 + g4;
        f16x4 ov = __builtin_shufflevector(pk2((f16)acc[0],(f16)acc[1]),
                                           pk2((f16)acc[2],(f16)acc[3]), 0,1,2,3);
        *(f16x4*)(Vt + ((size_t)(b*8+(ct-8))*16 + col)*1000 + nbase) = ov;
      }
    }
  }
}

// ---------------- kb: kmax[bh] (blocks 0..511) + qnorm (blocks 512..911) ----------------
__global__ __launch_bounds__(256) void kb_norms(const f16* __restrict__ Kp,
    const f16* __restrict__ qF, float* __restrict__ kmaxA, float* __restrict__ qnA)
{
  if (blockIdx.x < 512) {
    __shared__ float wmax[4];
    const int bh = blockIdx.x, tid = threadIdx.x, lane = tid & 63, w = tid >> 6;
    const f16* base = Kp + (size_t)bh*16000;
    float mx = 0.f;
    for (int n = tid; n < 1000; n += 256) mx = fmaxf(mx, sumsq16(base + n*16));
    #pragma unroll
    for (int off = 32; off; off >>= 1) mx = fmaxf(mx, __shfl_xor(mx, off, 64));
    if (lane == 0) wmax[w] = mx;
    __syncthreads();
    if (tid == 0) {
      float m = fmaxf(fmaxf(wmax[0], wmax[1]), fmaxf(wmax[2], wmax[3]));
      kmaxA[bh] = sqrtf(m);
    }
  } else {
    const int idx = (blockIdx.x - 512)*256 + threadIdx.x;   // 0..102399
    qnA[idx] = sqrtf(sumsq16(qF + (size_t)idx*16));
  }
}

// ---------------- k2: q = q1@Wqf^T + last@Wql^T + LoRA ----------------
__global__ __launch_bounds__(256) void k2_q(const float* __restrict__ q1,
    const float* __restrict__ last, const float* __restrict__ Wqf,
    const float* __restrict__ Wql, const float* __restrict__ lqA,
    const float* __restrict__ lqB, f16* __restrict__ qF)
{
  __shared__ f16 q1r[32*128];
  __shared__ f16 lar[32*128];
  __shared__ float t16[32*16];
  const int tid = threadIdx.x;
  const int row0 = blockIdx.x * 32;
  {
    const float4* s1 = (const float4*)(q1 + (size_t)row0*128);
    const float4* s2 = (const float4*)(last + (size_t)row0*128);
    f16x2* d1 = (f16x2*)q1r; f16x2* d2 = (f16x2*)lar;
    for (int i = tid; i < 32*32; i += 256) {
      float4 v = s1[i];
      d1[2*i] = pkrtz(v.x,v.y); d1[2*i+1] = pkrtz(v.z,v.w);
      float4 u = s2[i];
      d2[2*i] = pkrtz(u.x,u.y); d2[2*i+1] = pkrtz(u.z,u.w);
    }
  }
  __syncthreads();
  for (int idx = tid; idx < 32*16; idx += 256) {
    const int r = idx >> 4, kk = idx & 15;
    const f16x8* lrow = (const f16x8*)(lar + r*128);
    const float* arow = lqA + kk*128;
    float s = 0.f;
    #pragma unroll
    for (int cc = 0; cc < 16; ++cc) {
      f16x8 a = lrow[cc];
      float4 wa = *(const float4*)(arow + cc*8);
      float4 wb = *(const float4*)(arow + cc*8 + 4);
      s = fdot2f(pk2(a[0],a[1]), pkrtz(wa.x,wa.y), s);
      s = fdot2f(pk2(a[2],a[3]), pkrtz(wa.z,wa.w), s);
      s = fdot2f(pk2(a[4],a[5]), pkrtz(wb.x,wb.y), s);
      s = fdot2f(pk2(a[6],a[7]), pkrtz(wb.z,wb.w), s);
    }
    t16[idx] = s;
  }
  __syncthreads();
  const int c = tid & 127, rg = tid >> 7, rb = rg*16;
  float acc[16];
  #pragma unroll
  for (int r = 0; r < 16; ++r) acc[r] = 0.f;
  const float* wfr = Wqf + c*128;
  const float* wlr = Wql + c*128;
  for (int c0 = 0; c0 < 128; c0 += 16) {
    float4 f0 = *(const float4*)(wfr + c0);
    float4 f1 = *(const float4*)(wfr + c0 + 4);
    float4 f2 = *(const float4*)(wfr + c0 + 8);
    float4 f3 = *(const float4*)(wfr + c0 + 12);
    f16x2 wf[8] = { pkrtz(f0.x,f0.y), pkrtz(f0.z,f0.w), pkrtz(f1.x,f1.y), pkrtz(f1.z,f1.w),
                    pkrtz(f2.x,f2.y), pkrtz(f2.z,f2.w), pkrtz(f3.x,f3.y), pkrtz(f3.z,f3.w) };
    float4 g0 = *(const float4*)(wlr + c0);
    float4 g1 = *(const float4*)(wlr + c0 + 4);
    float4 g2 = *(const float4*)(wlr + c0 + 8);
    float4 g3 = *(const float4*)(wlr + c0 + 12);
    f16x2 wl[8] = { pkrtz(g0.x,g0.y), pkrtz(g0.z,g0.w), pkrtz(g1.x,g1.y), pkrtz(g1.z,g1.w),
                    pkrtz(g2.x,g2.y), pkrtz(g2.z,g2.w), pkrtz(g3.x,g3.y), pkrtz(g3.z,g3.w) };
    #pragma unroll
    for (int r = 0; r < 16; ++r) {
      const f16x8* qp = (const f16x8*)(q1r + (rb+r)*128 + c0);
      const f16x8* lp = (const f16x8*)(lar + (rb+r)*128 + c0);
      f16x8 a0 = qp[0], a1 = qp[1], b0 = lp[0], b1 = lp[1];
      float s = acc[r];
      s = fdot2f(pk2(a0[0],a0[1]), wf[0], s);
      s = fdot2f(pk2(a0[2],a0[3]), wf[1], s);
      s = fdot2f(pk2(a0[4],a0[5]), wf[2], s);
      s = fdot2f(pk2(a0[6],a0[7]), wf[3], s);
      s = fdot2f(pk2(a1[0],a1[1]), wf[4], s);
      s = fdot2f(pk2(a1[2],a1[3]), wf[5], s);
      s = fdot2f(pk2(a1[4],a1[5]), wf[6], s);
      s = fdot2f(pk2(a1[6],a1[7]), wf[7], s);
      s = fdot2f(pk2(b0[0],b0[1]), wl[0], s);
      s = fdot2f(pk2(b0[2],b0[3]), wl[1], s);
      s = fdot2f(pk2(b0[4],b0[5]), wl[2], s);
      s = fdot2f(pk2(b0[6],b0[7]), wl[3], s);
      s = fdot2f(pk2(b1[0],b1[1]), wl[4], s);
      s = fdot2f(pk2(b1[2],b1[3]), wl[5], s);
      s = fdot2f(pk2(b1[4],b1[5]), wl[6], s);
      s = fdot2f(pk2(b1[6],b1[7]), wl[7], s);
      acc[r] = s;
    }
  }
  const float* lb = lqB + c*16;
  float lbv[16];
  #pragma unroll
  for (int i = 0; i < 16; i += 4) {
    float4 t = *(const float4*)(lb + i);
    lbv[i] = t.x; lbv[i+1] = t.y; lbv[i+2] = t.z; lbv[i+3] = t.w;
  }
  #pragma unroll
  for (int r = 0; r < 16; ++r) {
    float dl = 0.f;
    #pragma unroll
    for (int kk = 0; kk < 16; ++kk) dl += t16[(rb+r)*16 + kk] * lbv[kk];
    acc[r] += dl * LORA_SCALE;
  }
  const int h = c >> 4, d = c & 15;
  #pragma unroll
  for (int r = 0; r < 16; ++r) {
    const int grow = row0 + rb + r;
    const int b = grow / 200, m = grow % 200;
    qF[(((size_t)b*8 + h)*200 + m)*16 + d] = (f16)acc[r];
  }
}

// ---------------- k3: MFMA attention, n-split halves, partial (O,l) out ----------------
// grid (64,8,2), 512 thr (8 waves). Wave w: tiles (tA=w, tB=w+8) with hasB=(w<5);
// waves 5-7 do ONLY tA (R17: they redundantly recomputed tile 12 = 19% wasted work).
// K padded [512][20]; f32 VALU row sums (f16 MFMA denominator fails accuracy, R16).
#define KSTR 20
#define VSTRL 516
__global__ __launch_bounds__(512) void k3_attn(const f16* __restrict__ Kp,
    const f16* __restrict__ Vt, const f16* __restrict__ qF,
    const float* __restrict__ mask, const float* __restrict__ kmaxA,
    const float* __restrict__ qnA, f16* __restrict__ Opart,
    float* __restrict__ lpart)
{
  extern __shared__ char smem[];
  f16* Kl = (f16*)smem;                     // [512][20] : 20480 B
  f16* Vl = (f16*)(smem + 20480);           // [16][516] : 16512 B
  const int tid = threadIdx.x;
  const int lane = tid & 63, w = tid >> 6;
  const int b = blockIdx.x, h = blockIdx.y, z = blockIdx.z;
  const int bh = b*8 + h;
  { // stage K half: one row per thread, padded stride 20
    const int nl = tid;
    const int n = z*512 + nl;
    f16x4 v0{}, v1{}, v2{}, v3{};
    if (n < 1000) {
      const f16x4* src = (const f16x4*)(Kp + (size_t)bh*16000 + n*16);
      v0 = src[0]; v1 = src[1]; v2 = src[2]; v3 = src[3];
    }
    f16* dst = Kl + nl*KSTR;
    *(f16x4*)(dst)    = v0;
    *(f16x4*)(dst+4)  = v1;
    *(f16x4*)(dst+8)  = v2;
    *(f16x4*)(dst+12) = v3;
  }
  { // stage V half: 16 f16 per thread
    const int d = tid >> 5, c16 = (tid & 31) * 16;
    const f16* srow = Vt + (size_t)bh*16000 + d*1000;
    f16* drow = Vl + d*VSTRL + c16;
    const int nbase = z*512 + c16;
    if (nbase + 15 < 1000) {
      const f16x4* s4 = (const f16x4*)(srow + nbase);
      *(f16x4*)(drow)    = s4[0];
      *(f16x4*)(drow+4)  = s4[1];
      *(f16x4*)(drow+8)  = s4[2];
      *(f16x4*)(drow+12) = s4[3];
    } else {
      for (int j = 0; j < 16; ++j) drow[j] = (nbase+j < 1000) ? srow[nbase+j] : (f16)0;
    }
  }
  __syncthreads();

  const int col = lane & 15, g = lane >> 4, g4 = g*4;
  const f32x4 zero = {0.f, 0.f, 0.f, 0.f};
  const int tA = w, tB = (w + 8 < 13) ? (w + 8) : 12;
  const bool hasB = (w < 5);                             // waves 5-7: single tile
  const int mA = tA*16, mB = tB*16;
  const int mqA = min(mA + col, 199), mqB = min(mB + col, 199);
  const f16x4 qfA = *(const f16x4*)(qF + (size_t)bh*3200 + mqA*16 + g4);
  const f16x4 qfB = *(const f16x4*)(qF + (size_t)bh*3200 + mqB*16 + g4);
  const float kmx = kmaxA[bh];
  const float mbA = -kmx * qnA[bh*200 + mqA] * 0.360673760f;
  const float mbB = -kmx * qnA[bh*200 + mqB] * 0.360673760f;
  const float* mpA = mask + ((size_t)b*200 + mqA)*1000 + z*512;
  const float* mpB = mask + ((size_t)b*200 + mqB)*1000 + z*512;

  f32x4 OA = zero, OB = zero;
  float lA0=0.f, lA1=0.f, lA2=0.f, lA3=0.f;
  float lB0=0.f, lB1=0.f, lB2=0.f, lB3=0.f;
  const int NTc = 32 - z*2;
  #pragma unroll 4
  for (int t = 0; t < NTc; ++t) {
    const int nl = t*16;
    const f16x4 kf = *(const f16x4*)(Kl + (nl+col)*KSTR + g4);
    const f16x4 vf = *(const f16x4*)(Vl + col*VSTRL + nl + g4);
    f32x4 sA = mfma16(kf, qfA, zero);
    const float4 mkA = *(const float4*)(mpA + nl + g4);
    const float pA0 = exp2f(fmaf(sA[0], 0.360673760f, fmaf(mkA.x, L2E, mbA)));
    const float pA1 = exp2f(fmaf(sA[1], 0.360673760f, fmaf(mkA.y, L2E, mbA)));
    const float pA2 = exp2f(fmaf(sA[2], 0.360673760f, fmaf(mkA.z, L2E, mbA)));
    const float pA3 = exp2f(fmaf(sA[3], 0.360673760f, fmaf(mkA.w, L2E, mbA)));
    lA0 += pA0; lA1 += pA1; lA2 += pA2; lA3 += pA3;
    const f16x4 pfA = __builtin_shufflevector(pkrtz(pA0,pA1), pkrtz(pA2,pA3), 0,1,2,3);
    OA = mfma16(vf, pfA, OA);
    if (hasB) {
      f32x4 sB = mfma16(kf, qfB, zero);
      const float4 mkB = *(const float4*)(mpB + nl + g4);
      const float pB0 = exp2f(fmaf(sB[0], 0.360673760f, fmaf(mkB.x, L2E, mbB)));
      const float pB1 = exp2f(fmaf(sB[1], 0.360673760f, fmaf(mkB.y, L2E, mbB)));
      const float pB2 = exp2f(fmaf(sB[2], 0.360673760f, fmaf(mkB.z, L2E, mbB)));
      const float pB3 = exp2f(fmaf(sB[3], 0.360673760f, fmaf(mkB.w, L2E, mbB)));
      lB0 += pB0; lB1 += pB1; lB2 += pB2; lB3 += pB3;
      const f16x4 pfB = __builtin_shufflevector(pkrtz(pB0,pB1), pkrtz(pB2,pB3), 0,1,2,3);
      OB = mfma16(vf, pfB, OB);
    }
  }
  if (z == 1) { // ragged global tile 62: local rows 480..495, keys valid only g<2
    const int nl = 480;
    const f16x4 kf = *(const f16x4*)(Kl + (nl+col)*KSTR + g4);
    const f16x4 vf = *(const f16x4*)(Vl + col*VSTRL + ((g < 2) ? (nl + g4) : 0));
    f32x4 sA = mfma16(kf, qfA, zero);
    float pA0=0.f,pA1=0.f,pA2=0.f,pA3=0.f;
    if (g < 2) {
      const float4 mkA = *(const float4*)(mpA + nl + g4);
      pA0 = exp2f(fmaf(sA[0], 0.360673760f, fmaf(mkA.x, L2E, mbA)));
      pA1 = exp2f(fmaf(sA[1], 0.360673760f, fmaf(mkA.y, L2E, mbA)));
      pA2 = exp2f(fmaf(sA[2], 0.360673760f, fmaf(mkA.z, L2E, mbA)));
      pA3 = exp2f(fmaf(sA[3], 0.360673760f, fmaf(mkA.w, L2E, mbA)));
      lA0 += pA0; lA1 += pA1; lA2 += pA2; lA3 += pA3;
    }
    const f16x4 pfA = __builtin_shufflevector(pkrtz(pA0,pA1), pkrtz(pA2,pA3), 0,1,2,3);
    OA = mfma16(vf, pfA, OA);
    if (hasB) {
      f32x4 sB = mfma16(kf, qfB, zero);
      float pB0=0.f,pB1=0.f,pB2=0.f,pB3=0.f;
      if (g < 2) {
        const float4 mkB = *(const float4*)(mpB + nl + g4);
        pB0 = exp2f(fmaf(sB[0], 0.360673760f, fmaf(mkB.x, L2E, mbB)));
        pB1 = exp2f(fmaf(sB[1], 0.360673760f, fmaf(mkB.y, L2E, mbB)));
        pB2 = exp2f(fmaf(sB[2], 0.360673760f, fmaf(mkB.z, L2E, mbB)));
        pB3 = exp2f(fmaf(sB[3], 0.360673760f, fmaf(mkB.w, L2E, mbB)));
        lB0 += pB0; lB1 += pB1; lB2 += pB2; lB3 += pB3;
      }
      const f16x4 pfB = __builtin_shufflevector(pkrtz(pB0,pB1), pkrtz(pB2,pB3), 0,1,2,3);
      OB = mfma16(vf, pfB, OB);
    }
  }
  float lA = (lA0 + lA1) + (lA2 + lA3);
  lA += __shfl_xor(lA, 16, 64); lA += __shfl_xor(lA, 32, 64);
  const size_t pbase = (size_t)(z*512 + bh)*200;
  if (mA + col < 200) {
    const f16x4 ov = __builtin_shufflevector(pkrtz(OA[0], OA[1]), pkrtz(OA[2], OA[3]), 0,1,2,3);
    *(f16x4*)(Opart + (pbase + mA + col)*16 + g4) = ov;
    if (g == 0) lpart[pbase + mA + col] = lA;
  }
  if (hasB) {
    float lB = (lB0 + lB1) + (lB2 + lB3);
    lB += __shfl_xor(lB, 16, 64); lB += __shfl_xor(lB, 32, 64);
    if (mB + col < 200) {
      const f16x4 ov = __builtin_shufflevector(pkrtz(OB[0], OB[1]), pkrtz(OB[2], OB[3]), 0,1,2,3);
      *(f16x4*)(Opart + (pbase + mB + col)*16 + g4) = ov;
      if (g == 0) lpart[pbase + mB + col] = lB;
    }
  }
}

// ---------------- k4: combine partials + normalize + Wc GEMM + LoRA (k3c fused) ----------------
// grid 400, 256 thr, 32 rows/block. Staging reads Opart halves + lpart, combines and
// normalizes inline (exact k3c math), then the Wc/LoRA GEMM as before. Writes mhF.
__global__ __launch_bounds__(256) void k4_comb(const f16* __restrict__ Opart,
    const float* __restrict__ lpart,
    const float* __restrict__ Wc, const float* __restrict__ bc,
    const float* __restrict__ lcA, const float* __restrict__ lcB,
    f16* __restrict__ mhF)
{
  __shared__ f16 ocr[32*128];
  __shared__ float t16[32*16];
  const int tid = threadIdx.x;
  const int row0 = blockIdx.x * 32;
  for (int i = tid; i < 1024; i += 256) {               // 32 rows x 32 quads(4 f16)
    const int r = i >> 5, c4 = i & 31;
    const int hh = c4 >> 2, q = c4 & 3;
    const int grow = row0 + r;
    const int b = grow / 200, m = grow - b*200;
    const int ridx = (b*8 + hh)*200 + m;
    const f16x4 o0 = *(const f16x4*)(Opart + (size_t)ridx*16 + q*4);
    const f16x4 o1 = *(const f16x4*)(Opart + ((size_t)102400 + ridx)*16 + q*4);
    const float l = lpart[ridx] + lpart[102400 + ridx];
    const float inv = 1.f / fmaxf(l, 1e-35f);
    const float v0 = ((float)o0[0] + (float)o1[0]) * inv;
    const float v1 = ((float)o0[1] + (float)o1[1]) * inv;
    const float v2 = ((float)o0[2] + (float)o1[2]) * inv;
    const float v3 = ((float)o0[3] + (float)o1[3]) * inv;
    *(f16x4*)(ocr + r*128 + hh*16 + q*4) =
        __builtin_shufflevector(pkrtz(v0, v1), pkrtz(v2, v3), 0, 1, 2, 3);
  }
  __syncthreads();
  for (int idx = tid; idx < 32*16; idx += 256) {
    const int r = idx >> 4, kk = idx & 15;
    const f16x8* lrow = (const f16x8*)(ocr + r*128);
    const float* arow = lcA + kk*128;
    float s = 0.f;
    #pragma unroll
    for (int cc = 0; cc < 16; ++cc) {
      f16x8 a = lrow[cc];
      float4 wa = *(const float4*)(arow + cc*8);
      float4 wb = *(const float4*)(arow + cc*8 + 4);
      s = fdot2f(pk2(a[0],a[1]), pkrtz(wa.x,wa.y), s);
      s = fdot2f(pk2(a[2],a[3]), pkrtz(wa.z,wa.w), s);
      s = fdot2f(pk2(a[4],a[5]), pkrtz(wb.x,wb.y), s);
      s = fdot2f(pk2(a[6],a[7]), pkrtz(wb.z,wb.w), s);
    }
    t16[idx] = s;
  }
  __syncthreads();
  const int c = tid & 127, rg = tid >> 7, rb = rg*16;
  float acc[16];
  const float bias = bc[c];
  #pragma unroll
  for (int r = 0; r < 16; ++r) acc[r] = bias;
  const float* wrow = Wc + c*128;
  for (int c0 = 0; c0 < 128; c0 += 16) {
    float4 w0 = *(const float4*)(wrow + c0);
    float4 w1 = *(const float4*)(wrow + c0 + 4);
    float4 w2 = *(const float4*)(wrow + c0 + 8);
    float4 w3 = *(const float4*)(wrow + c0 + 12);
    f16x2 wv[8] = { pkrtz(w0.x,w0.y), pkrtz(w0.z,w0.w), pkrtz(w1.x,w1.y), pkrtz(w1.z,w1.w),
                    pkrtz(w2.x,w2.y), pkrtz(w2.z,w2.w), pkrtz(w3.x,w3.y), pkrtz(w3.z,w3.w) };
    #pragma unroll
    for (int r = 0; r < 16; ++r) {
      const f16x8* op = (const f16x8*)(ocr + (rb+r)*128 + c0);
      f16x8 a0 = op[0], a1 = op[1];
      float s = acc[r];
      s = fdot2f(pk2(a0[0],a0[1]), wv[0], s);
      s = fdot2f(pk2(a0[2],a0[3]), wv[1], s);
      s = fdot2f(pk2(a0[4],a0[5]), wv[2], s);
      s = fdot2f(pk2(a0[6],a0[7]), wv[3], s);
      s = fdot2f(pk2(a1[0],a1[1]), wv[4], s);
      s = fdot2f(pk2(a1[2],a1[3]), wv[5], s);
      s = fdot2f(pk2(a1[4],a1[5]), wv[6], s);
      s = fdot2f(pk2(a1[6],a1[7]), wv[7], s);
      acc[r] = s;
    }
  }
  const float* lb = lcB + c*16;
  float lbv[16];
  #pragma unroll
  for (int i = 0; i < 16; i += 4) {
    float4 t = *(const float4*)(lb + i);
    lbv[i] = t.x; lbv[i+1] = t.y; lbv[i+2] = t.z; lbv[i+3] = t.w;
  }
  #pragma unroll
  for (int r = 0; r < 16; ++r) {
    float dl = 0.f;
    #pragma unroll
    for (int kk = 0; kk < 16; ++kk) dl += t16[(rb+r)*16 + kk] * lbv[kk];
    acc[r] += dl * LORA_SCALE;
  }
  #pragma unroll
  for (int r = 0; r < 16; ++r) {
    mhF[(size_t)(row0 + rb + r)*128 + c] = (f16)acc[r];
  }
}

// ---------------- k5: MFMA probs = softmax(10*tanh(mh@nodes^T/sqrt(128)) + mask) ----------------
// grid (64, 7), 1024 thr (16 waves). A-frags from nodesT (contiguous 512B wave-loads),
// output staged through LDS then streamed coalesced.
__global__ __launch_bounds__(1024) void k5_final(const f16* __restrict__ mhF,
    const f16* __restrict__ nodesT, const float* __restrict__ mask,
    float* __restrict__ out)
{
  __shared__ float sumsA[16][16];
  __shared__ float sumsB[16][16];
  __shared__ float obuf[16][1012];
  const int tid = threadIdx.x, lane = tid & 63, w = tid >> 6;
  const int b = blockIdx.x, j = blockIdx.y;
  const int col = lane & 15, g = lane >> 4, g4 = g*4;
  const int tmA = 2*j, tmB = min(2*j + 1, 12);
  const int mA = tmA*16 + col, mB = tmB*16 + col;
  const int mqA = min(mA, 199), mqB = min(mB, 199);
  f16x4 bfA[8], bfB[8];
  {
    const f16* a = mhF + (size_t)(b*200 + mqA)*128;
    const f16* bb = mhF + (size_t)(b*200 + mqB)*128;
    #pragma unroll
    for (int kk = 0; kk < 8; ++kk) {
      bfA[kk] = *(const f16x4*)(a + kk*16 + g4);
      bfB[kk] = *(const f16x4*)(bb + kk*16 + g4);
    }
  }
  const float* mrowA = mask + (size_t)(b*200 + mqA)*1000;
  const float* mrowB = mask + (size_t)(b*200 + mqB)*1000;
  const f16* ntb = nodesT + (size_t)b*129024;           // 63*8*256
  f16x4 pfA[4], pfB[4];
  float lsumA = 0.f, lsumB = 0.f;
  #pragma unroll
  for (int i = 0; i < 4; ++i) {
    const int t = w + i*16;
    float pA0 = 0.f, pA1 = 0.f, pA2 = 0.f, pA3 = 0.f;
    float pB0 = 0.f, pB1 = 0.f, pB2 = 0.f, pB3 = 0.f;
    if (t < 63) {
      const f16* na = ntb + (size_t)t*2048;             // 8*256
      f32x4 accA = {0.f, 0.f, 0.f, 0.f};
      f32x4 accB = {0.f, 0.f, 0.f, 0.f};
      #pragma unroll
      for (int kk = 0; kk < 8; ++kk) {
        f16x4 af = *(const f16x4*)(na + kk*256 + lane*4);
        accA = mfma16(af, bfA[kk], accA);
        accB = mfma16(af, bfB[kk], accB);
      }
      const int n0 = t*16 + g4;
      float mkvA[4] = {0.f, 0.f, 0.f, 0.f};
      float mkvB[4] = {0.f, 0.f, 0.f, 0.f};
      if (n0 + 3 < 1000) {
        float4 mkA = *(const float4*)(mrowA + n0);
        float4 mkB = *(const float4*)(mrowB + n0);
        mkvA[0] = mkA.x; mkvA[1] = mkA.y; mkvA[2] = mkA.z; mkvA[3] = mkA.w;
        mkvB[0] = mkB.x; mkvB[1] = mkB.y; mkvB[2] = mkB.z; mkvB[3] = mkB.w;
      }
      float pvA[4], pvB[4];
      #pragma unroll
      for (int r = 0; r < 4; ++r) {
        const bool ok = (n0 + r < 1000);
        float xA = accA[r] * 0.08838834764831845f;      // /sqrt(128)
        float eA = exp2f(xA * 2.8853900817779268f);     // e^{2x}
        float thA = 1.f - 2.f/(eA + 1.f);               // tanh
        float tA0 = exp2f((10.f*thA + mkvA[r]) * L2E);
        pvA[r] = ok ? tA0 : 0.f;
        lsumA += pvA[r];
        float xB = accB[r] * 0.08838834764831845f;
        float eB = exp2f(xB * 2.8853900817779268f);
        float thB = 1.f - 2.f/(eB + 1.f);
        float tB0 = exp2f((10.f*thB + mkvB[r]) * L2E);
        pvB[r] = ok ? tB0 : 0.f;
        lsumB += pvB[r];
      }
      pA0 = pvA[0]; pA1 = pvA[1]; pA2 = pvA[2]; pA3 = pvA[3];
      pB0 = pvB[0]; pB1 = pvB[1]; pB2 = pvB[2]; pB3 = pvB[3];
    }
    pfA[i] = __builtin_shufflevector(pkrtz(pA0, pA1), pkrtz(pA2, pA3), 0, 1, 2, 3);
    pfB[i] = __builtin_shufflevector(pkrtz(pB0, pB1), pkrtz(pB2, pB3), 0, 1, 2, 3);
  }
  lsumA += __shfl_xor(lsumA, 16, 64);
  lsumA += __shfl_xor(lsumA, 32, 64);
  lsumB += __shfl_xor(lsumB, 16, 64);
  lsumB += __shfl_xor(lsumB, 32, 64);
  if (lane < 16) { sumsA[w][lane] = lsumA; sumsB[w][lane] = lsumB; }
  __syncthreads();
  float SA = 0.f, SB = 0.f;
  #pragma unroll
  for (int ww = 0; ww < 16; ++ww) { SA += sumsA[ww][col]; SB += sumsB[ww][col]; }
  const float invA = 1.f / SA;
  const float invB = 1.f / SB;
  // ---- tile A: stage normalized probs to LDS, then coalesced row streams ----
  #pragma unroll
  for (int i = 0; i < 4; ++i) {
    const int t = w + i*16;
    if (t < 63) {
      const f16x4 pv = pfA[i];
      const int n0 = t*16 + g4;
      #pragma unroll
      for (int r = 0; r < 4; ++r) obuf[col][n0 + r] = (float)pv[r]*invA;
    }
  }
  __syncthreads();
  if (tid < 1000) {
    for (int rr = 0; rr < 16; ++rr) {
      const int m = tmA*16 + rr;
      if (m < 200) out[((size_t)b*200 + m)*1000 + tid] = obuf[rr][tid];
    }
  }
  __syncthreads();
  if (tmB != tmA) {
    #pragma unroll
    for (int i = 0; i < 4; ++i) {
      const int t = w + i*16;
      if (t < 63) {
        const f16x4 pv = pfB[i];
        const int n0 = t*16 + g4;
        #pragma unroll
        for (int r = 0; r < 4; ++r) obuf[col][n0 + r] = (float)pv[r]*invB;
      }
    }
    __syncthreads();
    if (tid < 1000) {
      for (int rr = 0; rr < 16; ++rr) {
        const int m = tmB*16 + rr;
        if (m < 200) out[((size_t)b*200 + m)*1000 + tid] = obuf[rr][tid];
      }
    }
  }
}

extern "C" void kernel_launch(void* const* d_in, const int* in_sizes, int n_in,
                              void* d_out, int out_size, void* d_ws, size_t ws_size,
                              hipStream_t stream)
{
  (void)in_sizes; (void)n_in; (void)out_size; (void)ws_size;
  const float* nodes = (const float*)d_in[0];
  const float* q1    = (const float*)d_in[1];
  const float* last  = (const float*)d_in[2];
  const float* mask  = (const float*)d_in[3];
  const float* Wqf   = (const float*)d_in[4];
  const float* Wql   = (const float*)d_in[5];
  const float* Wk    = (const float*)d_in[6];
  const float* Wv    = (const float*)d_in[7];
  const float* Wc    = (const float*)d_in[8];
  const float* bc    = (const float*)d_in[9];
  const float* lqA   = (const float*)d_in[10];
  const float* lqB   = (const float*)d_in[11];
  const float* lcA   = (const float*)d_in[12];
  const float* lcB   = (const float*)d_in[13];
  float* out = (float*)d_out;
  char* ws = (char*)d_ws;
  // ws layout (bytes):
  f16* Kp      = (f16*)(ws + 16384000);    // 16,384,000
  f16* Vt      = (f16*)(ws + 32768000);    // 16,384,000
  f16* qF      = (f16*)(ws + 49152000);    //  3,276,800
  f16* ocmh    = (f16*)(ws + 52428800);    //  3,276,800  (mh only; oc fused into k4)
  float* kmaxA = (float*)(ws + 55771136);  //      2,048
  float* qnA   = (float*)(ws + 55773184);  //    409,600
  f16* OpartF  = (f16*)(ws + 56182784);    //  6,553,600
  float* lpart = (float*)(ws + 62736384);  //    819,200  (end 63,555,584)
  f16* nodesT  = (f16*)(ws + 63555584);    // 16,515,072  (end 80,070,656)

  k1_proj<<<dim3(16, 64), 256, 0, stream>>>(nodes, Wk, Wv, nodesT, Kp, Vt);
  k2_q<<<dim3(400), 256, 0, stream>>>(q1, last, Wqf, Wql, lqA, lqB, qF);
  kb_norms<<<dim3(912), 256, 0, stream>>>(Kp, qF, kmaxA, qnA);
  k3_attn<<<dim3(64, 8, 2), 512, 36992, stream>>>(Kp, Vt, qF, mask, kmaxA, qnA, OpartF, lpart);
  k4_comb<<<dim3(400), 256, 0, stream>>>(OpartF, lpart, Wc, bc, lcA, lcB, ocmh);
  k5_final<<<dim3(64, 7), 1024, 0, stream>>>(ocmh, nodesT, mask, out);
}

// Round 20
// 182.150 us; speedup vs baseline: 1.2117x; 1.0016x over previous
//
#include <hip/hip_runtime.h>
#include <hip/hip_bf16.h>

// TSP decoder forward: B=64, POMO=200, N=1000, EMB=128, H=8, D=16.
// k1 MFMA K/V proj + nodes->nodesT | k2 q (+LoRA) | kb kmax+qnorm |
// k3 MFMA attention n-split (no redundant tile-12 work) |
// k4 combine partials + Wc GEMM (+LoRA) fused | k5 MFMA final.
// (R19's 39-unit balanced k3 NaN'd; this is the verified R18 structure.)

typedef _Float16 f16;
typedef _Float16 f16x2 __attribute__((ext_vector_type(2)));
typedef _Float16 f16x4 __attribute__((ext_vector_type(4)));
typedef _Float16 f16x8 __attribute__((ext_vector_type(8)));
typedef __fp16  h4   __attribute__((ext_vector_type(4)));
typedef float   f32x4 __attribute__((ext_vector_type(4)));

#define LORA_SCALE 1.0f
#define L2E 1.44269504f

__device__ __forceinline__ f16x2 pk2(f16 a, f16 b){ f16x2 r; r[0]=a; r[1]=b; return r; }

#if __has_builtin(__builtin_amdgcn_fdot2)
__device__ __forceinline__ float fdot2f(f16x2 a, f16x2 b, float c){ return __builtin_amdgcn_fdot2(a, b, c, false); }
#else
__device__ __forceinline__ float fdot2f(f16x2 a, f16x2 b, float c){ return c + (float)a[0]*(float)b[0] + (float)a[1]*(float)b[1]; }
#endif

#if __has_builtin(__builtin_amdgcn_cvt_pkrtz)
__device__ __forceinline__ f16x2 pkrtz(float a, float b){
  return __builtin_bit_cast(f16x2, __builtin_amdgcn_cvt_pkrtz(a, b));
}
#else
__device__ __forceinline__ f16x2 pkrtz(float a, float b){ return pk2((f16)a, (f16)b); }
#endif

// D[i][j] = sum_k A[i][k]*B[k][j] + C  via v_mfma_f32_16x16x16_f16.
// A: lane holds row i=(l&15), k=4*(l>>4)+j. B: lane holds col j=(l&15), k=4*(l>>4)+j.
// D: lane holds col j=(l&15), row i=4*(l>>4)+reg.   (validated end-to-end in k3/k5)
__device__ __forceinline__ f32x4 mfma16(f16x4 a, f16x4 b, f32x4 c){
  return __builtin_amdgcn_mfma_f32_16x16x16f16(
      __builtin_bit_cast(h4, a), __builtin_bit_cast(h4, b), c, 0, 0, 0);
}

__device__ __forceinline__ float sumsq16(const f16* p){
  const f16x8* v = (const f16x8*)p;
  f16x8 a = v[0], b = v[1];
  float s = 0.f;
  s = fdot2f(pk2(a[0],a[1]), pk2(a[0],a[1]), s);
  s = fdot2f(pk2(a[2],a[3]), pk2(a[2],a[3]), s);
  s = fdot2f(pk2(a[4],a[5]), pk2(a[4],a[5]), s);
  s = fdot2f(pk2(a[6],a[7]), pk2(a[6],a[7]), s);
  s = fdot2f(pk2(b[0],b[1]), pk2(b[0],b[1]), s);
  s = fdot2f(pk2(b[2],b[3]), pk2(b[2],b[3]), s);
  s = fdot2f(pk2(b[4],b[5]), pk2(b[4],b[5]), s);
  s = fdot2f(pk2(b[6],b[7]), pk2(b[6],b[7]), s);
  return s;
}

// ---------------- k1: MFMA K/V projection + nodes -> nodesT (fragment-tiled) ----------------
#define NSTR 132
#define WSTR 136
__global__ __launch_bounds__(256) void k1_proj(const float* __restrict__ nodes,
    const float* __restrict__ Wk, const float* __restrict__ Wv,
    f16* __restrict__ nodesT, f16* __restrict__ Kp, f16* __restrict__ Vt)
{
  __shared__ f16 lds[64*NSTR];     // 16896 B node tile
  __shared__ f16 wlds[16*WSTR];    //  4352 B weight tile
  const int tid = threadIdx.x, lane = tid & 63, w = tid >> 6;
  const int b = blockIdx.y;
  const int n0 = blockIdx.x * 64;
  const int rows = min(64, 1000 - n0);                  // 64 or 40
  for (int i = tid; i < rows*32; i += 256) {            // 32 f32x4 per row
    const int r = i >> 5, cq = i & 31;
    float4 v = ((const float4*)(nodes + ((size_t)b*1000 + n0 + r)*128))[cq];
    f16x2 lo = pkrtz(v.x,v.y), hi = pkrtz(v.z,v.w);
    f16x4 o = __builtin_shufflevector(lo, hi, 0, 1, 2, 3);
    *(f16x4*)(lds + r*NSTR + cq*4) = o;
    const int grow = n0 + r;
    const int t = grow >> 4, gcol = grow & 15;
    const int kk = cq >> 2, gg = cq & 3;
    f16* dstT = nodesT + (((size_t)(b*63 + t)*8 + kk)*256);
    *(f16x4*)(dstT + (gg*16 + gcol)*4) = o;
    if (grow == 999) {                                   // clamp-fill tile 62 cols 8..15
      f16* d62 = nodesT + (((size_t)(b*63 + 62)*8 + kk)*256);
      #pragma unroll
      for (int cf = 8; cf < 16; ++cf) *(f16x4*)(d62 + (gg*16 + cf)*4) = o;
    }
  }
  __syncthreads();
  const int col = lane & 15, g = lane >> 4, g4 = g*4;
  const int mloc = w*16 + col;
  f16x4 nf[8];
  #pragma unroll
  for (int kk = 0; kk < 8; ++kk)
    nf[kk] = *(const f16x4*)(lds + min(mloc, rows-1)*NSTR + kk*16 + g4);
  const int wr = tid >> 4, wc = tid & 15;
  for (int ct = 0; ct < 16; ++ct) {
    __syncthreads();
    {
      const int r = ct*16 + wr;                          // 0..255 over Wk|Wv
      const float* src = (r < 128) ? (Wk + (size_t)r*128) : (Wv + (size_t)(r-128)*128);
      float4 a = *(const float4*)(src + wc*8);
      float4 bb = *(const float4*)(src + wc*8 + 4);
      *(f16x4*)(wlds + wr*WSTR + wc*8) =
          __builtin_shufflevector(pkrtz(a.x,a.y), pkrtz(a.z,a.w), 0,1,2,3);
      *(f16x4*)(wlds + wr*WSTR + wc*8 + 4) =
          __builtin_shufflevector(pkrtz(bb.x,bb.y), pkrtz(bb.z,bb.w), 0,1,2,3);
    }
    __syncthreads();
    f16x4 wf[8];
    #pragma unroll
    for (int kk = 0; kk < 8; ++kk)
      wf[kk] = *(const f16x4*)(wlds + col*WSTR + kk*16 + g4);
    f32x4 acc = {0.f, 0.f, 0.f, 0.f};
    if (ct < 8) {                                       // K-head ct: D[c][m]
      #pragma unroll
      for (int kk = 0; kk < 8; ++kk) acc = mfma16(wf[kk], nf[kk], acc);
      if (mloc < rows) {
        const int nn = n0 + mloc;
        f16x4 ov = __builtin_shufflevector(pk2((f16)acc[0],(f16)acc[1]),
                                           pk2((f16)acc[2],(f16)acc[3]), 0,1,2,3);
        *(f16x4*)(Kp + ((size_t)(b*8+ct)*1000 + nn)*16 + g4) = ov;
      }
    } else {                                            // V-head ct-8: D[m][c]
      #pragma unroll
      for (int kk = 0; kk < 8; ++kk) acc = mfma16(nf[kk], wf[kk], acc);
      if (w*16 + g4 + 3 < rows) {
        const int nbase = n0 + w*16 + g4;
        f16x4 ov = __builtin_shufflevector(pk2((f16)acc[0],(f16)acc[1]),
                                           pk2((f16)acc[2],(f16)acc[3]), 0,1,2,3);
        *(f16x4*)(Vt + ((size_t)(b*8+(ct-8))*16 + col)*1000 + nbase) = ov;
      }
    }
  }
}

// ---------------- kb: kmax[bh] (blocks 0..511) + qnorm (blocks 512..911) ----------------
__global__ __launch_bounds__(256) void kb_norms(const f16* __restrict__ Kp,
    const f16* __restrict__ qF, float* __restrict__ kmaxA, float* __restrict__ qnA)
{
  if (blockIdx.x < 512) {
    __shared__ float wmax[4];
    const int bh = blockIdx.x, tid = threadIdx.x, lane = tid & 63, w = tid >> 6;
    const f16* base = Kp + (size_t)bh*16000;
    float mx = 0.f;
    for (int n = tid; n < 1000; n += 256) mx = fmaxf(mx, sumsq16(base + n*16));
    #pragma unroll
    for (int off = 32; off; off >>= 1) mx = fmaxf(mx, __shfl_xor(mx, off, 64));
    if (lane == 0) wmax[w] = mx;
    __syncthreads();
    if (tid == 0) {
      float m = fmaxf(fmaxf(wmax[0], wmax[1]), fmaxf(wmax[2], wmax[3]));
      kmaxA[bh] = sqrtf(m);
    }
  } else {
    const int idx = (blockIdx.x - 512)*256 + threadIdx.x;   // 0..102399
    qnA[idx] = sqrtf(sumsq16(qF + (size_t)idx*16));
  }
}

// ---------------- k2: q = q1@Wqf^T + last@Wql^T + LoRA ----------------
__global__ __launch_bounds__(256) void k2_q(const float* __restrict__ q1,
    const float* __restrict__ last, const float* __restrict__ Wqf,
    const float* __restrict__ Wql, const float* __restrict__ lqA,
    const float* __restrict__ lqB, f16* __restrict__ qF)
{
  __shared__ f16 q1r[32*128];
  __shared__ f16 lar[32*128];
  __shared__ float t16[32*16];
  const int tid = threadIdx.x;
  const int row0 = blockIdx.x * 32;
  {
    const float4* s1 = (const float4*)(q1 + (size_t)row0*128);
    const float4* s2 = (const float4*)(last + (size_t)row0*128);
    f16x2* d1 = (f16x2*)q1r; f16x2* d2 = (f16x2*)lar;
    for (int i = tid; i < 32*32; i += 256) {
      float4 v = s1[i];
      d1[2*i] = pkrtz(v.x,v.y); d1[2*i+1] = pkrtz(v.z,v.w);
      float4 u = s2[i];
      d2[2*i] = pkrtz(u.x,u.y); d2[2*i+1] = pkrtz(u.z,u.w);
    }
  }
  __syncthreads();
  for (int idx = tid; idx < 32*16; idx += 256) {
    const int r = idx >> 4, kk = idx & 15;
    const f16x8* lrow = (const f16x8*)(lar + r*128);
    const float* arow = lqA + kk*128;
    float s = 0.f;
    #pragma unroll
    for (int cc = 0; cc < 16; ++cc) {
      f16x8 a = lrow[cc];
      float4 wa = *(const float4*)(arow + cc*8);
      float4 wb = *(const float4*)(arow + cc*8 + 4);
      s = fdot2f(pk2(a[0],a[1]), pkrtz(wa.x,wa.y), s);
      s = fdot2f(pk2(a[2],a[3]), pkrtz(wa.z,wa.w), s);
      s = fdot2f(pk2(a[4],a[5]), pkrtz(wb.x,wb.y), s);
      s = fdot2f(pk2(a[6],a[7]), pkrtz(wb.z,wb.w), s);
    }
    t16[idx] = s;
  }
  __syncthreads();
  const int c = tid & 127, rg = tid >> 7, rb = rg*16;
  float acc[16];
  #pragma unroll
  for (int r = 0; r < 16; ++r) acc[r] = 0.f;
  const float* wfr = Wqf + c*128;
  const float* wlr = Wql + c*128;
  for (int c0 = 0; c0 < 128; c0 += 16) {
    float4 f0 = *(const float4*)(wfr + c0);
    float4 f1 = *(const float4*)(wfr + c0 + 4);
    float4 f2 = *(const float4*)(wfr + c0 + 8);
    float4 f3 = *(const float4*)(wfr + c0 + 12);
    f16x2 wf[8] = { pkrtz(f0.x,f0.y), pkrtz(f0.z,f0.w), pkrtz(f1.x,f1.y), pkrtz(f1.z,f1.w),
                    pkrtz(f2.x,f2.y), pkrtz(f2.z,f2.w), pkrtz(f3.x,f3.y), pkrtz(f3.z,f3.w) };
    float4 g0 = *(const float4*)(wlr + c0);
    float4 g1 = *(const float4*)(wlr + c0 + 4);
    float4 g2 = *(const float4*)(wlr + c0 + 8);
    float4 g3 = *(const float4*)(wlr + c0 + 12);
    f16x2 wl[8] = { pkrtz(g0.x,g0.y), pkrtz(g0.z,g0.w), pkrtz(g1.x,g1.y), pkrtz(g1.z,g1.w),
                    pkrtz(g2.x,g2.y), pkrtz(g2.z,g2.w), pkrtz(g3.x,g3.y), pkrtz(g3.z,g3.w) };
    #pragma unroll
    for (int r = 0; r < 16; ++r) {
      const f16x8* qp = (const f16x8*)(q1r + (rb+r)*128 + c0);
      const f16x8* lp = (const f16x8*)(lar + (rb+r)*128 + c0);
      f16x8 a0 = qp[0], a1 = qp[1], b0 = lp[0], b1 = lp[1];
      float s = acc[r];
      s = fdot2f(pk2(a0[0],a0[1]), wf[0], s);
      s = fdot2f(pk2(a0[2],a0[3]), wf[1], s);
      s = fdot2f(pk2(a0[4],a0[5]), wf[2], s);
      s = fdot2f(pk2(a0[6],a0[7]), wf[3], s);
      s = fdot2f(pk2(a1[0],a1[1]), wf[4], s);
      s = fdot2f(pk2(a1[2],a1[3]), wf[5], s);
      s = fdot2f(pk2(a1[4],a1[5]), wf[6], s);
      s = fdot2f(pk2(a1[6],a1[7]), wf[7], s);
      s = fdot2f(pk2(b0[0],b0[1]), wl[0], s);
      s = fdot2f(pk2(b0[2],b0[3]), wl[1], s);
      s = fdot2f(pk2(b0[4],b0[5]), wl[2], s);
      s = fdot2f(pk2(b0[6],b0[7]), wl[3], s);
      s = fdot2f(pk2(b1[0],b1[1]), wl[4], s);
      s = fdot2f(pk2(b1[2],b1[3]), wl[5], s);
      s = fdot2f(pk2(b1[4],b1[5]), wl[6], s);
      s = fdot2f(pk2(b1[6],b1[7]), wl[7], s);
      acc[r] = s;
    }
  }
  const float* lb = lqB + c*16;
  float lbv[16];
  #pragma unroll
  for (int i = 0; i < 16; i += 4) {
    float4 t = *(const float4*)(lb + i);
    lbv[i] = t.x; lbv[i+1] = t.y; lbv[i+2] = t.z; lbv[i+3] = t.w;
  }
  #pragma unroll
  for (int r = 0; r < 16; ++r) {
    float dl = 0.f;
    #pragma unroll
    for (int kk = 0; kk < 16; ++kk) dl += t16[(rb+r)*16 + kk] * lbv[kk];
    acc[r] += dl * LORA_SCALE;
  }
  const int h = c >> 4, d = c & 15;
  #pragma unroll
  for (int r = 0; r < 16; ++r) {
    const int grow = row0 + rb + r;
    const int b = grow / 200, m = grow % 200;
    qF[(((size_t)b*8 + h)*200 + m)*16 + d] = (f16)acc[r];
  }
}

// ---------------- k3: MFMA attention, n-split halves, partial (O,l) out ----------------
// grid (64,8,2), 512 thr (8 waves). Wave w: tiles (tA=w, tB=w+8) with hasB=(w<5);
// waves 5-7 do ONLY tA. K padded [512][20]; f32 VALU row sums.
#define KSTR 20
#define VSTRL 516
__global__ __launch_bounds__(512) void k3_attn(const f16* __restrict__ Kp,
    const f16* __restrict__ Vt, const f16* __restrict__ qF,
    const float* __restrict__ mask, const float* __restrict__ kmaxA,
    const float* __restrict__ qnA, f16* __restrict__ Opart,
    float* __restrict__ lpart)
{
  extern __shared__ char smem[];
  f16* Kl = (f16*)smem;                     // [512][20] : 20480 B
  f16* Vl = (f16*)(smem + 20480);           // [16][516] : 16512 B
  const int tid = threadIdx.x;
  const int lane = tid & 63, w = tid >> 6;
  const int b = blockIdx.x, h = blockIdx.y, z = blockIdx.z;
  const int bh = b*8 + h;
  { // stage K half: one row per thread, padded stride 20
    const int nl = tid;
    const int n = z*512 + nl;
    f16x4 v0{}, v1{}, v2{}, v3{};
    if (n < 1000) {
      const f16x4* src = (const f16x4*)(Kp + (size_t)bh*16000 + n*16);
      v0 = src[0]; v1 = src[1]; v2 = src[2]; v3 = src[3];
    }
    f16* dst = Kl + nl*KSTR;
    *(f16x4*)(dst)    = v0;
    *(f16x4*)(dst+4)  = v1;
    *(f16x4*)(dst+8)  = v2;
    *(f16x4*)(dst+12) = v3;
  }
  { // stage V half: 16 f16 per thread
    const int d = tid >> 5, c16 = (tid & 31) * 16;
    const f16* srow = Vt + (size_t)bh*16000 + d*1000;
    f16* drow = Vl + d*VSTRL + c16;
    const int nbase = z*512 + c16;
    if (nbase + 15 < 1000) {
      const f16x4* s4 = (const f16x4*)(srow + nbase);
      *(f16x4*)(drow)    = s4[0];
      *(f16x4*)(drow+4)  = s4[1];
      *(f16x4*)(drow+8)  = s4[2];
      *(f16x4*)(drow+12) = s4[3];
    } else {
      for (int j = 0; j < 16; ++j) drow[j] = (nbase+j < 1000) ? srow[nbase+j] : (f16)0;
    }
  }
  __syncthreads();

  const int col = lane & 15, g = lane >> 4, g4 = g*4;
  const f32x4 zero = {0.f, 0.f, 0.f, 0.f};
  const int tA = w, tB = (w + 8 < 13) ? (w + 8) : 12;
  const bool hasB = (w < 5);                             // waves 5-7: single tile
  const int mA = tA*16, mB = tB*16;
  const int mqA = min(mA + col, 199), mqB = min(mB + col, 199);
  const f16x4 qfA = *(const f16x4*)(qF + (size_t)bh*3200 + mqA*16 + g4);
  const f16x4 qfB = *(const f16x4*)(qF + (size_t)bh*3200 + mqB*16 + g4);
  const float kmx = kmaxA[bh];
  const float mbA = -kmx * qnA[bh*200 + mqA] * 0.360673760f;
  const float mbB = -kmx * qnA[bh*200 + mqB] * 0.360673760f;
  const float* mpA = mask + ((size_t)b*200 + mqA)*1000 + z*512;
  const float* mpB = mask + ((size_t)b*200 + mqB)*1000 + z*512;

  f32x4 OA = zero, OB = zero;
  float lA0=0.f, lA1=0.f, lA2=0.f, lA3=0.f;
  float lB0=0.f, lB1=0.f, lB2=0.f, lB3=0.f;
  const int NTc = 32 - z*2;
  #pragma unroll 4
  for (int t = 0; t < NTc; ++t) {
    const int nl = t*16;
    const f16x4 kf = *(const f16x4*)(Kl + (nl+col)*KSTR + g4);
    const f16x4 vf = *(const f16x4*)(Vl + col*VSTRL + nl + g4);
    f32x4 sA = mfma16(kf, qfA, zero);
    const float4 mkA = *(const float4*)(mpA + nl + g4);
    const float pA0 = exp2f(fmaf(sA[0], 0.360673760f, fmaf(mkA.x, L2E, mbA)));
    const float pA1 = exp2f(fmaf(sA[1], 0.360673760f, fmaf(mkA.y, L2E, mbA)));
    const float pA2 = exp2f(fmaf(sA[2], 0.360673760f, fmaf(mkA.z, L2E, mbA)));
    const float pA3 = exp2f(fmaf(sA[3], 0.360673760f, fmaf(mkA.w, L2E, mbA)));
    lA0 += pA0; lA1 += pA1; lA2 += pA2; lA3 += pA3;
    const f16x4 pfA = __builtin_shufflevector(pkrtz(pA0,pA1), pkrtz(pA2,pA3), 0,1,2,3);
    OA = mfma16(vf, pfA, OA);
    if (hasB) {
      f32x4 sB = mfma16(kf, qfB, zero);
      const float4 mkB = *(const float4*)(mpB + nl + g4);
      const float pB0 = exp2f(fmaf(sB[0], 0.360673760f, fmaf(mkB.x, L2E, mbB)));
      const float pB1 = exp2f(fmaf(sB[1], 0.360673760f, fmaf(mkB.y, L2E, mbB)));
      const float pB2 = exp2f(fmaf(sB[2], 0.360673760f, fmaf(mkB.z, L2E, mbB)));
      const float pB3 = exp2f(fmaf(sB[3], 0.360673760f, fmaf(mkB.w, L2E, mbB)));
      lB0 += pB0; lB1 += pB1; lB2 += pB2; lB3 += pB3;
      const f16x4 pfB = __builtin_shufflevector(pkrtz(pB0,pB1), pkrtz(pB2,pB3), 0,1,2,3);
      OB = mfma16(vf, pfB, OB);
    }
  }
  if (z == 1) { // ragged global tile 62: local rows 480..495, keys valid only g<2
    const int nl = 480;
    const f16x4 kf = *(const f16x4*)(Kl + (nl+col)*KSTR + g4);
    const f16x4 vf = *(const f16x4*)(Vl + col*VSTRL + ((g < 2) ? (nl + g4) : 0));
    f32x4 sA = mfma16(kf, qfA, zero);
    float pA0=0.f,pA1=0.f,pA2=0.f,pA3=0.f;
    if (g < 2) {
      const float4 mkA = *(const float4*)(mpA + nl + g4);
      pA0 = exp2f(fmaf(sA[0], 0.360673760f, fmaf(mkA.x, L2E, mbA)));
      pA1 = exp2f(fmaf(sA[1], 0.360673760f, fmaf(mkA.y, L2E, mbA)));
      pA2 = exp2f(fmaf(sA[2], 0.360673760f, fmaf(mkA.z, L2E, mbA)));
      pA3 = exp2f(fmaf(sA[3], 0.360673760f, fmaf(mkA.w, L2E, mbA)));
      lA0 += pA0; lA1 += pA1; lA2 += pA2; lA3 += pA3;
    }
    const f16x4 pfA = __builtin_shufflevector(pkrtz(pA0,pA1), pkrtz(pA2,pA3), 0,1,2,3);
    OA = mfma16(vf, pfA, OA);
    if (hasB) {
      f32x4 sB = mfma16(kf, qfB, zero);
      float pB0=0.f,pB1=0.f,pB2=0.f,pB3=0.f;
      if (g < 2) {
        const float4 mkB = *(const float4*)(mpB + nl + g4);
        pB0 = exp2f(fmaf(sB[0], 0.360673760f, fmaf(mkB.x, L2E, mbB)));
        pB1 = exp2f(fmaf(sB[1], 0.360673760f, fmaf(mkB.y, L2E, mbB)));
        pB2 = exp2f(fmaf(sB[2], 0.360673760f, fmaf(mkB.z, L2E, mbB)));
        pB3 = exp2f(fmaf(sB[3], 0.360673760f, fmaf(mkB.w, L2E, mbB)));
        lB0 += pB0; lB1 += pB1; lB2 += pB2; lB3 += pB3;
      }
      const f16x4 pfB = __builtin_shufflevector(pkrtz(pB0,pB1), pkrtz(pB2,pB3), 0,1,2,3);
      OB = mfma16(vf, pfB, OB);
    }
  }
  float lA = (lA0 + lA1) + (lA2 + lA3);
  lA += __shfl_xor(lA, 16, 64); lA += __shfl_xor(lA, 32, 64);
  const size_t pbase = (size_t)(z*512 + bh)*200;
  if (mA + col < 200) {
    const f16x4 ov = __builtin_shufflevector(pkrtz(OA[0], OA[1]), pkrtz(OA[2], OA[3]), 0,1,2,3);
    *(f16x4*)(Opart + (pbase + mA + col)*16 + g4) = ov;
    if (g == 0) lpart[pbase + mA + col] = lA;
  }
  if (hasB) {
    float lB = (lB0 + lB1) + (lB2 + lB3);
    lB += __shfl_xor(lB, 16, 64); lB += __shfl_xor(lB, 32, 64);
    if (mB + col < 200) {
      const f16x4 ov = __builtin_shufflevector(pkrtz(OB[0], OB[1]), pkrtz(OB[2], OB[3]), 0,1,2,3);
      *(f16x4*)(Opart + (pbase + mB + col)*16 + g4) = ov;
      if (g == 0) lpart[pbase + mB + col] = lB;
    }
  }
}

// ---------------- k4: combine partials + normalize + Wc GEMM + LoRA (k3c fused) ----------------
__global__ __launch_bounds__(256) void k4_comb(const f16* __restrict__ Opart,
    const float* __restrict__ lpart,
    const float* __restrict__ Wc, const float* __restrict__ bc,
    const float* __restrict__ lcA, const float* __restrict__ lcB,
    f16* __restrict__ mhF)
{
  __shared__ f16 ocr[32*128];
  __shared__ float t16[32*16];
  const int tid = threadIdx.x;
  const int row0 = blockIdx.x * 32;
  for (int i = tid; i < 1024; i += 256) {               // 32 rows x 32 quads(4 f16)
    const int r = i >> 5, c4 = i & 31;
    const int hh = c4 >> 2, q = c4 & 3;
    const int grow = row0 + r;
    const int b = grow / 200, m = grow - b*200;
    const int ridx = (b*8 + hh)*200 + m;
    const f16x4 o0 = *(const f16x4*)(Opart + (size_t)ridx*16 + q*4);
    const f16x4 o1 = *(const f16x4*)(Opart + ((size_t)102400 + ridx)*16 + q*4);
    const float l = lpart[ridx] + lpart[102400 + ridx];
    const float inv = 1.f / fmaxf(l, 1e-35f);
    const float v0 = ((float)o0[0] + (float)o1[0]) * inv;
    const float v1 = ((float)o0[1] + (float)o1[1]) * inv;
    const float v2 = ((float)o0[2] + (float)o1[2]) * inv;
    const float v3 = ((float)o0[3] + (float)o1[3]) * inv;
    *(f16x4*)(ocr + r*128 + hh*16 + q*4) =
        __builtin_shufflevector(pkrtz(v0, v1), pkrtz(v2, v3), 0, 1, 2, 3);
  }
  __syncthreads();
  for (int idx = tid; idx < 32*16; idx += 256) {
    const int r = idx >> 4, kk = idx & 15;
    const f16x8* lrow = (const f16x8*)(ocr + r*128);
    const float* arow = lcA + kk*128;
    float s = 0.f;
    #pragma unroll
    for (int cc = 0; cc < 16; ++cc) {
      f16x8 a = lrow[cc];
      float4 wa = *(const float4*)(arow + cc*8);
      float4 wb = *(const float4*)(arow + cc*8 + 4);
      s = fdot2f(pk2(a[0],a[1]), pkrtz(wa.x,wa.y), s);
      s = fdot2f(pk2(a[2],a[3]), pkrtz(wa.z,wa.w), s);
      s = fdot2f(pk2(a[4],a[5]), pkrtz(wb.x,wb.y), s);
      s = fdot2f(pk2(a[6],a[7]), pkrtz(wb.z,wb.w), s);
    }
    t16[idx] = s;
  }
  __syncthreads();
  const int c = tid & 127, rg = tid >> 7, rb = rg*16;
  float acc[16];
  const float bias = bc[c];
  #pragma unroll
  for (int r = 0; r < 16; ++r) acc[r] = bias;
  const float* wrow = Wc + c*128;
  for (int c0 = 0; c0 < 128; c0 += 16) {
    float4 w0 = *(const float4*)(wrow + c0);
    float4 w1 = *(const float4*)(wrow + c0 + 4);
    float4 w2 = *(const float4*)(wrow + c0 + 8);
    float4 w3 = *(const float4*)(wrow + c0 + 12);
    f16x2 wv[8] = { pkrtz(w0.x,w0.y), pkrtz(w0.z,w0.w), pkrtz(w1.x,w1.y), pkrtz(w1.z,w1.w),
                    pkrtz(w2.x,w2.y), pkrtz(w2.z,w2.w), pkrtz(w3.x,w3.y), pkrtz(w3.z,w3.w) };
    #pragma unroll
    for (int r = 0; r < 16; ++r) {
      const f16x8* op = (const f16x8*)(ocr + (rb+r)*128 + c0);
      f16x8 a0 = op[0], a1 = op[1];
      float s = acc[r];
      s = fdot2f(pk2(a0[0],a0[1]), wv[0], s);
      s = fdot2f(pk2(a0[2],a0[3]), wv[1], s);
      s = fdot2f(pk2(a0[4],a0[5]), wv[2], s);
      s = fdot2f(pk2(a0[6],a0[7]), wv[3], s);
      s = fdot2f(pk2(a1[0],a1[1]), wv[4], s);
      s = fdot2f(pk2(a1[2],a1[3]), wv[5], s);
      s = fdot2f(pk2(a1[4],a1[5]), wv[6], s);
      s = fdot2f(pk2(a1[6],a1[7]), wv[7], s);
      acc[r] = s;
    }
  }
  const float* lb = lcB + c*16;
  float lbv[16];
  #pragma unroll
  for (int i = 0; i < 16; i += 4) {
    float4 t = *(const float4*)(lb + i);
    lbv[i] = t.x; lbv[i+1] = t.y; lbv[i+2] = t.z; lbv[i+3] = t.w;
  }
  #pragma unroll
  for (int r = 0; r < 16; ++r) {
    float dl = 0.f;
    #pragma unroll
    for (int kk = 0; kk < 16; ++kk) dl += t16[(rb+r)*16 + kk] * lbv[kk];
    acc[r] += dl * LORA_SCALE;
  }
  #pragma unroll
  for (int r = 0; r < 16; ++r) {
    mhF[(size_t)(row0 + rb + r)*128 + c] = (f16)acc[r];
  }
}

// ---------------- k5: MFMA probs = softmax(10*tanh(mh@nodes^T/sqrt(128)) + mask) ----------------
__global__ __launch_bounds__(1024) void k5_final(const f16* __restrict__ mhF,
    const f16* __restrict__ nodesT, const float* __restrict__ mask,
    float* __restrict__ out)
{
  __shared__ float sumsA[16][16];
  __shared__ float sumsB[16][16];
  __shared__ float obuf[16][1012];
  const int tid = threadIdx.x, lane = tid & 63, w = tid >> 6;
  const int b = blockIdx.x, j = blockIdx.y;
  const int col = lane & 15, g = lane >> 4, g4 = g*4;
  const int tmA = 2*j, tmB = min(2*j + 1, 12);
  const int mA = tmA*16 + col, mB = tmB*16 + col;
  const int mqA = min(mA, 199), mqB = min(mB, 199);
  f16x4 bfA[8], bfB[8];
  {
    const f16* a = mhF + (size_t)(b*200 + mqA)*128;
    const f16* bb = mhF + (size_t)(b*200 + mqB)*128;
    #pragma unroll
    for (int kk = 0; kk < 8; ++kk) {
      bfA[kk] = *(const f16x4*)(a + kk*16 + g4);
      bfB[kk] = *(const f16x4*)(bb + kk*16 + g4);
    }
  }
  const float* mrowA = mask + (size_t)(b*200 + mqA)*1000;
  const float* mrowB = mask + (size_t)(b*200 + mqB)*1000;
  const f16* ntb = nodesT + (size_t)b*129024;           // 63*8*256
  f16x4 pfA[4], pfB[4];
  float lsumA = 0.f, lsumB = 0.f;
  #pragma unroll
  for (int i = 0; i < 4; ++i) {
    const int t = w + i*16;
    float pA0 = 0.f, pA1 = 0.f, pA2 = 0.f, pA3 = 0.f;
    float pB0 = 0.f, pB1 = 0.f, pB2 = 0.f, pB3 = 0.f;
    if (t < 63) {
      const f16* na = ntb + (size_t)t*2048;             // 8*256
      f32x4 accA = {0.f, 0.f, 0.f, 0.f};
      f32x4 accB = {0.f, 0.f, 0.f, 0.f};
      #pragma unroll
      for (int kk = 0; kk < 8; ++kk) {
        f16x4 af = *(const f16x4*)(na + kk*256 + lane*4);
        accA = mfma16(af, bfA[kk], accA);
        accB = mfma16(af, bfB[kk], accB);
      }
      const int n0 = t*16 + g4;
      float mkvA[4] = {0.f, 0.f, 0.f, 0.f};
      float mkvB[4] = {0.f, 0.f, 0.f, 0.f};
      if (n0 + 3 < 1000) {
        float4 mkA = *(const float4*)(mrowA + n0);
        float4 mkB = *(const float4*)(mrowB + n0);
        mkvA[0] = mkA.x; mkvA[1] = mkA.y; mkvA[2] = mkA.z; mkvA[3] = mkA.w;
        mkvB[0] = mkB.x; mkvB[1] = mkB.y; mkvB[2] = mkB.z; mkvB[3] = mkB.w;
      }
      float pvA[4], pvB[4];
      #pragma unroll
      for (int r = 0; r < 4; ++r) {
        const bool ok = (n0 + r < 1000);
        float xA = accA[r] * 0.08838834764831845f;      // /sqrt(128)
        float eA = exp2f(xA * 2.8853900817779268f);     // e^{2x}
        float thA = 1.f - 2.f/(eA + 1.f);               // tanh
        float tA0 = exp2f((10.f*thA + mkvA[r]) * L2E);
        pvA[r] = ok ? tA0 : 0.f;
        lsumA += pvA[r];
        float xB = accB[r] * 0.08838834764831845f;
        float eB = exp2f(xB * 2.8853900817779268f);
        float thB = 1.f - 2.f/(eB + 1.f);
        float tB0 = exp2f((10.f*thB + mkvB[r]) * L2E);
        pvB[r] = ok ? tB0 : 0.f;
        lsumB += pvB[r];
      }
      pA0 = pvA[0]; pA1 = pvA[1]; pA2 = pvA[2]; pA3 = pvA[3];
      pB0 = pvB[0]; pB1 = pvB[1]; pB2 = pvB[2]; pB3 = pvB[3];
    }
    pfA[i] = __builtin_shufflevector(pkrtz(pA0, pA1), pkrtz(pA2, pA3), 0, 1, 2, 3);
    pfB[i] = __builtin_shufflevector(pkrtz(pB0, pB1), pkrtz(pB2, pB3), 0, 1, 2, 3);
  }
  lsumA += __shfl_xor(lsumA, 16, 64);
  lsumA += __shfl_xor(lsumA, 32, 64);
  lsumB += __shfl_xor(lsumB, 16, 64);
  lsumB += __shfl_xor(lsumB, 32, 64);
  if (lane < 16) { sumsA[w][lane] = lsumA; sumsB[w][lane] = lsumB; }
  __syncthreads();
  float SA = 0.f, SB = 0.f;
  #pragma unroll
  for (int ww = 0; ww < 16; ++ww) { SA += sumsA[ww][col]; SB += sumsB[ww][col]; }
  const float invA = 1.f / SA;
  const float invB = 1.f / SB;
  // ---- tile A: stage normalized probs to LDS, then coalesced row streams ----
  #pragma unroll
  for (int i = 0; i < 4; ++i) {
    const int t = w + i*16;
    if (t < 63) {
      const f16x4 pv = pfA[i];
      const int n0 = t*16 + g4;
      #pragma unroll
      for (int r = 0; r < 4; ++r) obuf[col][n0 + r] = (float)pv[r]*invA;
    }
  }
  __syncthreads();
  if (tid < 1000) {
    for (int rr = 0; rr < 16; ++rr) {
      const int m = tmA*16 + rr;
      if (m < 200) out[((size_t)b*200 + m)*1000 + tid] = obuf[rr][tid];
    }
  }
  __syncthreads();
  if (tmB != tmA) {
    #pragma unroll
    for (int i = 0; i < 4; ++i) {
      const int t = w + i*16;
      if (t < 63) {
        const f16x4 pv = pfB[i];
        const int n0 = t*16 + g4;
        #pragma unroll
        for (int r = 0; r < 4; ++r) obuf[col][n0 + r] = (float)pv[r]*invB;
      }
    }
    __syncthreads();
    if (tid < 1000) {
      for (int rr = 0; rr < 16; ++rr) {
        const int m = tmB*16 + rr;
        if (m < 200) out[((size_t)b*200 + m)*1000 + tid] = obuf[rr][tid];
      }
    }
  }
}

extern "C" void kernel_launch(void* const* d_in, const int* in_sizes, int n_in,
                              void* d_out, int out_size, void* d_ws, size_t ws_size,
                              hipStream_t stream)
{
  (void)in_sizes; (void)n_in; (void)out_size; (void)ws_size;
  const float* nodes = (const float*)d_in[0];
  const float* q1    = (const float*)d_in[1];
  const float* last  = (const float*)d_in[2];
  const float* mask  = (const float*)d_in[3];
  const float* Wqf   = (const float*)d_in[4];
  const float* Wql   = (const float*)d_in[5];
  const float* Wk    = (const float*)d_in[6];
  const float* Wv    = (const float*)d_in[7];
  const float* Wc    = (const float*)d_in[8];
  const float* bc    = (const float*)d_in[9];
  const float* lqA   = (const float*)d_in[10];
  const float* lqB   = (const float*)d_in[11];
  const float* lcA   = (const float*)d_in[12];
  const float* lcB   = (const float*)d_in[13];
  float* out = (float*)d_out;
  char* ws = (char*)d_ws;
  // ws layout (bytes):
  f16* Kp      = (f16*)(ws + 16384000);    // 16,384,000
  f16* Vt      = (f16*)(ws + 32768000);    // 16,384,000
  f16* qF      = (f16*)(ws + 49152000);    //  3,276,800
  f16* ocmh    = (f16*)(ws + 52428800);    //  3,276,800  (mh only; oc fused into k4)
  float* kmaxA = (float*)(ws + 55771136);  //      2,048
  float* qnA   = (float*)(ws + 55773184);  //    409,600
  f16* OpartF  = (f16*)(ws + 56182784);    //  6,553,600
  float* lpart = (float*)(ws + 62736384);  //    819,200  (end 63,555,584)
  f16* nodesT  = (f16*)(ws + 63555584);    // 16,515,072  (end 80,070,656)

  k1_proj<<<dim3(16, 64), 256, 0, stream>>>(nodes, Wk, Wv, nodesT, Kp, Vt);
  k2_q<<<dim3(400), 256, 0, stream>>>(q1, last, Wqf, Wql, lqA, lqB, qF);
  kb_norms<<<dim3(912), 256, 0, stream>>>(Kp, qF, kmaxA, qnA);
  k3_attn<<<dim3(64, 8, 2), 512, 36992, stream>>>(Kp, Vt, qF, mask, kmaxA, qnA, OpartF, lpart);
  k4_comb<<<dim3(400), 256, 0, stream>>>(OpartF, lpart, Wc, bc, lcA, lcB, ocmh);
  k5_final<<<dim3(64, 7), 1024, 0, stream>>>(ocmh, nodesT, mask, out);
}